// Round 7
// baseline (525.947 us; speedup 1.0000x reference)
//
#include <hip/hip_runtime.h>

// GraphAttention (e3nn-style) on MI355X — Round 11: round-10 design, compile fix.
// Round-10 failed to compile: __builtin_amdgcn_cvt_pkrtz returns __fp16x2, our
// h2 is _Float16x2 -> no implicit conversion. Fix: __builtin_bit_cast the result.
// Design (unchanged): (a) inner products via packed f16 FMA (v_pk_fma_f16 —
// baseline VOP3P on gfx950) with f16 accumulation: 2 MACs/instr, zero unpack.
// (b) 2 edges/thread at BS=128, EPB=64 (1563 blocks): per-wave weight sweep
// serves 32 edges -> LDS-broadcast floor halves. h2-packed accumulators keep
// VGPR ~130-170 (no spill; round-7 lesson: no launch-bounds cap).
// LDS staging layouts identical to round 9 (verified passing).
//
// Dims: M0=16 M1=8 Q0=8 Q1=4 O0=16 O1=8 EDGE_BASIS=16 HIDDEN=32
// TPK [32][320]: w1[0,128) w2[128,192) w3[192,256) w4[256,288) w5[288,320)
// TPV [32][640]: w1[0,256) w2[256,384) w3[384,512) w4[512,576) w5[576,640)
//
// Pipeline: node_pre | count_edges | scan | edge_k | edge_v_a | edge_v_b | node_reduce
// ws (4B units): qd[N*20] | cnt[N] | start[N+1] | cursor[N] | flag | pad |
//                exbuf[E] | sabuf[E] | posbuf[E] | vbuf[E*40]

#define BS 128           // threads per block (edge kernels): 2 waves
#define EPB 64           // edges per block: 2 waves x 16 q-lanes x 2 edges

typedef _Float16 h2 __attribute__((ext_vector_type(2)));

__device__ __forceinline__ float silu_f(float x) {
    return x * (1.0f / (1.0f + __expf(-x)));
}
__device__ __forceinline__ unsigned short f2h(float f) {   // f32 -> f16 RNE
    return __builtin_bit_cast(unsigned short, (_Float16)f);
}
__device__ __forceinline__ unsigned pk2h(float a, float b) { // pack 2 f16 (RNE)
    return (unsigned)f2h(a) | ((unsigned)f2h(b) << 16);
}
__device__ __forceinline__ h2 uh2(unsigned u) {
    return __builtin_bit_cast(h2, u);
}
__device__ __forceinline__ h2 pkrtz(float a, float b) {    // v_cvt_pkrtz_f16_f32
    return __builtin_bit_cast(h2, __builtin_amdgcn_cvt_pkrtz(a, b));
}
__device__ __forceinline__ h2 pfma(h2 a, h2 b, h2 c) {     // v_pk_fma_f16
    return __builtin_elementwise_fma(a, b, c);
}
__device__ __forceinline__ float h2s(h2 a) {               // lo+hi in f32
    return (float)a[0] + (float)a[1];
}
__device__ __forceinline__ h2 dup0(h2 a) { return __builtin_shufflevector(a, a, 0, 0); }
__device__ __forceinline__ h2 dup1(h2 a) { return __builtin_shufflevector(a, a, 1, 1); }
__device__ __forceinline__ float wred4(float v) {          // sum over 4 p-groups
    v += __shfl_xor(v, 16);
    v += __shfl_xor(v, 32);
    return v;
}

__global__ __launch_bounds__(256) void node_pre(
    const float* __restrict__ node_ft,
    const int*   __restrict__ ei,
    const float* __restrict__ w_q_s, const float* __restrict__ w_q_v,
    const float* __restrict__ wdot_s, const float* __restrict__ wdot_v,
    float* __restrict__ qd, int* __restrict__ cnt, int* __restrict__ flag,
    int N, int E)
{
    const int n = blockIdx.x * blockDim.x + threadIdx.x;
    if (n == 0) {
        int acc = 0;
        const int kmax = (E < 64) ? E : 64;
        for (int k = 0; k < kmax; ++k) acc |= ei[2*k + 1];
        *flag = (acc == 0) ? 1 : 0;   // int64 layout => odd words all zero
    }
    if (n >= N) return;
    cnt[n] = 0;

    const float* nf = node_ft + (size_t)n * 40;
    float xs[16];
#pragma unroll
    for (int i = 0; i < 16; ++i) xs[i] = nf[i];
    float q[8];
#pragma unroll
    for (int o = 0; o < 8; ++o) {
        float a = 0.f;
#pragma unroll
        for (int i = 0; i < 16; ++i) a += xs[i] * w_q_s[i*8 + o];
        q[o] = a * 0.25f;
    }
    float* qdn = qd + (size_t)n * 20;
#pragma unroll
    for (int j = 0; j < 8; ++j) {
        float a = 0.f;
#pragma unroll
        for (int i = 0; i < 8; ++i) a += q[i] * wdot_s[i*8 + j];
        qdn[j] = a;
    }
    float xv[8][3];
#pragma unroll
    for (int i = 0; i < 8; ++i)
#pragma unroll
        for (int c = 0; c < 3; ++c) xv[i][c] = nf[16 + i*3 + c];
    float qv[4][3];
#pragma unroll
    for (int o = 0; o < 4; ++o)
#pragma unroll
        for (int c = 0; c < 3; ++c) {
            float a = 0.f;
#pragma unroll
            for (int i = 0; i < 8; ++i) a += xv[i][c] * w_q_v[i*4 + o];
            qv[o][c] = a * 0.35355339059327379f;
        }
#pragma unroll
    for (int j = 0; j < 4; ++j)
#pragma unroll
        for (int c = 0; c < 3; ++c) {
            float a = 0.f;
#pragma unroll
            for (int i = 0; i < 4; ++i) a += qv[i][c] * wdot_v[i*4 + j];
            qdn[8 + j*3 + c] = a;
        }
}

__global__ __launch_bounds__(256) void count_edges(
    const int* __restrict__ ei, int* __restrict__ cnt,
    const int* __restrict__ flag, int E)
{
    const int e = blockIdx.x * blockDim.x + threadIdx.x;
    if (e >= E) return;
    const int is64 = *flag;
    const int rcv = is64 ? ei[2*(E + e)] : ei[E + e];
    atomicAdd(cnt + rcv, 1);
}

// 1 block, 1024 threads; shuffle-based scan (few barriers).
__global__ __launch_bounds__(1024) void scan_kernel(
    const int* __restrict__ cnt, int* __restrict__ start,
    int* __restrict__ cursor, int N)
{
    __shared__ int wsum[16];
    __shared__ int s_carry;
    const int tid = threadIdx.x, wave = tid >> 6, lane = tid & 63;
    if (tid == 0) s_carry = 0;
    __syncthreads();
    for (int base = 0; base < N; base += 1024) {
        const int i = base + tid;
        const int v = (i < N) ? cnt[i] : 0;
        int x = v;                                  // inclusive intra-wave scan
#pragma unroll
        for (int d = 1; d < 64; d <<= 1) {
            const int y = __shfl_up(x, d, 64);
            if (lane >= d) x += y;
        }
        if (lane == 63) wsum[wave] = x;
        __syncthreads();
        if (wave == 0 && lane < 16) {
            int w = wsum[lane];
#pragma unroll
            for (int d = 1; d < 16; d <<= 1) {
                const int y = __shfl_up(w, d, 64);
                if (lane >= d) w += y;              // lanes 16..63 inactive
            }
            wsum[lane] = w;                         // inclusive wave-prefix
        }
        __syncthreads();
        const int woff = (wave == 0) ? 0 : wsum[wave - 1];
        const int carry = s_carry;
        if (i < N) {
            const int s = carry + woff + x - v;     // exclusive
            start[i] = s;
            cursor[i] = s;
        }
        __syncthreads();
        if (tid == 0) s_carry = carry + wsum[15];
        __syncthreads();
    }
    if (tid == 0) start[N] = s_carry;
}

// ===================== edge_k: K-side TP + dot + softmax terms =====================
// LDS: 4 groups x 321 uint4 = 20544 B (group stride 5136 B; %128==16 ->
// 4 concurrent group reads hit disjoint bank quads, conflict-free).
// Per-group uint4 map (f16 pairs) — identical to round 9:
//  [0,128):  w1  idx j*4 + ip*2 + h   half2=(i0,i0+1), i0=4p+2ip, outs o=4h..4h+3
//  [128,192): w3 idx 128 + j*2 + ip   half2=(i0,i0+1), outs o=0..3
//  [192,256): w2 idx 192 + j*2 + h    half2=(2p,2p+1), outs o=4h..4h+3
//  [256,320): w45 idx 256 + jp*4 + {il0w4,il0w5,il1w4,il1w5}, half2=(j0,j0+1)
__global__ __launch_bounds__(BS) void edge_k(
    const float* __restrict__ node_ft,
    const int*   __restrict__ ei,
    const float* __restrict__ edge_sh,
    const float* __restrict__ edge_scalars,
    const float* __restrict__ fck_w1,
    const float* __restrict__ fck_w2,
    const float* __restrict__ qd,
    int*   __restrict__ cursor,
    float* __restrict__ exbuf,              // [E] CSR order
    float* __restrict__ sabuf,              // [E] edge order
    int*   __restrict__ posbuf,             // [E] edge order
    const int* __restrict__ flag,
    int N, int E)
{
    __shared__ uint4 sk4[4 * 321];          // 20544 B

    const int tid = threadIdx.x;
    // ---- stage weights (f16 pairs, group-split, permuted) ----
    for (int idx = tid; idx < 4 * 320; idx += BS) {
        const int p = idx / 320;
        const int local = idx - p * 320;
        unsigned r0, r1, r2, r3;
        if (local < 128) {                       // w1: pair over i, 4 outs
            const int j = local >> 2, rr = local & 3, ip = rr >> 1, h = rr & 1;
            const int i0 = 4*p + 2*ip;
            const float* s0 = fck_w2 + j*320 + i0*8 + 4*h;
            const float* s1 = s0 + 8;
            r0 = pk2h(s0[0], s1[0]); r1 = pk2h(s0[1], s1[1]);
            r2 = pk2h(s0[2], s1[2]); r3 = pk2h(s0[3], s1[3]);
        } else if (local < 192) {                // w3: pair over i, 4 outs
            const int l = local - 128; const int j = l >> 1, ip = l & 1;
            const int i0 = 4*p + 2*ip;
            const float* s0 = fck_w2 + j*320 + 192 + i0*4;
            const float* s1 = s0 + 4;
            r0 = pk2h(s0[0], s1[0]); r1 = pk2h(s0[1], s1[1]);
            r2 = pk2h(s0[2], s1[2]); r3 = pk2h(s0[3], s1[3]);
        } else if (local < 256) {                // w2: pair over i=(2p,2p+1)
            const int l = local - 192; const int j = l >> 1, h = l & 1;
            const int i0 = 2*p;
            const float* s0 = fck_w2 + j*320 + 128 + i0*8 + 4*h;
            const float* s1 = s0 + 8;
            r0 = pk2h(s0[0], s1[0]); r1 = pk2h(s0[1], s1[1]);
            r2 = pk2h(s0[2], s1[2]); r3 = pk2h(s0[3], s1[3]);
        } else {                                 // w45: pair over j=(2jp,2jp+1)
            const int l = local - 256; const int jp = l >> 2, rr = l & 3;
            const int il = rr >> 1, h = rr & 1;
            const int i = 2*p + il, j0 = 2*jp;
            const int col = (h == 0 ? 256 : 288) + i*4;
            const float* s0 = fck_w2 + j0*320 + col;
            const float* s1 = s0 + 320;
            r0 = pk2h(s0[0], s1[0]); r1 = pk2h(s0[1], s1[1]);
            r2 = pk2h(s0[2], s1[2]); r3 = pk2h(s0[3], s1[3]);
        }
        sk4[p * 321 + local] = make_uint4(r0, r1, r2, r3);
    }

    const int lane = tid & 63;
    const int p = lane >> 4;
    const int q = lane & 15;
    const int w = tid >> 6;
    const int e0 = blockIdx.x * EPB + w * 32 + 2 * q;
    const int e1 = e0 + 1;
    const bool v0 = (e0 < E), v1 = (e1 < E);
    const int e0c = v0 ? e0 : (E - 1);
    const int e1c = v1 ? e1 : (E - 1);

    const int is64 = *flag;
    const int snd0 = is64 ? ei[2*e0c]       : ei[e0c];
    const int rcv0 = is64 ? ei[2*(E + e0c)] : ei[E + e0c];
    const int snd1 = is64 ? ei[2*e1c]       : ei[e1c];
    const int rcv1 = is64 ? ei[2*(E + e1c)] : ei[E + e1c];

    int pos0 = 0, pos1 = 0;
    if (p == 0) {                                 // one claimant per edge
        if (v0) pos0 = atomicAdd(cursor + rcv0, 1);
        if (v1) pos1 = atomicAdd(cursor + rcv1, 1);
    }

    const float4 s40 = *(const float4*)(edge_sh + (size_t)e0c * 4);
    const float4 s41 = *(const float4*)(edge_sh + (size_t)e1c * 4);
    const float sh_s0 = s40.x, sh_s1 = s41.x;
    const float sh_v0[3] = {s40.y, s40.z, s40.w};
    const float sh_v1[3] = {s41.y, s41.z, s41.w};

    const float* nf0 = node_ft + (size_t)snd0 * 40;
    const float* nf1 = node_ft + (size_t)snd1 * 40;

    __syncthreads();                              // weights staged; no barriers below

    // ---- hidden activations, packed (e0,e1) per j ----
    h2 hkp[32];
    {
        float es0[16], es1[16];
        const float4* a0 = (const float4*)(edge_scalars + (size_t)e0c * 16);
        const float4* a1 = (const float4*)(edge_scalars + (size_t)e1c * 16);
#pragma unroll
        for (int t = 0; t < 4; ++t) {
            const float4 a = a0[t], b = a1[t];
            es0[4*t+0]=a.x; es0[4*t+1]=a.y; es0[4*t+2]=a.z; es0[4*t+3]=a.w;
            es1[4*t+0]=b.x; es1[4*t+1]=b.y; es1[4*t+2]=b.z; es1[4*t+3]=b.w;
        }
#pragma unroll 8
        for (int j = 0; j < 32; ++j) {
            float a = 0.f, b = 0.f;
#pragma unroll
            for (int t = 0; t < 16; ++t) {
                const float w1 = fck_w1[t*32 + j];
                a += es0[t] * w1; b += es1[t] * w1;
            }
            hkp[j] = pkrtz(silu_f(a * 0.25f), silu_f(b * 0.25f));
        }
    }

    const uint4* g = sk4 + p * 321;

    // x packs (f16 pairs of this group's i-quarter) + xv f32 for epilogue
    const h2 xs01a = pkrtz(nf0[4*p + 0], nf0[4*p + 1]);
    const h2 xs23a = pkrtz(nf0[4*p + 2], nf0[4*p + 3]);
    const h2 xs01b = pkrtz(nf1[4*p + 0], nf1[4*p + 1]);
    const h2 xs23b = pkrtz(nf1[4*p + 2], nf1[4*p + 3]);
    const float c3 = 0.57735026918962576f;
    const float xa00 = nf0[16 + 6*p], xa01 = nf0[17 + 6*p], xa02 = nf0[18 + 6*p];
    const float xa10 = nf0[19 + 6*p], xa11 = nf0[20 + 6*p], xa12 = nf0[21 + 6*p];
    const float xb00 = nf1[16 + 6*p], xb01 = nf1[17 + 6*p], xb02 = nf1[18 + 6*p];
    const float xb10 = nf1[19 + 6*p], xb11 = nf1[20 + 6*p], xb12 = nf1[21 + 6*p];
    const h2 pvpa = pkrtz((xa00*sh_v0[0] + xa01*sh_v0[1] + xa02*sh_v0[2]) * c3,
                          (xa10*sh_v0[0] + xa11*sh_v0[1] + xa12*sh_v0[2]) * c3);
    const h2 pvpb = pkrtz((xb00*sh_v1[0] + xb01*sh_v1[1] + xb02*sh_v1[2]) * c3,
                          (xb10*sh_v1[0] + xb11*sh_v1[1] + xb12*sh_v1[2]) * c3);

    // ---- merged w1+w3+w2 j-loop (packed f16 accumulate) ----
    h2 K1a[8] = {}, K3a[4] = {}, K2a[8] = {};
    h2 K1b[8] = {}, K3b[4] = {}, K2b[8] = {};
#pragma unroll 4
    for (int j = 0; j < 32; ++j) {
        const uint4 A = g[j*4+0], B = g[j*4+1], C = g[j*4+2], D = g[j*4+3];
        const uint4 Ea = g[128 + j*2], Fb = g[128 + j*2 + 1];
        const uint4 U = g[192 + j*2], V = g[192 + j*2 + 1];
        const h2 hj = hkp[j];
        {
            const h2 hh = dup0(hj);
            const h2 t01 = hh * xs01a, t23 = hh * xs23a, tp = hh * pvpa;
            K1a[0]=pfma(t01,uh2(A.x),K1a[0]); K1a[0]=pfma(t23,uh2(C.x),K1a[0]);
            K1a[1]=pfma(t01,uh2(A.y),K1a[1]); K1a[1]=pfma(t23,uh2(C.y),K1a[1]);
            K1a[2]=pfma(t01,uh2(A.z),K1a[2]); K1a[2]=pfma(t23,uh2(C.z),K1a[2]);
            K1a[3]=pfma(t01,uh2(A.w),K1a[3]); K1a[3]=pfma(t23,uh2(C.w),K1a[3]);
            K1a[4]=pfma(t01,uh2(B.x),K1a[4]); K1a[4]=pfma(t23,uh2(D.x),K1a[4]);
            K1a[5]=pfma(t01,uh2(B.y),K1a[5]); K1a[5]=pfma(t23,uh2(D.y),K1a[5]);
            K1a[6]=pfma(t01,uh2(B.z),K1a[6]); K1a[6]=pfma(t23,uh2(D.z),K1a[6]);
            K1a[7]=pfma(t01,uh2(B.w),K1a[7]); K1a[7]=pfma(t23,uh2(D.w),K1a[7]);
            K3a[0]=pfma(t01,uh2(Ea.x),K3a[0]); K3a[0]=pfma(t23,uh2(Fb.x),K3a[0]);
            K3a[1]=pfma(t01,uh2(Ea.y),K3a[1]); K3a[1]=pfma(t23,uh2(Fb.y),K3a[1]);
            K3a[2]=pfma(t01,uh2(Ea.z),K3a[2]); K3a[2]=pfma(t23,uh2(Fb.z),K3a[2]);
            K3a[3]=pfma(t01,uh2(Ea.w),K3a[3]); K3a[3]=pfma(t23,uh2(Fb.w),K3a[3]);
            K2a[0]=pfma(tp,uh2(U.x),K2a[0]); K2a[1]=pfma(tp,uh2(U.y),K2a[1]);
            K2a[2]=pfma(tp,uh2(U.z),K2a[2]); K2a[3]=pfma(tp,uh2(U.w),K2a[3]);
            K2a[4]=pfma(tp,uh2(V.x),K2a[4]); K2a[5]=pfma(tp,uh2(V.y),K2a[5]);
            K2a[6]=pfma(tp,uh2(V.z),K2a[6]); K2a[7]=pfma(tp,uh2(V.w),K2a[7]);
        }
        {
            const h2 hh = dup1(hj);
            const h2 t01 = hh * xs01b, t23 = hh * xs23b, tp = hh * pvpb;
            K1b[0]=pfma(t01,uh2(A.x),K1b[0]); K1b[0]=pfma(t23,uh2(C.x),K1b[0]);
            K1b[1]=pfma(t01,uh2(A.y),K1b[1]); K1b[1]=pfma(t23,uh2(C.y),K1b[1]);
            K1b[2]=pfma(t01,uh2(A.z),K1b[2]); K1b[2]=pfma(t23,uh2(C.z),K1b[2]);
            K1b[3]=pfma(t01,uh2(A.w),K1b[3]); K1b[3]=pfma(t23,uh2(C.w),K1b[3]);
            K1b[4]=pfma(t01,uh2(B.x),K1b[4]); K1b[4]=pfma(t23,uh2(D.x),K1b[4]);
            K1b[5]=pfma(t01,uh2(B.y),K1b[5]); K1b[5]=pfma(t23,uh2(D.y),K1b[5]);
            K1b[6]=pfma(t01,uh2(B.z),K1b[6]); K1b[6]=pfma(t23,uh2(D.z),K1b[6]);
            K1b[7]=pfma(t01,uh2(B.w),K1b[7]); K1b[7]=pfma(t23,uh2(D.w),K1b[7]);
            K3b[0]=pfma(t01,uh2(Ea.x),K3b[0]); K3b[0]=pfma(t23,uh2(Fb.x),K3b[0]);
            K3b[1]=pfma(t01,uh2(Ea.y),K3b[1]); K3b[1]=pfma(t23,uh2(Fb.y),K3b[1]);
            K3b[2]=pfma(t01,uh2(Ea.z),K3b[2]); K3b[2]=pfma(t23,uh2(Fb.z),K3b[2]);
            K3b[3]=pfma(t01,uh2(Ea.w),K3b[3]); K3b[3]=pfma(t23,uh2(Fb.w),K3b[3]);
            K2b[0]=pfma(tp,uh2(U.x),K2b[0]); K2b[1]=pfma(tp,uh2(U.y),K2b[1]);
            K2b[2]=pfma(tp,uh2(U.z),K2b[2]); K2b[3]=pfma(tp,uh2(U.w),K2b[3]);
            K2b[4]=pfma(tp,uh2(V.x),K2b[4]); K2b[5]=pfma(tp,uh2(V.y),K2b[5]);
            K2b[6]=pfma(tp,uh2(V.z),K2b[6]); K2b[7]=pfma(tp,uh2(V.w),K2b[7]);
        }
    }

    // ---- w4/w5: contract over j-pairs; acc2 = (j-even, j-odd) partials ----
    h2 P4a[8] = {}, P5a[8] = {}, P4b[8] = {}, P5b[8] = {};   // [il*4+o]
#pragma unroll 4
    for (int jp = 0; jp < 16; ++jp) {
        const uint4 a4 = g[256 + jp*4 + 0];   // il0 w4
        const uint4 b4 = g[256 + jp*4 + 1];   // il0 w5
        const uint4 c4 = g[256 + jp*4 + 2];   // il1 w4
        const uint4 d4 = g[256 + jp*4 + 3];   // il1 w5
        const h2 hja = hkp[2*jp], hjb = hkp[2*jp+1];
        const h2 hpa = __builtin_shufflevector(hja, hjb, 0, 2);
        const h2 hpb = __builtin_shufflevector(hja, hjb, 1, 3);
        P4a[0]=pfma(hpa,uh2(a4.x),P4a[0]); P4a[1]=pfma(hpa,uh2(a4.y),P4a[1]);
        P4a[2]=pfma(hpa,uh2(a4.z),P4a[2]); P4a[3]=pfma(hpa,uh2(a4.w),P4a[3]);
        P5a[0]=pfma(hpa,uh2(b4.x),P5a[0]); P5a[1]=pfma(hpa,uh2(b4.y),P5a[1]);
        P5a[2]=pfma(hpa,uh2(b4.z),P5a[2]); P5a[3]=pfma(hpa,uh2(b4.w),P5a[3]);
        P4a[4]=pfma(hpa,uh2(c4.x),P4a[4]); P4a[5]=pfma(hpa,uh2(c4.y),P4a[5]);
        P4a[6]=pfma(hpa,uh2(c4.z),P4a[6]); P4a[7]=pfma(hpa,uh2(c4.w),P4a[7]);
        P5a[4]=pfma(hpa,uh2(d4.x),P5a[4]); P5a[5]=pfma(hpa,uh2(d4.y),P5a[5]);
        P5a[6]=pfma(hpa,uh2(d4.z),P5a[6]); P5a[7]=pfma(hpa,uh2(d4.w),P5a[7]);
        P4b[0]=pfma(hpb,uh2(a4.x),P4b[0]); P4b[1]=pfma(hpb,uh2(a4.y),P4b[1]);
        P4b[2]=pfma(hpb,uh2(a4.z),P4b[2]); P4b[3]=pfma(hpb,uh2(a4.w),P4b[3]);
        P5b[0]=pfma(hpb,uh2(b4.x),P5b[0]); P5b[1]=pfma(hpb,uh2(b4.y),P5b[1]);
        P5b[2]=pfma(hpb,uh2(b4.z),P5b[2]); P5b[3]=pfma(hpb,uh2(b4.w),P5b[3]);
        P4b[4]=pfma(hpb,uh2(c4.x),P4b[4]); P4b[5]=pfma(hpb,uh2(c4.y),P4b[5]);
        P4b[6]=pfma(hpb,uh2(c4.z),P4b[6]); P4b[7]=pfma(hpb,uh2(c4.w),P4b[7]);
        P5b[4]=pfma(hpb,uh2(d4.x),P5b[4]); P5b[5]=pfma(hpb,uh2(d4.y),P5b[5]);
        P5b[6]=pfma(hpb,uh2(d4.z),P5b[6]); P5b[7]=pfma(hpb,uh2(d4.w),P5b[7]);
    }

    // ---- epilogue: per-thread PARTIAL dot, reduce only 2 scalars per edge ----
    const float c7 = 0.70710678118654752f;
    float ds0 = 0.f, dv0 = 0.f, ds1 = 0.f, dv1 = 0.f;
    {
        float qdr[20];
        const float4* rp = (const float4*)(qd + (size_t)rcv0 * 20);
#pragma unroll
        for (int t = 0; t < 5; ++t) {
            const float4 a = rp[t];
            qdr[4*t+0]=a.x; qdr[4*t+1]=a.y; qdr[4*t+2]=a.z; qdr[4*t+3]=a.w;
        }
#pragma unroll
        for (int o = 0; o < 8; ++o)
            ds0 += qdr[o] * (sh_s0*h2s(K1a[o]) + h2s(K2a[o]));
        float KV[12] = {};
        {
            const float s0=sh_s0*xa00, s1=sh_s0*xa01, s2=sh_s0*xa02;
            const float cx0=c7*(xa01*sh_v0[2]-xa02*sh_v0[1]);
            const float cx1=c7*(xa02*sh_v0[0]-xa00*sh_v0[2]);
            const float cx2=c7*(xa00*sh_v0[1]-xa01*sh_v0[0]);
#pragma unroll
            for (int o = 0; o < 4; ++o) {
                const float w4 = h2s(P4a[o]), w5 = h2s(P5a[o]);
                KV[o*3+0] += s0*w4 + cx0*w5;
                KV[o*3+1] += s1*w4 + cx1*w5;
                KV[o*3+2] += s2*w4 + cx2*w5;
            }
        }
        {
            const float s0=sh_s0*xa10, s1=sh_s0*xa11, s2=sh_s0*xa12;
            const float cx0=c7*(xa11*sh_v0[2]-xa12*sh_v0[1]);
            const float cx1=c7*(xa12*sh_v0[0]-xa10*sh_v0[2]);
            const float cx2=c7*(xa10*sh_v0[1]-xa11*sh_v0[0]);
#pragma unroll
            for (int o = 0; o < 4; ++o) {
                const float w4 = h2s(P4a[4+o]), w5 = h2s(P5a[4+o]);
                KV[o*3+0] += s0*w4 + cx0*w5;
                KV[o*3+1] += s1*w4 + cx1*w5;
                KV[o*3+2] += s2*w4 + cx2*w5;
            }
        }
#pragma unroll
        for (int o = 0; o < 4; ++o) {
            const float k3 = h2s(K3a[o]);
#pragma unroll
            for (int c = 0; c < 3; ++c)
                dv0 += qdr[8 + o*3 + c] * (k3*sh_v0[c] + KV[o*3+c]);
        }
    }
    {
        float qdr[20];
        const float4* rp = (const float4*)(qd + (size_t)rcv1 * 20);
#pragma unroll
        for (int t = 0; t < 5; ++t) {
            const float4 a = rp[t];
            qdr[4*t+0]=a.x; qdr[4*t+1]=a.y; qdr[4*t+2]=a.z; qdr[4*t+3]=a.w;
        }
#pragma unroll
        for (int o = 0; o < 8; ++o)
            ds1 += qdr[o] * (sh_s1*h2s(K1b[o]) + h2s(K2b[o]));
        float KV[12] = {};
        {
            const float s0=sh_s1*xb00, s1=sh_s1*xb01, s2=sh_s1*xb02;
            const float cx0=c7*(xb01*sh_v1[2]-xb02*sh_v1[1]);
            const float cx1=c7*(xb02*sh_v1[0]-xb00*sh_v1[2]);
            const float cx2=c7*(xb00*sh_v1[1]-xb01*sh_v1[0]);
#pragma unroll
            for (int o = 0; o < 4; ++o) {
                const float w4 = h2s(P4b[o]), w5 = h2s(P5b[o]);
                KV[o*3+0] += s0*w4 + cx0*w5;
                KV[o*3+1] += s1*w4 + cx1*w5;
                KV[o*3+2] += s2*w4 + cx2*w5;
            }
        }
        {
            const float s0=sh_s1*xb10, s1=sh_s1*xb11, s2=sh_s1*xb12;
            const float cx0=c7*(xb11*sh_v1[2]-xb12*sh_v1[1]);
            const float cx1=c7*(xb12*sh_v1[0]-xb10*sh_v1[2]);
            const float cx2=c7*(xb10*sh_v1[1]-xb11*sh_v1[0]);
#pragma unroll
            for (int o = 0; o < 4; ++o) {
                const float w4 = h2s(P4b[4+o]), w5 = h2s(P5b[4+o]);
                KV[o*3+0] += s0*w4 + cx0*w5;
                KV[o*3+1] += s1*w4 + cx1*w5;
                KV[o*3+2] += s2*w4 + cx2*w5;
            }
        }
#pragma unroll
        for (int o = 0; o < 4; ++o) {
            const float k3 = h2s(K3b[o]);
#pragma unroll
            for (int c = 0; c < 3; ++c)
                dv1 += qdr[8 + o*3 + c] * (k3*sh_v1[c] + KV[o*3+c]);
        }
    }
    ds0 = wred4(ds0); dv0 = wred4(dv0);
    ds1 = wred4(ds1); dv1 = wred4(dv1);

    if (p == 0) {
        if (v0) {
            const float dot = ds0 * 4.0343567508008e-3f + dv0 * 2.0171788261497e-3f;
            const float sa = __expf(0.5f * dot);
            exbuf[pos0] = sa*sa; sabuf[e0] = sa; posbuf[e0] = pos0;
        }
        if (v1) {
            const float dot = ds1 * 4.0343567508008e-3f + dv1 * 2.0171788261497e-3f;
            const float sa = __expf(0.5f * dot);
            exbuf[pos1] = sa*sa; sabuf[e1] = sa; posbuf[e1] = pos1;
        }
    }
}

// ===================== edge_v_a: V scalar outputs (cols [0,384)) =====================
// LDS: 4 x 385 uint4 = 24640 B (stride 6160 B, %128==16 -> conflict-free).
// Per-group uint4 map (round 9): [0,256): w1 idx j*8 + ip*4 + h(0..3),
// half2=(i0,i0+1), outs 4h..; [256,384): w2 idx 256 + j*4 + h, half2=(2p,2p+1).
__global__ __launch_bounds__(BS) void edge_v_a(
    const float* __restrict__ node_ft,
    const int*   __restrict__ ei,
    const float* __restrict__ edge_sh,
    const float* __restrict__ edge_scalars,
    const float* __restrict__ fcv_w1,
    const float* __restrict__ fcv_w2,
    const float* __restrict__ sabuf,
    const int*   __restrict__ posbuf,
    float* __restrict__ vbuf,               // [E,40]
    const int* __restrict__ flag,
    int E)
{
    __shared__ uint4 sa4[4 * 385];          // 24640 B

    const int tid = threadIdx.x;
    for (int idx = tid; idx < 4 * 384; idx += BS) {
        const int p = idx / 384;
        const int local = idx - p * 384;
        const float* s0;
        const float* s1;
        if (local < 256) {                           // w1
            const int j = local >> 3, rr = local & 7, ip = rr >> 2, h = rr & 3;
            const int i0 = 4*p + 2*ip;
            s0 = fcv_w2 + j*640 + i0*16 + h*4;
            s1 = s0 + 16;
        } else {                                     // w2
            const int l = local - 256; const int j = l >> 2, h = l & 3;
            const int i0 = 2*p;
            s0 = fcv_w2 + j*640 + 256 + i0*16 + h*4;
            s1 = s0 + 16;
        }
        sa4[p * 385 + local] = make_uint4(
            pk2h(s0[0], s1[0]), pk2h(s0[1], s1[1]),
            pk2h(s0[2], s1[2]), pk2h(s0[3], s1[3]));
    }

    const int lane = tid & 63;
    const int p = lane >> 4;
    const int q = lane & 15;
    const int w = tid >> 6;
    const int e0 = blockIdx.x * EPB + w * 32 + 2 * q;
    const int e1 = e0 + 1;
    const bool v0 = (e0 < E), v1 = (e1 < E);
    const int e0c = v0 ? e0 : (E - 1);
    const int e1c = v1 ? e1 : (E - 1);

    const int is64 = *flag;
    const int snd0 = is64 ? ei[2*e0c] : ei[e0c];
    const int snd1 = is64 ? ei[2*e1c] : ei[e1c];

    const float4 s40 = *(const float4*)(edge_sh + (size_t)e0c * 4);
    const float4 s41 = *(const float4*)(edge_sh + (size_t)e1c * 4);

    const float* nf0 = node_ft + (size_t)snd0 * 40;
    const float* nf1 = node_ft + (size_t)snd1 * 40;

    __syncthreads();

    h2 hvp[32];
    {
        float es0[16], es1[16];
        const float4* a0 = (const float4*)(edge_scalars + (size_t)e0c * 16);
        const float4* a1 = (const float4*)(edge_scalars + (size_t)e1c * 16);
#pragma unroll
        for (int t = 0; t < 4; ++t) {
            const float4 a = a0[t], b = a1[t];
            es0[4*t+0]=a.x; es0[4*t+1]=a.y; es0[4*t+2]=a.z; es0[4*t+3]=a.w;
            es1[4*t+0]=b.x; es1[4*t+1]=b.y; es1[4*t+2]=b.z; es1[4*t+3]=b.w;
        }
#pragma unroll 8
        for (int j = 0; j < 32; ++j) {
            float a = 0.f, b = 0.f;
#pragma unroll
            for (int t = 0; t < 16; ++t) {
                const float w1 = fcv_w1[t*32 + j];
                a += es0[t] * w1; b += es1[t] * w1;
            }
            hvp[j] = pkrtz(silu_f(a * 0.25f), silu_f(b * 0.25f));
        }
    }

    const uint4* g = sa4 + p * 385;

    // packs: shs folded into xs; pv packs for w2
    const h2 xs01a = pkrtz(nf0[4*p + 0]*s40.x, nf0[4*p + 1]*s40.x);
    const h2 xs23a = pkrtz(nf0[4*p + 2]*s40.x, nf0[4*p + 3]*s40.x);
    const h2 xs01b = pkrtz(nf1[4*p + 0]*s41.x, nf1[4*p + 1]*s41.x);
    const h2 xs23b = pkrtz(nf1[4*p + 2]*s41.x, nf1[4*p + 3]*s41.x);
    const float c3 = 0.57735026918962576f;
    const h2 pvpa = pkrtz(
        (nf0[16+6*p]*s40.y + nf0[17+6*p]*s40.z + nf0[18+6*p]*s40.w) * c3,
        (nf0[19+6*p]*s40.y + nf0[20+6*p]*s40.z + nf0[21+6*p]*s40.w) * c3);
    const h2 pvpb = pkrtz(
        (nf1[16+6*p]*s41.y + nf1[17+6*p]*s41.z + nf1[18+6*p]*s41.w) * c3,
        (nf1[19+6*p]*s41.y + nf1[20+6*p]*s41.z + nf1[21+6*p]*s41.w) * c3);

    h2 Aa[16] = {}, Ab[16] = {};
#pragma unroll 2
    for (int j = 0; j < 32; ++j) {
        const uint4* gw = g + j*8;
        const uint4 a0 = gw[0], a1 = gw[1], a2 = gw[2], a3 = gw[3];   // ip0
        const uint4 b0 = gw[4], b1 = gw[5], b2 = gw[6], b3 = gw[7];   // ip1
        const uint4* g2 = g + 256 + j*4;
        const uint4 u0 = g2[0], u1 = g2[1], u2 = g2[2], u3 = g2[3];
        const h2 hj = hvp[j];
        {
            const h2 hh = dup0(hj);
            const h2 t01 = hh * xs01a, t23 = hh * xs23a, tp = hh * pvpa;
            Aa[0] =pfma(t01,uh2(a0.x),Aa[0]);  Aa[0] =pfma(t23,uh2(b0.x),Aa[0]);  Aa[0] =pfma(tp,uh2(u0.x),Aa[0]);
            Aa[1] =pfma(t01,uh2(a0.y),Aa[1]);  Aa[1] =pfma(t23,uh2(b0.y),Aa[1]);  Aa[1] =pfma(tp,uh2(u0.y),Aa[1]);
            Aa[2] =pfma(t01,uh2(a0.z),Aa[2]);  Aa[2] =pfma(t23,uh2(b0.z),Aa[2]);  Aa[2] =pfma(tp,uh2(u0.z),Aa[2]);
            Aa[3] =pfma(t01,uh2(a0.w),Aa[3]);  Aa[3] =pfma(t23,uh2(b0.w),Aa[3]);  Aa[3] =pfma(tp,uh2(u0.w),Aa[3]);
            Aa[4] =pfma(t01,uh2(a1.x),Aa[4]);  Aa[4] =pfma(t23,uh2(b1.x),Aa[4]);  Aa[4] =pfma(tp,uh2(u1.x),Aa[4]);
            Aa[5] =pfma(t01,uh2(a1.y),Aa[5]);  Aa[5] =pfma(t23,uh2(b1.y),Aa[5]);  Aa[5] =pfma(tp,uh2(u1.y),Aa[5]);
            Aa[6] =pfma(t01,uh2(a1.z),Aa[6]);  Aa[6] =pfma(t23,uh2(b1.z),Aa[6]);  Aa[6] =pfma(tp,uh2(u1.z),Aa[6]);
            Aa[7] =pfma(t01,uh2(a1.w),Aa[7]);  Aa[7] =pfma(t23,uh2(b1.w),Aa[7]);  Aa[7] =pfma(tp,uh2(u1.w),Aa[7]);
            Aa[8] =pfma(t01,uh2(a2.x),Aa[8]);  Aa[8] =pfma(t23,uh2(b2.x),Aa[8]);  Aa[8] =pfma(tp,uh2(u2.x),Aa[8]);
            Aa[9] =pfma(t01,uh2(a2.y),Aa[9]);  Aa[9] =pfma(t23,uh2(b2.y),Aa[9]);  Aa[9] =pfma(tp,uh2(u2.y),Aa[9]);
            Aa[10]=pfma(t01,uh2(a2.z),Aa[10]); Aa[10]=pfma(t23,uh2(b2.z),Aa[10]); Aa[10]=pfma(tp,uh2(u2.z),Aa[10]);
            Aa[11]=pfma(t01,uh2(a2.w),Aa[11]); Aa[11]=pfma(t23,uh2(b2.w),Aa[11]); Aa[11]=pfma(tp,uh2(u2.w),Aa[11]);
            Aa[12]=pfma(t01,uh2(a3.x),Aa[12]); Aa[12]=pfma(t23,uh2(b3.x),Aa[12]); Aa[12]=pfma(tp,uh2(u3.x),Aa[12]);
            Aa[13]=pfma(t01,uh2(a3.y),Aa[13]); Aa[13]=pfma(t23,uh2(b3.y),Aa[13]); Aa[13]=pfma(tp,uh2(u3.y),Aa[13]);
            Aa[14]=pfma(t01,uh2(a3.z),Aa[14]); Aa[14]=pfma(t23,uh2(b3.z),Aa[14]); Aa[14]=pfma(tp,uh2(u3.z),Aa[14]);
            Aa[15]=pfma(t01,uh2(a3.w),Aa[15]); Aa[15]=pfma(t23,uh2(b3.w),Aa[15]); Aa[15]=pfma(tp,uh2(u3.w),Aa[15]);
        }
        {
            const h2 hh = dup1(hj);
            const h2 t01 = hh * xs01b, t23 = hh * xs23b, tp = hh * pvpb;
            Ab[0] =pfma(t01,uh2(a0.x),Ab[0]);  Ab[0] =pfma(t23,uh2(b0.x),Ab[0]);  Ab[0] =pfma(tp,uh2(u0.x),Ab[0]);
            Ab[1] =pfma(t01,uh2(a0.y),Ab[1]);  Ab[1] =pfma(t23,uh2(b0.y),Ab[1]);  Ab[1] =pfma(tp,uh2(u0.y),Ab[1]);
            Ab[2] =pfma(t01,uh2(a0.z),Ab[2]);  Ab[2] =pfma(t23,uh2(b0.z),Ab[2]);  Ab[2] =pfma(tp,uh2(u0.z),Ab[2]);
            Ab[3] =pfma(t01,uh2(a0.w),Ab[3]);  Ab[3] =pfma(t23,uh2(b0.w),Ab[3]);  Ab[3] =pfma(tp,uh2(u0.w),Ab[3]);
            Ab[4] =pfma(t01,uh2(a1.x),Ab[4]);  Ab[4] =pfma(t23,uh2(b1.x),Ab[4]);  Ab[4] =pfma(tp,uh2(u1.x),Ab[4]);
            Ab[5] =pfma(t01,uh2(a1.y),Ab[5]);  Ab[5] =pfma(t23,uh2(b1.y),Ab[5]);  Ab[5] =pfma(tp,uh2(u1.y),Ab[5]);
            Ab[6] =pfma(t01,uh2(a1.z),Ab[6]);  Ab[6] =pfma(t23,uh2(b1.z),Ab[6]);  Ab[6] =pfma(tp,uh2(u1.z),Ab[6]);
            Ab[7] =pfma(t01,uh2(a1.w),Ab[7]);  Ab[7] =pfma(t23,uh2(b1.w),Ab[7]);  Ab[7] =pfma(tp,uh2(u1.w),Ab[7]);
            Ab[8] =pfma(t01,uh2(a2.x),Ab[8]);  Ab[8] =pfma(t23,uh2(b2.x),Ab[8]);  Ab[8] =pfma(tp,uh2(u2.x),Ab[8]);
            Ab[9] =pfma(t01,uh2(a2.y),Ab[9]);  Ab[9] =pfma(t23,uh2(b2.y),Ab[9]);  Ab[9] =pfma(tp,uh2(u2.y),Ab[9]);
            Ab[10]=pfma(t01,uh2(a2.z),Ab[10]); Ab[10]=pfma(t23,uh2(b2.z),Ab[10]); Ab[10]=pfma(tp,uh2(u2.z),Ab[10]);
            Ab[11]=pfma(t01,uh2(a2.w),Ab[11]); Ab[11]=pfma(t23,uh2(b2.w),Ab[11]); Ab[11]=pfma(tp,uh2(u2.w),Ab[11]);
            Ab[12]=pfma(t01,uh2(a3.x),Ab[12]); Ab[12]=pfma(t23,uh2(b3.x),Ab[12]); Ab[12]=pfma(tp,uh2(u3.x),Ab[12]);
            Ab[13]=pfma(t01,uh2(a3.y),Ab[13]); Ab[13]=pfma(t23,uh2(b3.y),Ab[13]); Ab[13]=pfma(tp,uh2(u3.y),Ab[13]);
            Ab[14]=pfma(t01,uh2(a3.z),Ab[14]); Ab[14]=pfma(t23,uh2(b3.z),Ab[14]); Ab[14]=pfma(tp,uh2(u3.z),Ab[14]);
            Ab[15]=pfma(t01,uh2(a3.w),Ab[15]); Ab[15]=pfma(t23,uh2(b3.w),Ab[15]); Ab[15]=pfma(tp,uh2(u3.w),Ab[15]);
        }
    }

    float A0[16], A1[16];
#pragma unroll
    for (int o = 0; o < 16; ++o) { A0[o] = wred4(h2s(Aa[o])); A1[o] = wred4(h2s(Ab[o])); }

    if (p == 0) {
        const float cs = 0.03608439182435161f;   // (1/sqrt32)*(1/sqrt24)
        if (v0) {
            const float sa = sabuf[e0];
            const int pos = posbuf[e0];
            float4* vp = (float4*)(vbuf + (size_t)pos * 40);
#pragma unroll
            for (int t = 0; t < 4; ++t) {
                float4 r;
                r.x = sa * A0[4*t+0] * cs; r.y = sa * A0[4*t+1] * cs;
                r.z = sa * A0[4*t+2] * cs; r.w = sa * A0[4*t+3] * cs;
                vp[t] = r;
            }
        }
        if (v1) {
            const float sa = sabuf[e1];
            const int pos = posbuf[e1];
            float4* vp = (float4*)(vbuf + (size_t)pos * 40);
#pragma unroll
            for (int t = 0; t < 4; ++t) {
                float4 r;
                r.x = sa * A1[4*t+0] * cs; r.y = sa * A1[4*t+1] * cs;
                r.z = sa * A1[4*t+2] * cs; r.w = sa * A1[4*t+3] * cs;
                vp[t] = r;
            }
        }
    }
}

// ===================== edge_v_b: V vector outputs (cols [384,640)) =====================
// LDS: 4 x 257 uint4 = 16448 B (stride 4112 B, %128==16 -> conflict-free).
// Per-group uint4 map (round 9): [0,128): w3 idx j*4 + ip*2 + h, half2=(i0,i0+1),
// o=4h..; [128,256): w45 idx 128 + (jp*2+il)*4 + h2, half2=(j0,j0+1);
// h2<2 -> w4, else w5, o0=(h2&1)*4.
__global__ __launch_bounds__(BS) void edge_v_b(
    const float* __restrict__ node_ft,
    const int*   __restrict__ ei,
    const float* __restrict__ edge_sh,
    const float* __restrict__ edge_scalars,
    const float* __restrict__ fcv_w1,
    const float* __restrict__ fcv_w2,
    const float* __restrict__ sabuf,
    const int*   __restrict__ posbuf,
    float* __restrict__ vbuf,               // [E,40]
    const int* __restrict__ flag,
    int E)
{
    __shared__ uint4 sb4[4 * 257];          // 16448 B

    const int tid = threadIdx.x;
    for (int idx = tid; idx < 4 * 256; idx += BS) {
        const int p = idx >> 8;
        const int local = idx & 255;
        const float* s0;
        const float* s1;
        if (local < 128) {                           // w3: pair over i
            const int j = local >> 2, rr = local & 3, ip = rr >> 1, h = rr & 1;
            const int i0 = 4*p + 2*ip;
            s0 = fcv_w2 + j*640 + 384 + i0*8 + 4*h;
            s1 = s0 + 8;
        } else {                                     // w45: pair over j
            const int l = local - 128;
            const int jp = l >> 3, rr = l & 7, il = rr >> 2, h2c = rr & 3;
            const int i = 2*p + il, j0 = 2*jp;
            const int base = (h2c < 2) ? 512 : 576;
            s0 = fcv_w2 + j0*640 + base + i*8 + (h2c & 1)*4;
            s1 = s0 + 640;
        }
        sb4[p * 257 + local] = make_uint4(
            pk2h(s0[0], s1[0]), pk2h(s0[1], s1[1]),
            pk2h(s0[2], s1[2]), pk2h(s0[3], s1[3]));
    }

    const int lane = tid & 63;
    const int p = lane >> 4;
    const int q = lane & 15;
    const int w = tid >> 6;
    const int e0 = blockIdx.x * EPB + w * 32 + 2 * q;
    const int e1 = e0 + 1;
    const bool v0 = (e0 < E), v1 = (e1 < E);
    const int e0c = v0 ? e0 : (E - 1);
    const int e1c = v1 ? e1 : (E - 1);

    const int is64 = *flag;
    const int snd0 = is64 ? ei[2*e0c] : ei[e0c];
    const int snd1 = is64 ? ei[2*e1c] : ei[e1c];

    const float4 s40 = *(const float4*)(edge_sh + (size_t)e0c * 4);
    const float4 s41 = *(const float4*)(edge_sh + (size_t)e1c * 4);
    const float sh_s0 = s40.x, sh_s1 = s41.x;
    const float sh_v0[3] = {s40.y, s40.z, s40.w};
    const float sh_v1[3] = {s41.y, s41.z, s41.w};

    const float* nf0 = node_ft + (size_t)snd0 * 40;
    const float* nf1 = node_ft + (size_t)snd1 * 40;

    __syncthreads();

    h2 hvp[32];
    {
        float es0[16], es1[16];
        const float4* a0 = (const float4*)(edge_scalars + (size_t)e0c * 16);
        const float4* a1 = (const float4*)(edge_scalars + (size_t)e1c * 16);
#pragma unroll
        for (int t = 0; t < 4; ++t) {
            const float4 a = a0[t], b = a1[t];
            es0[4*t+0]=a.x; es0[4*t+1]=a.y; es0[4*t+2]=a.z; es0[4*t+3]=a.w;
            es1[4*t+0]=b.x; es1[4*t+1]=b.y; es1[4*t+2]=b.z; es1[4*t+3]=b.w;
        }
#pragma unroll 8
        for (int j = 0; j < 32; ++j) {
            float a = 0.f, b = 0.f;
#pragma unroll
            for (int t = 0; t < 16; ++t) {
                const float w1 = fcv_w1[t*32 + j];
                a += es0[t] * w1; b += es1[t] * w1;
            }
            hvp[j] = pkrtz(silu_f(a * 0.25f), silu_f(b * 0.25f));
        }
    }

    const uint4* g = sb4 + p * 257;

    const h2 xs01a = pkrtz(nf0[4*p + 0], nf0[4*p + 1]);
    const h2 xs23a = pkrtz(nf0[4*p + 2], nf0[4*p + 3]);
    const h2 xs01b = pkrtz(nf1[4*p + 0], nf1[4*p + 1]);
    const h2 xs23b = pkrtz(nf1[4*p + 2], nf1[4*p + 3]);

    // ---- w3 path ----
    h2 T3a[8] = {}, T3b[8] = {};
#pragma unroll 4
    for (int j = 0; j < 32; ++j) {
        const uint4 E0 = g[j*4+0], E1 = g[j*4+1];   // ip0: o0..3, o4..7
        const uint4 F0 = g[j*4+2], F1 = g[j*4+3];   // ip1
        const h2 hj = hvp[j];
        {
            const h2 hh = dup0(hj);
            const h2 t01 = hh * xs01a, t23 = hh * xs23a;
            T3a[0]=pfma(t01,uh2(E0.x),T3a[0]); T3a[0]=pfma(t23,uh2(F0.x),T3a[0]);
            T3a[1]=pfma(t01,uh2(E0.y),T3a[1]); T3a[1]=pfma(t23,uh2(F0.y),T3a[1]);
            T3a[2]=pfma(t01,uh2(E0.z),T3a[2]); T3a[2]=pfma(t23,uh2(F0.z),T3a[2]);
            T3a[3]=pfma(t01,uh2(E0.w),T3a[3]); T3a[3]=pfma(t23,uh2(F0.w),T3a[3]);
            T3a[4]=pfma(t01,uh2(E1.x),T3a[4]); T3a[4]=pfma(t23,uh2(F1.x),T3a[4]);
            T3a[5]=pfma(t01,uh2(E1.y),T3a[5]); T3a[5]=pfma(t23,uh2(F1.y),T3a[5]);
            T3a[6]=pfma(t01,uh2(E1.z),T3a[6]); T3a[6]=pfma(t23,uh2(F1.z),T3a[6]);
            T3a[7]=pfma(t01,uh2(E1.w),T3a[7]); T3a[7]=pfma(t23,uh2(F1.w),T3a[7]);
        }
        {
            const h2 hh = dup1(hj);
            const h2 t01 = hh * xs01b, t23 = hh * xs23b;
            T3b[0]=pfma(t01,uh2(E0.x),T3b[0]); T3b[0]=pfma(t23,uh2(F0.x),T3b[0]);
            T3b[1]=pfma(t01,uh2(E0.y),T3b[1]); T3b[1]=pfma(t23,uh2(F0.y),T3b[1]);
            T3b[2]=pfma(t01,uh2(E0.z),T3b[2]); T3b[2]=pfma(t23,uh2(F0.z),T3b[2]);
            T3b[3]=pfma(t01,uh2(E0.w),T3b[3]); T3b[3]=pfma(t23,uh2(F0.w),T3b[3]);
            T3b[4]=pfma(t01,uh2(E1.x),T3b[4]); T3b[4]=pfma(t23,uh2(F1.x),T3b[4]);
            T3b[5]=pfma(t01,uh2(E1.y),T3b[5]); T3b[5]=pfma(t23,uh2(F1.y),T3b[5]);
            T3b[6]=pfma(t01,uh2(E1.z),T3b[6]); T3b[6]=pfma(t23,uh2(F1.z),T3b[6]);
            T3b[7]=pfma(t01,uh2(E1.w),T3b[7]); T3b[7]=pfma(t23,uh2(F1.w),T3b[7]);
        }
    }

    // ---- w4/w5: contract over j-pairs ----
    h2 P4a[16] = {}, P5a[16] = {}, P4b[16] = {}, P5b[16] = {};   // [il*8+o]
#pragma unroll 2
    for (int jp = 0; jp < 16; ++jp) {
        const uint4* gw = g + 128 + jp*8;
        const uint4 a4 = gw[0], b4 = gw[1];   // il0 w4 o0-3, o4-7
        const uint4 c4 = gw[2], d4 = gw[3];   // il0 w5
        const uint4 e4 = gw[4], f4 = gw[5];   // il1 w4
        const uint4 m4 = gw[6], n4 = gw[7];   // il1 w5
        const h2 hja = hvp[2*jp], hjb = hvp[2*jp+1];
        const h2 hpa = __builtin_shufflevector(hja, hjb, 0, 2);
        const h2 hpb = __builtin_shufflevector(hja, hjb, 1, 3);
        P4a[0] =pfma(hpa,uh2(a4.x),P4a[0]);  P4a[1] =pfma(hpa,uh2(a4.y),P4a[1]);
        P4a[2] =pfma(hpa,uh2(a4.z),P4a[2]);  P4a[3] =pfma(hpa,uh2(a4.w),P4a[3]);
        P4a[4] =pfma(hpa,uh2(b4.x),P4a[4]);  P4a[5] =pfma(hpa,uh2(b4.y),P4a[5]);
        P4a[6] =pfma(hpa,uh2(b4.z),P4a[6]);  P4a[7] =pfma(hpa,uh2(b4.w),P4a[7]);
        P5a[0] =pfma(hpa,uh2(c4.x),P5a[0]);  P5a[1] =pfma(hpa,uh2(c4.y),P5a[1]);
        P5a[2] =pfma(hpa,uh2(c4.z),P5a[2]);  P5a[3] =pfma(hpa,uh2(c4.w),P5a[3]);
        P5a[4] =pfma(hpa,uh2(d4.x),P5a[4]);  P5a[5] =pfma(hpa,uh2(d4.y),P5a[5]);
        P5a[6] =pfma(hpa,uh2(d4.z),P5a[6]);  P5a[7] =pfma(hpa,uh2(d4.w),P5a[7]);
        P4a[8] =pfma(hpa,uh2(e4.x),P4a[8]);  P4a[9] =pfma(hpa,uh2(e4.y),P4a[9]);
        P4a[10]=pfma(hpa,uh2(e4.z),P4a[10]); P4a[11]=pfma(hpa,uh2(e4.w),P4a[11]);
        P4a[12]=pfma(hpa,uh2(f4.x),P4a[12]); P4a[13]=pfma(hpa,uh2(f4.y),P4a[13]);
        P4a[14]=pfma(hpa,uh2(f4.z),P4a[14]); P4a[15]=pfma(hpa,uh2(f4.w),P4a[15]);
        P5a[8] =pfma(hpa,uh2(m4.x),P5a[8]);  P5a[9] =pfma(hpa,uh2(m4.y),P5a[9]);
        P5a[10]=pfma(hpa,uh2(m4.z),P5a[10]); P5a[11]=pfma(hpa,uh2(m4.w),P5a[11]);
        P5a[12]=pfma(hpa,uh2(n4.x),P5a[12]); P5a[13]=pfma(hpa,uh2(n4.y),P5a[13]);
        P5a[14]=pfma(hpa,uh2(n4.z),P5a[14]); P5a[15]=pfma(hpa,uh2(n4.w),P5a[15]);
        P4b[0] =pfma(hpb,uh2(a4.x),P4b[0]);  P4b[1] =pfma(hpb,uh2(a4.y),P4b[1]);
        P4b[2] =pfma(hpb,uh2(a4.z),P4b[2]);  P4b[3] =pfma(hpb,uh2(a4.w),P4b[3]);
        P4b[4] =pfma(hpb,uh2(b4.x),P4b[4]);  P4b[5] =pfma(hpb,uh2(b4.y),P4b[5]);
        P4b[6] =pfma(hpb,uh2(b4.z),P4b[6]);  P4b[7] =pfma(hpb,uh2(b4.w),P4b[7]);
        P5b[0] =pfma(hpb,uh2(c4.x),P5b[0]);  P5b[1] =pfma(hpb,uh2(c4.y),P5b[1]);
        P5b[2] =pfma(hpb,uh2(c4.z),P5b[2]);  P5b[3] =pfma(hpb,uh2(c4.w),P5b[3]);
        P5b[4] =pfma(hpb,uh2(d4.x),P5b[4]);  P5b[5] =pfma(hpb,uh2(d4.y),P5b[5]);
        P5b[6] =pfma(hpb,uh2(d4.z),P5b[6]);  P5b[7] =pfma(hpb,uh2(d4.w),P5b[7]);
        P4b[8] =pfma(hpb,uh2(e4.x),P4b[8]);  P4b[9] =pfma(hpb,uh2(e4.y),P4b[9]);
        P4b[10]=pfma(hpb,uh2(e4.z),P4b[10]); P4b[11]=pfma(hpb,uh2(e4.w),P4b[11]);
        P4b[12]=pfma(hpb,uh2(f4.x),P4b[12]); P4b[13]=pfma(hpb,uh2(f4.y),P4b[13]);
        P4b[14]=pfma(hpb,uh2(f4.z),P4b[14]); P4b[15]=pfma(hpb,uh2(f4.w),P4b[15]);
        P5b[8] =pfma(hpb,uh2(m4.x),P5b[8]);  P5b[9] =pfma(hpb,uh2(m4.y),P5b[9]);
        P5b[10]=pfma(hpb,uh2(m4.z),P5b[10]); P5b[11]=pfma(hpb,uh2(m4.w),P5b[11]);
        P5b[12]=pfma(hpb,uh2(n4.x),P5b[12]); P5b[13]=pfma(hpb,uh2(n4.y),P5b[13]);
        P5b[14]=pfma(hpb,uh2(n4.z),P5b[14]); P5b[15]=pfma(hpb,uh2(n4.w),P5b[15]);
    }

    // ---- epilogue: per-thread partial R/T3, reduce, p==0 writes ----
    const float c7 = 0.70710678118654752f;
    float R0[24], R1[24], T30[8], T31[8];
    {
        float acc[24];
#pragma unroll
        for (int o = 0; o < 24; ++o) acc[o] = 0.f;
        {
            const float x0 = nf0[16 + 6*p], x1 = nf0[17 + 6*p], x2 = nf0[18 + 6*p];
            const float s0 = sh_s0*x0, s1 = sh_s0*x1, s2 = sh_s0*x2;
            const float cx0 = c7*(x1*sh_v0[2] - x2*sh_v0[1]);
            const float cx1 = c7*(x2*sh_v0[0] - x0*sh_v0[2]);
            const float cx2 = c7*(x0*sh_v0[1] - x1*sh_v0[0]);
#pragma unroll
            for (int o = 0; o < 8; ++o) {
                const float w4 = h2s(P4a[o]), w5 = h2s(P5a[o]);
                acc[o*3+0] += s0*w4 + cx0*w5;
                acc[o*3+1] += s1*w4 + cx1*w5;
                acc[o*3+2] += s2*w4 + cx2*w5;
            }
        }
        {
            const float x0 = nf0[19 + 6*p], x1 = nf0[20 + 6*p], x2 = nf0[21 + 6*p];
            const float s0 = sh_s0*x0, s1 = sh_s0*x1, s2 = sh_s0*x2;
            const float cx0 = c7*(x1*sh_v0[2] - x2*sh_v0[1]);
            const float cx1 = c7*(x2*sh_v0[0] - x0*sh_v0[2]);
            const float cx2 = c7*(x0*sh_v0[1] - x1*sh_v0[0]);
#pragma unroll
            for (int o = 0; o < 8; ++o) {
                const float w4 = h2s(P4a[8+o]), w5 = h2s(P5a[8+o]);
                acc[o*3+0] += s0*w4 + cx0*w5;
                acc[o*3+1] += s1*w4 + cx1*w5;
                acc[o*3+2] += s2*w4 + cx2*w5;
            }
        }
#pragma unroll
        for (int o = 0; o < 24; ++o) R0[o] = wred4(acc[o]);
    }
    {
        float acc[24];
#pragma unroll
        for (int o = 0; o < 24; ++o) acc[o] = 0.f;
        {
            const float x0 = nf1[16 + 6*p], x1 = nf1[17 + 6*p], x2 = nf1[18 + 6*p];
            const float s0 = sh_s1*x0, s1 = sh_s1*x1, s2 = sh_s1*x2;
            const float cx0 = c7*(x1*sh_v1[2] - x2*sh_v1[1]);
            const float cx1 = c7*(x2*sh_v1[0] - x0*sh_v1[2]);
            const float cx2 = c7*(x0*sh_v1[1] - x1*sh_v1[0]);
#pragma unroll
            for (int o = 0; o < 8; ++o) {
                const float w4 = h2s(P4b[o]), w5 = h2s(P5b[o]);
                acc[o*3+0] += s0*w4 + cx0*w5;
                acc[o*3+1] += s1*w4 + cx1*w5;
                acc[o*3+2] += s2*w4 + cx2*w5;
            }
        }
        {
            const float x0 = nf1[19 + 6*p], x1 = nf1[20 + 6*p], x2 = nf1[21 + 6*p];
            const float s0 = sh_s1*x0, s1 = sh_s1*x1, s2 = sh_s1*x2;
            const float cx0 = c7*(x1*sh_v1[2] - x2*sh_v1[1]);
            const float cx1 = c7*(x2*sh_v1[0] - x0*sh_v1[2]);
            const float cx2 = c7*(x0*sh_v1[1] - x1*sh_v1[0]);
#pragma unroll
            for (int o = 0; o < 8; ++o) {
                const float w4 = h2s(P4b[8+o]), w5 = h2s(P5b[8+o]);
                acc[o*3+0] += s0*w4 + cx0*w5;
                acc[o*3+1] += s1*w4 + cx1*w5;
                acc[o*3+2] += s2*w4 + cx2*w5;
            }
        }
#pragma unroll
        for (int o = 0; o < 24; ++o) R1[o] = wred4(acc[o]);
    }
#pragma unroll
    for (int o = 0; o < 8; ++o) { T30[o] = wred4(h2s(T3a[o])); T31[o] = wred4(h2s(T3b[o])); }

    if (p == 0) {
        const float sc = 0.03125f;               // (1/sqrt32)*(1/sqrt32)
        if (v0) {
            const float sa = sabuf[e0];
            const int pos = posbuf[e0];
            float row[24];
#pragma unroll
            for (int o = 0; o < 8; ++o)
#pragma unroll
                for (int c = 0; c < 3; ++c)
                    row[o*3+c] = sa * (T30[o]*sh_v0[c] + R0[o*3+c]) * sc;
            float4* vp = (float4*)(vbuf + (size_t)pos * 40 + 16);
#pragma unroll
            for (int t = 0; t < 6; ++t) {
                float4 r; r.x = row[4*t+0]; r.y = row[4*t+1]; r.z = row[4*t+2]; r.w = row[4*t+3];
                vp[t] = r;
            }
        }
        if (v1) {
            const float sa = sabuf[e1];
            const int pos = posbuf[e1];
            float row[24];
#pragma unroll
            for (int o = 0; o < 8; ++o)
#pragma unroll
                for (int c = 0; c < 3; ++c)
                    row[o*3+c] = sa * (T31[o]*sh_v1[c] + R1[o*3+c]) * sc;
            float4* vp = (float4*)(vbuf + (size_t)pos * 40 + 16);
#pragma unroll
            for (int t = 0; t < 6; ++t) {
                float4 r; r.x = row[4*t+0]; r.y = row[4*t+1]; r.z = row[4*t+2]; r.w = row[4*t+3];
                vp[t] = r;
            }
        }
    }
}

__global__ __launch_bounds__(256) void node_reduce(
    const int*   __restrict__ start,
    const float* __restrict__ exbuf,
    const float* __restrict__ vbuf,
    float* __restrict__ out, int N)
{
    const int wave = threadIdx.x >> 6;
    const int lane = threadIdx.x & 63;
    const int n = blockIdx.x * 4 + wave;
    if (n >= N) return;
    const int r0 = start[n], r1 = start[n + 1];
    float z = 0.f, comp = 0.f;
    for (int r = r0; r < r1; ++r) {
        z += exbuf[r];
        if (lane < 40) comp += vbuf[(size_t)r * 40 + lane];
    }
    if (lane < 40)
        out[(size_t)n * 40 + lane] = (z > 0.f) ? comp * rsqrtf(z) : 0.f;
}

extern "C" void kernel_launch(void* const* d_in, const int* in_sizes, int n_in,
                              void* d_out, int out_size, void* d_ws, size_t ws_size,
                              hipStream_t stream) {
    const float* node_ft      = (const float*)d_in[0];
    const int*   edge_index   = (const int*)  d_in[1];
    const float* edge_sh      = (const float*)d_in[2];
    const float* edge_scalars = (const float*)d_in[3];
    const float* w_q_s        = (const float*)d_in[4];
    const float* w_q_v        = (const float*)d_in[5];
    const float* fck_w1       = (const float*)d_in[6];
    const float* fck_w2       = (const float*)d_in[7];
    const float* fcv_w1       = (const float*)d_in[8];
    const float* fcv_w2       = (const float*)d_in[9];
    const float* wdot_s       = (const float*)d_in[10];
    const float* wdot_v       = (const float*)d_in[11];

    const int N = in_sizes[0] / 40;
    const int E = in_sizes[2] / 4;

    float* ws    = (float*)d_ws;
    float* qd    = ws;                               // N*20
    int*   cnt   = (int*)(ws + (size_t)N * 20);      // N
    int*   start = cnt + N;                          // N+1
    int*   curs  = start + N + 1;                    // N
    int*   flg   = curs + N;                         // 1
    size_t off   = (size_t)N * 20 + N + (N + 1) + N + 1;
    off = (off + 3) & ~(size_t)3;                    // 16B align
    float* exbuf  = ws + off;                        // E
    float* sabuf  = exbuf + E;                       // E
    int*   posbuf = (int*)(sabuf + E);               // E
    float* vbuf   = (float*)(posbuf + E);            // E*40 (E%4==0 -> aligned)

    float* out = (float*)d_out;

    const int EB = (E + EPB - 1) / EPB;

    hipLaunchKernelGGL(node_pre, dim3((N + 255) / 256), dim3(256), 0, stream,
                       node_ft, edge_index, w_q_s, w_q_v, wdot_s, wdot_v,
                       qd, cnt, flg, N, E);
    hipLaunchKernelGGL(count_edges, dim3((E + 255) / 256), dim3(256), 0, stream,
                       edge_index, cnt, flg, E);
    hipLaunchKernelGGL(scan_kernel, dim3(1), dim3(1024), 0, stream,
                       cnt, start, curs, N);
    hipLaunchKernelGGL(edge_k, dim3(EB), dim3(BS), 0, stream,
                       node_ft, edge_index, edge_sh, edge_scalars,
                       fck_w1, fck_w2, qd, curs, exbuf, sabuf, posbuf, flg, N, E);
    hipLaunchKernelGGL(edge_v_a, dim3(EB), dim3(BS), 0, stream,
                       node_ft, edge_index, edge_sh, edge_scalars,
                       fcv_w1, fcv_w2, sabuf, posbuf, vbuf, flg, E);
    hipLaunchKernelGGL(edge_v_b, dim3(EB), dim3(BS), 0, stream,
                       node_ft, edge_index, edge_sh, edge_scalars,
                       fcv_w1, fcv_w2, sabuf, posbuf, vbuf, flg, E);
    hipLaunchKernelGGL(node_reduce, dim3((N + 3) / 4), dim3(256), 0, stream,
                       start, exbuf, vbuf, out, N);
}

// Round 8
// 269.156 us; speedup vs baseline: 1.9541x; 1.9541x over previous
//
#include <hip/hip_runtime.h>

// GraphAttention (e3nn-style) on MI355X — Round 12: pk_fma f16 math at
// round-9 occupancy (BS=256, 1 edge/thread).
// Round-11 post-mortem: 2-edges/thread at BS=128 HALVED total waves (6252->
// 3126, occ 16.8%, VALUBusy 28%) -> latency-bound, 3.8x regression. The
// packed-f16 math itself passed (absmax 0.015625). Fix: single-edge reduction
// of round 11's verified inner loops on round 9's skeleton (BS=256, EPB=64,
// 1563 blocks x 4 waves, occ ~24%). VALU per weight-pair drops 4 ops (scalar
// d2 fallback) -> ~1.3 (pfma + amortized muls); LDS broadcast floor binds.
//
// Dims: M0=16 M1=8 Q0=8 Q1=4 O0=16 O1=8 EDGE_BASIS=16 HIDDEN=32
// TPK [32][320]: w1[0,128) w2[128,192) w3[192,256) w4[256,288) w5[288,320)
// TPV [32][640]: w1[0,256) w2[256,384) w3[384,512) w4[512,576) w5[576,640)
//
// Pipeline: node_pre | count_edges | scan | edge_k | edge_v_a | edge_v_b | node_reduce
// ws (4B units): qd[N*20] | cnt[N] | start[N+1] | cursor[N] | flag | pad |
//                exbuf[E] | sabuf[E] | posbuf[E] | vbuf[E*40]

#define BS 256           // threads per block (edge kernels): 4 waves
#define EPB 64           // edges per block: 4 waves x 16 q-lanes x 1 edge

typedef _Float16 h2 __attribute__((ext_vector_type(2)));

__device__ __forceinline__ float silu_f(float x) {
    return x * (1.0f / (1.0f + __expf(-x)));
}
__device__ __forceinline__ unsigned short f2h(float f) {   // f32 -> f16 RNE
    return __builtin_bit_cast(unsigned short, (_Float16)f);
}
__device__ __forceinline__ unsigned pk2h(float a, float b) { // pack 2 f16 (RNE)
    return (unsigned)f2h(a) | ((unsigned)f2h(b) << 16);
}
__device__ __forceinline__ h2 uh2(unsigned u) {
    return __builtin_bit_cast(h2, u);
}
__device__ __forceinline__ h2 pkrtz(float a, float b) {    // v_cvt_pkrtz_f16_f32
    return __builtin_bit_cast(h2, __builtin_amdgcn_cvt_pkrtz(a, b));
}
__device__ __forceinline__ h2 pfma(h2 a, h2 b, h2 c) {     // v_pk_fma_f16
    return __builtin_elementwise_fma(a, b, c);
}
__device__ __forceinline__ float h2s(h2 a) {               // lo+hi in f32
    return (float)a[0] + (float)a[1];
}
__device__ __forceinline__ float wred4(float v) {          // sum over 4 p-groups
    v += __shfl_xor(v, 16);
    v += __shfl_xor(v, 32);
    return v;
}

__global__ __launch_bounds__(256) void node_pre(
    const float* __restrict__ node_ft,
    const int*   __restrict__ ei,
    const float* __restrict__ w_q_s, const float* __restrict__ w_q_v,
    const float* __restrict__ wdot_s, const float* __restrict__ wdot_v,
    float* __restrict__ qd, int* __restrict__ cnt, int* __restrict__ flag,
    int N, int E)
{
    const int n = blockIdx.x * blockDim.x + threadIdx.x;
    if (n == 0) {
        int acc = 0;
        const int kmax = (E < 64) ? E : 64;
        for (int k = 0; k < kmax; ++k) acc |= ei[2*k + 1];
        *flag = (acc == 0) ? 1 : 0;   // int64 layout => odd words all zero
    }
    if (n >= N) return;
    cnt[n] = 0;

    const float* nf = node_ft + (size_t)n * 40;
    float xs[16];
#pragma unroll
    for (int i = 0; i < 16; ++i) xs[i] = nf[i];
    float q[8];
#pragma unroll
    for (int o = 0; o < 8; ++o) {
        float a = 0.f;
#pragma unroll
        for (int i = 0; i < 16; ++i) a += xs[i] * w_q_s[i*8 + o];
        q[o] = a * 0.25f;
    }
    float* qdn = qd + (size_t)n * 20;
#pragma unroll
    for (int j = 0; j < 8; ++j) {
        float a = 0.f;
#pragma unroll
        for (int i = 0; i < 8; ++i) a += q[i] * wdot_s[i*8 + j];
        qdn[j] = a;
    }
    float xv[8][3];
#pragma unroll
    for (int i = 0; i < 8; ++i)
#pragma unroll
        for (int c = 0; c < 3; ++c) xv[i][c] = nf[16 + i*3 + c];
    float qv[4][3];
#pragma unroll
    for (int o = 0; o < 4; ++o)
#pragma unroll
        for (int c = 0; c < 3; ++c) {
            float a = 0.f;
#pragma unroll
            for (int i = 0; i < 8; ++i) a += xv[i][c] * w_q_v[i*4 + o];
            qv[o][c] = a * 0.35355339059327379f;
        }
#pragma unroll
    for (int j = 0; j < 4; ++j)
#pragma unroll
        for (int c = 0; c < 3; ++c) {
            float a = 0.f;
#pragma unroll
            for (int i = 0; i < 4; ++i) a += qv[i][c] * wdot_v[i*4 + j];
            qdn[8 + j*3 + c] = a;
        }
}

__global__ __launch_bounds__(256) void count_edges(
    const int* __restrict__ ei, int* __restrict__ cnt,
    const int* __restrict__ flag, int E)
{
    const int e = blockIdx.x * blockDim.x + threadIdx.x;
    if (e >= E) return;
    const int is64 = *flag;
    const int rcv = is64 ? ei[2*(E + e)] : ei[E + e];
    atomicAdd(cnt + rcv, 1);
}

// 1 block, 1024 threads; shuffle-based scan (few barriers).
__global__ __launch_bounds__(1024) void scan_kernel(
    const int* __restrict__ cnt, int* __restrict__ start,
    int* __restrict__ cursor, int N)
{
    __shared__ int wsum[16];
    __shared__ int s_carry;
    const int tid = threadIdx.x, wave = tid >> 6, lane = tid & 63;
    if (tid == 0) s_carry = 0;
    __syncthreads();
    for (int base = 0; base < N; base += 1024) {
        const int i = base + tid;
        const int v = (i < N) ? cnt[i] : 0;
        int x = v;                                  // inclusive intra-wave scan
#pragma unroll
        for (int d = 1; d < 64; d <<= 1) {
            const int y = __shfl_up(x, d, 64);
            if (lane >= d) x += y;
        }
        if (lane == 63) wsum[wave] = x;
        __syncthreads();
        if (wave == 0 && lane < 16) {
            int w = wsum[lane];
#pragma unroll
            for (int d = 1; d < 16; d <<= 1) {
                const int y = __shfl_up(w, d, 64);
                if (lane >= d) w += y;              // lanes 16..63 inactive
            }
            wsum[lane] = w;                         // inclusive wave-prefix
        }
        __syncthreads();
        const int woff = (wave == 0) ? 0 : wsum[wave - 1];
        const int carry = s_carry;
        if (i < N) {
            const int s = carry + woff + x - v;     // exclusive
            start[i] = s;
            cursor[i] = s;
        }
        __syncthreads();
        if (tid == 0) s_carry = carry + wsum[15];
        __syncthreads();
    }
    if (tid == 0) start[N] = s_carry;
}

// ===================== edge_k: K-side TP + dot + softmax terms =====================
// LDS: 4 groups x 321 uint4 = 20544 B (group stride 5136 B; %128==16 ->
// 4 concurrent group reads hit disjoint bank quads, conflict-free).
// Per-group uint4 map (f16 pairs) — identical to rounds 9/11:
//  [0,128):  w1  idx j*4 + ip*2 + h   half2=(i0,i0+1), i0=4p+2ip, outs o=4h..4h+3
//  [128,192): w3 idx 128 + j*2 + ip   half2=(i0,i0+1), outs o=0..3
//  [192,256): w2 idx 192 + j*2 + h    half2=(2p,2p+1), outs o=4h..4h+3
//  [256,320): w45 idx 256 + jp*4 + {il0w4,il0w5,il1w4,il1w5}, half2=(j0,j0+1)
__global__ __launch_bounds__(BS) void edge_k(
    const float* __restrict__ node_ft,
    const int*   __restrict__ ei,
    const float* __restrict__ edge_sh,
    const float* __restrict__ edge_scalars,
    const float* __restrict__ fck_w1,
    const float* __restrict__ fck_w2,
    const float* __restrict__ qd,
    int*   __restrict__ cursor,
    float* __restrict__ exbuf,              // [E] CSR order
    float* __restrict__ sabuf,              // [E] edge order
    int*   __restrict__ posbuf,             // [E] edge order
    const int* __restrict__ flag,
    int N, int E)
{
    __shared__ uint4 sk4[4 * 321];          // 20544 B

    const int tid = threadIdx.x;
    // ---- stage weights (f16 pairs, group-split, permuted) ----
    for (int idx = tid; idx < 4 * 320; idx += BS) {
        const int p = idx / 320;
        const int local = idx - p * 320;
        unsigned r0, r1, r2, r3;
        if (local < 128) {                       // w1: pair over i, 4 outs
            const int j = local >> 2, rr = local & 3, ip = rr >> 1, h = rr & 1;
            const int i0 = 4*p + 2*ip;
            const float* s0 = fck_w2 + j*320 + i0*8 + 4*h;
            const float* s1 = s0 + 8;
            r0 = pk2h(s0[0], s1[0]); r1 = pk2h(s0[1], s1[1]);
            r2 = pk2h(s0[2], s1[2]); r3 = pk2h(s0[3], s1[3]);
        } else if (local < 192) {                // w3: pair over i, 4 outs
            const int l = local - 128; const int j = l >> 1, ip = l & 1;
            const int i0 = 4*p + 2*ip;
            const float* s0 = fck_w2 + j*320 + 192 + i0*4;
            const float* s1 = s0 + 4;
            r0 = pk2h(s0[0], s1[0]); r1 = pk2h(s0[1], s1[1]);
            r2 = pk2h(s0[2], s1[2]); r3 = pk2h(s0[3], s1[3]);
        } else if (local < 256) {                // w2: pair over i=(2p,2p+1)
            const int l = local - 192; const int j = l >> 1, h = l & 1;
            const int i0 = 2*p;
            const float* s0 = fck_w2 + j*320 + 128 + i0*8 + 4*h;
            const float* s1 = s0 + 8;
            r0 = pk2h(s0[0], s1[0]); r1 = pk2h(s0[1], s1[1]);
            r2 = pk2h(s0[2], s1[2]); r3 = pk2h(s0[3], s1[3]);
        } else {                                 // w45: pair over j=(2jp,2jp+1)
            const int l = local - 256; const int jp = l >> 2, rr = l & 3;
            const int il = rr >> 1, h = rr & 1;
            const int i = 2*p + il, j0 = 2*jp;
            const int col = (h == 0 ? 256 : 288) + i*4;
            const float* s0 = fck_w2 + j0*320 + col;
            const float* s1 = s0 + 320;
            r0 = pk2h(s0[0], s1[0]); r1 = pk2h(s0[1], s1[1]);
            r2 = pk2h(s0[2], s1[2]); r3 = pk2h(s0[3], s1[3]);
        }
        sk4[p * 321 + local] = make_uint4(r0, r1, r2, r3);
    }

    const int lane = tid & 63;
    const int p = lane >> 4;
    const int q = lane & 15;
    const int w = tid >> 6;
    const int e = blockIdx.x * EPB + w * 16 + q;
    const bool val = (e < E);
    const int ec = val ? e : (E - 1);

    const int is64 = *flag;
    const int snd = is64 ? ei[2*ec]       : ei[ec];
    const int rcv = is64 ? ei[2*(E + ec)] : ei[E + ec];

    int pos = 0;
    if (p == 0 && val) pos = atomicAdd(cursor + rcv, 1);  // one claimant/edge

    const float4 s4 = *(const float4*)(edge_sh + (size_t)ec * 4);
    const float sh_s = s4.x;
    const float sh_v[3] = {s4.y, s4.z, s4.w};

    const float* nf = node_ft + (size_t)snd * 40;

    __syncthreads();                              // weights staged; no barriers below

    // ---- hidden activations (per lane; redundant across p) ----
    float hk[32];
    {
        float es[16];
        const float4* a0 = (const float4*)(edge_scalars + (size_t)ec * 16);
#pragma unroll
        for (int t = 0; t < 4; ++t) {
            const float4 v = a0[t];
            es[4*t+0]=v.x; es[4*t+1]=v.y; es[4*t+2]=v.z; es[4*t+3]=v.w;
        }
#pragma unroll 8
        for (int j = 0; j < 32; ++j) {
            float a = 0.f;
#pragma unroll
            for (int t = 0; t < 16; ++t) a += es[t] * fck_w1[t*32 + j];
            hk[j] = silu_f(a * 0.25f);
        }
    }

    const uint4* g = sk4 + p * 321;

    // x packs (f16 pairs of this group's i-quarter) + xv f32 for epilogue
    const h2 xs01 = pkrtz(nf[4*p + 0], nf[4*p + 1]);
    const h2 xs23 = pkrtz(nf[4*p + 2], nf[4*p + 3]);
    const float c3 = 0.57735026918962576f;
    const float x00 = nf[16 + 6*p], x01 = nf[17 + 6*p], x02 = nf[18 + 6*p];
    const float x10 = nf[19 + 6*p], x11 = nf[20 + 6*p], x12 = nf[21 + 6*p];
    const h2 pvp = pkrtz((x00*sh_v[0] + x01*sh_v[1] + x02*sh_v[2]) * c3,
                         (x10*sh_v[0] + x11*sh_v[1] + x12*sh_v[2]) * c3);

    // ---- merged w1+w3+w2 j-loop (packed f16 accumulate) ----
    h2 K1[8] = {}, K3[4] = {}, K2[8] = {};
#pragma unroll 4
    for (int j = 0; j < 32; ++j) {
        const uint4 A = g[j*4+0], B = g[j*4+1], C = g[j*4+2], D = g[j*4+3];
        const uint4 Ea = g[128 + j*2], Fb = g[128 + j*2 + 1];
        const uint4 U = g[192 + j*2], V = g[192 + j*2 + 1];
        const h2 hh = pkrtz(hk[j], hk[j]);
        const h2 t01 = hh * xs01, t23 = hh * xs23, tp = hh * pvp;
        K1[0]=pfma(t01,uh2(A.x),K1[0]); K1[0]=pfma(t23,uh2(C.x),K1[0]);
        K1[1]=pfma(t01,uh2(A.y),K1[1]); K1[1]=pfma(t23,uh2(C.y),K1[1]);
        K1[2]=pfma(t01,uh2(A.z),K1[2]); K1[2]=pfma(t23,uh2(C.z),K1[2]);
        K1[3]=pfma(t01,uh2(A.w),K1[3]); K1[3]=pfma(t23,uh2(C.w),K1[3]);
        K1[4]=pfma(t01,uh2(B.x),K1[4]); K1[4]=pfma(t23,uh2(D.x),K1[4]);
        K1[5]=pfma(t01,uh2(B.y),K1[5]); K1[5]=pfma(t23,uh2(D.y),K1[5]);
        K1[6]=pfma(t01,uh2(B.z),K1[6]); K1[6]=pfma(t23,uh2(D.z),K1[6]);
        K1[7]=pfma(t01,uh2(B.w),K1[7]); K1[7]=pfma(t23,uh2(D.w),K1[7]);
        K3[0]=pfma(t01,uh2(Ea.x),K3[0]); K3[0]=pfma(t23,uh2(Fb.x),K3[0]);
        K3[1]=pfma(t01,uh2(Ea.y),K3[1]); K3[1]=pfma(t23,uh2(Fb.y),K3[1]);
        K3[2]=pfma(t01,uh2(Ea.z),K3[2]); K3[2]=pfma(t23,uh2(Fb.z),K3[2]);
        K3[3]=pfma(t01,uh2(Ea.w),K3[3]); K3[3]=pfma(t23,uh2(Fb.w),K3[3]);
        K2[0]=pfma(tp,uh2(U.x),K2[0]); K2[1]=pfma(tp,uh2(U.y),K2[1]);
        K2[2]=pfma(tp,uh2(U.z),K2[2]); K2[3]=pfma(tp,uh2(U.w),K2[3]);
        K2[4]=pfma(tp,uh2(V.x),K2[4]); K2[5]=pfma(tp,uh2(V.y),K2[5]);
        K2[6]=pfma(tp,uh2(V.z),K2[6]); K2[7]=pfma(tp,uh2(V.w),K2[7]);
    }

    // ---- w4/w5: contract over j-pairs (packed h); P[il*4+o] ----
    h2 P4[8] = {}, P5[8] = {};
#pragma unroll 4
    for (int jp = 0; jp < 16; ++jp) {
        const uint4 a4 = g[256 + jp*4 + 0];   // il0 w4
        const uint4 b4 = g[256 + jp*4 + 1];   // il0 w5
        const uint4 c4 = g[256 + jp*4 + 2];   // il1 w4
        const uint4 d4 = g[256 + jp*4 + 3];   // il1 w5
        const h2 hp = pkrtz(hk[2*jp], hk[2*jp+1]);
        P4[0]=pfma(hp,uh2(a4.x),P4[0]); P4[1]=pfma(hp,uh2(a4.y),P4[1]);
        P4[2]=pfma(hp,uh2(a4.z),P4[2]); P4[3]=pfma(hp,uh2(a4.w),P4[3]);
        P5[0]=pfma(hp,uh2(b4.x),P5[0]); P5[1]=pfma(hp,uh2(b4.y),P5[1]);
        P5[2]=pfma(hp,uh2(b4.z),P5[2]); P5[3]=pfma(hp,uh2(b4.w),P5[3]);
        P4[4]=pfma(hp,uh2(c4.x),P4[4]); P4[5]=pfma(hp,uh2(c4.y),P4[5]);
        P4[6]=pfma(hp,uh2(c4.z),P4[6]); P4[7]=pfma(hp,uh2(c4.w),P4[7]);
        P5[4]=pfma(hp,uh2(d4.x),P5[4]); P5[5]=pfma(hp,uh2(d4.y),P5[5]);
        P5[6]=pfma(hp,uh2(d4.z),P5[6]); P5[7]=pfma(hp,uh2(d4.w),P5[7]);
    }

    // ---- epilogue: per-thread PARTIAL dot, reduce only 2 scalars ----
    const float c7 = 0.70710678118654752f;
    float ds = 0.f, dv = 0.f;
    {
        float qdr[20];
        const float4* rp = (const float4*)(qd + (size_t)rcv * 20);
#pragma unroll
        for (int t = 0; t < 5; ++t) {
            const float4 a = rp[t];
            qdr[4*t+0]=a.x; qdr[4*t+1]=a.y; qdr[4*t+2]=a.z; qdr[4*t+3]=a.w;
        }
#pragma unroll
        for (int o = 0; o < 8; ++o)
            ds += qdr[o] * (sh_s*h2s(K1[o]) + h2s(K2[o]));
        float KV[12] = {};
        {
            const float s0=sh_s*x00, s1=sh_s*x01, s2=sh_s*x02;
            const float cx0=c7*(x01*sh_v[2]-x02*sh_v[1]);
            const float cx1=c7*(x02*sh_v[0]-x00*sh_v[2]);
            const float cx2=c7*(x00*sh_v[1]-x01*sh_v[0]);
#pragma unroll
            for (int o = 0; o < 4; ++o) {
                const float w4 = h2s(P4[o]), w5 = h2s(P5[o]);
                KV[o*3+0] += s0*w4 + cx0*w5;
                KV[o*3+1] += s1*w4 + cx1*w5;
                KV[o*3+2] += s2*w4 + cx2*w5;
            }
        }
        {
            const float s0=sh_s*x10, s1=sh_s*x11, s2=sh_s*x12;
            const float cx0=c7*(x11*sh_v[2]-x12*sh_v[1]);
            const float cx1=c7*(x12*sh_v[0]-x10*sh_v[2]);
            const float cx2=c7*(x10*sh_v[1]-x11*sh_v[0]);
#pragma unroll
            for (int o = 0; o < 4; ++o) {
                const float w4 = h2s(P4[4+o]), w5 = h2s(P5[4+o]);
                KV[o*3+0] += s0*w4 + cx0*w5;
                KV[o*3+1] += s1*w4 + cx1*w5;
                KV[o*3+2] += s2*w4 + cx2*w5;
            }
        }
#pragma unroll
        for (int o = 0; o < 4; ++o) {
            const float k3 = h2s(K3[o]);
#pragma unroll
            for (int c = 0; c < 3; ++c)
                dv += qdr[8 + o*3 + c] * (k3*sh_v[c] + KV[o*3+c]);
        }
    }
    ds = wred4(ds); dv = wred4(dv);

    if (p == 0 && val) {
        const float dot = ds * 4.0343567508008e-3f + dv * 2.0171788261497e-3f;
        const float sa = __expf(0.5f * dot);
        exbuf[pos] = sa*sa; sabuf[e] = sa; posbuf[e] = pos;
    }
}

// ===================== edge_v_a: V scalar outputs (cols [0,384)) =====================
// LDS: 4 x 385 uint4 = 24640 B (stride 6160 B, %128==16 -> conflict-free).
// Per-group uint4 map (round 9): [0,256): w1 idx j*8 + ip*4 + h(0..3),
// half2=(i0,i0+1), outs 4h..; [256,384): w2 idx 256 + j*4 + h, half2=(2p,2p+1).
__global__ __launch_bounds__(BS) void edge_v_a(
    const float* __restrict__ node_ft,
    const int*   __restrict__ ei,
    const float* __restrict__ edge_sh,
    const float* __restrict__ edge_scalars,
    const float* __restrict__ fcv_w1,
    const float* __restrict__ fcv_w2,
    const float* __restrict__ sabuf,
    const int*   __restrict__ posbuf,
    float* __restrict__ vbuf,               // [E,40]
    const int* __restrict__ flag,
    int E)
{
    __shared__ uint4 sa4[4 * 385];          // 24640 B

    const int tid = threadIdx.x;
    for (int idx = tid; idx < 4 * 384; idx += BS) {
        const int p = idx / 384;
        const int local = idx - p * 384;
        const float* s0;
        const float* s1;
        if (local < 256) {                           // w1
            const int j = local >> 3, rr = local & 7, ip = rr >> 2, h = rr & 3;
            const int i0 = 4*p + 2*ip;
            s0 = fcv_w2 + j*640 + i0*16 + h*4;
            s1 = s0 + 16;
        } else {                                     // w2
            const int l = local - 256; const int j = l >> 2, h = l & 3;
            const int i0 = 2*p;
            s0 = fcv_w2 + j*640 + 256 + i0*16 + h*4;
            s1 = s0 + 16;
        }
        sa4[p * 385 + local] = make_uint4(
            pk2h(s0[0], s1[0]), pk2h(s0[1], s1[1]),
            pk2h(s0[2], s1[2]), pk2h(s0[3], s1[3]));
    }

    const int lane = tid & 63;
    const int p = lane >> 4;
    const int q = lane & 15;
    const int w = tid >> 6;
    const int e = blockIdx.x * EPB + w * 16 + q;
    const bool val = (e < E);
    const int ec = val ? e : (E - 1);

    const int is64 = *flag;
    const int snd = is64 ? ei[2*ec] : ei[ec];

    const float4 s4 = *(const float4*)(edge_sh + (size_t)ec * 4);

    const float* nf = node_ft + (size_t)snd * 40;

    __syncthreads();

    float hv[32];
    {
        float es[16];
        const float4* a0 = (const float4*)(edge_scalars + (size_t)ec * 16);
#pragma unroll
        for (int t = 0; t < 4; ++t) {
            const float4 v = a0[t];
            es[4*t+0]=v.x; es[4*t+1]=v.y; es[4*t+2]=v.z; es[4*t+3]=v.w;
        }
#pragma unroll 8
        for (int j = 0; j < 32; ++j) {
            float a = 0.f;
#pragma unroll
            for (int t = 0; t < 16; ++t) a += es[t] * fcv_w1[t*32 + j];
            hv[j] = silu_f(a * 0.25f);
        }
    }

    const uint4* g = sa4 + p * 385;

    // packs: shs folded into xs; pv pack for w2
    const h2 xs01 = pkrtz(nf[4*p + 0]*s4.x, nf[4*p + 1]*s4.x);
    const h2 xs23 = pkrtz(nf[4*p + 2]*s4.x, nf[4*p + 3]*s4.x);
    const float c3 = 0.57735026918962576f;
    const h2 pvp = pkrtz(
        (nf[16+6*p]*s4.y + nf[17+6*p]*s4.z + nf[18+6*p]*s4.w) * c3,
        (nf[19+6*p]*s4.y + nf[20+6*p]*s4.z + nf[21+6*p]*s4.w) * c3);

    h2 Aa[16] = {};
#pragma unroll 4
    for (int j = 0; j < 32; ++j) {
        const uint4* gw = g + j*8;
        const uint4 a0 = gw[0], a1 = gw[1], a2 = gw[2], a3 = gw[3];   // ip0
        const uint4 b0 = gw[4], b1 = gw[5], b2 = gw[6], b3 = gw[7];   // ip1
        const uint4* g2 = g + 256 + j*4;
        const uint4 u0 = g2[0], u1 = g2[1], u2 = g2[2], u3 = g2[3];
        const h2 hh = pkrtz(hv[j], hv[j]);
        const h2 t01 = hh * xs01, t23 = hh * xs23, tp = hh * pvp;
        Aa[0] =pfma(t01,uh2(a0.x),Aa[0]);  Aa[0] =pfma(t23,uh2(b0.x),Aa[0]);  Aa[0] =pfma(tp,uh2(u0.x),Aa[0]);
        Aa[1] =pfma(t01,uh2(a0.y),Aa[1]);  Aa[1] =pfma(t23,uh2(b0.y),Aa[1]);  Aa[1] =pfma(tp,uh2(u0.y),Aa[1]);
        Aa[2] =pfma(t01,uh2(a0.z),Aa[2]);  Aa[2] =pfma(t23,uh2(b0.z),Aa[2]);  Aa[2] =pfma(tp,uh2(u0.z),Aa[2]);
        Aa[3] =pfma(t01,uh2(a0.w),Aa[3]);  Aa[3] =pfma(t23,uh2(b0.w),Aa[3]);  Aa[3] =pfma(tp,uh2(u0.w),Aa[3]);
        Aa[4] =pfma(t01,uh2(a1.x),Aa[4]);  Aa[4] =pfma(t23,uh2(b1.x),Aa[4]);  Aa[4] =pfma(tp,uh2(u1.x),Aa[4]);
        Aa[5] =pfma(t01,uh2(a1.y),Aa[5]);  Aa[5] =pfma(t23,uh2(b1.y),Aa[5]);  Aa[5] =pfma(tp,uh2(u1.y),Aa[5]);
        Aa[6] =pfma(t01,uh2(a1.z),Aa[6]);  Aa[6] =pfma(t23,uh2(b1.z),Aa[6]);  Aa[6] =pfma(tp,uh2(u1.z),Aa[6]);
        Aa[7] =pfma(t01,uh2(a1.w),Aa[7]);  Aa[7] =pfma(t23,uh2(b1.w),Aa[7]);  Aa[7] =pfma(tp,uh2(u1.w),Aa[7]);
        Aa[8] =pfma(t01,uh2(a2.x),Aa[8]);  Aa[8] =pfma(t23,uh2(b2.x),Aa[8]);  Aa[8] =pfma(tp,uh2(u2.x),Aa[8]);
        Aa[9] =pfma(t01,uh2(a2.y),Aa[9]);  Aa[9] =pfma(t23,uh2(b2.y),Aa[9]);  Aa[9] =pfma(tp,uh2(u2.y),Aa[9]);
        Aa[10]=pfma(t01,uh2(a2.z),Aa[10]); Aa[10]=pfma(t23,uh2(b2.z),Aa[10]); Aa[10]=pfma(tp,uh2(u2.z),Aa[10]);
        Aa[11]=pfma(t01,uh2(a2.w),Aa[11]); Aa[11]=pfma(t23,uh2(b2.w),Aa[11]); Aa[11]=pfma(tp,uh2(u2.w),Aa[11]);
        Aa[12]=pfma(t01,uh2(a3.x),Aa[12]); Aa[12]=pfma(t23,uh2(b3.x),Aa[12]); Aa[12]=pfma(tp,uh2(u3.x),Aa[12]);
        Aa[13]=pfma(t01,uh2(a3.y),Aa[13]); Aa[13]=pfma(t23,uh2(b3.y),Aa[13]); Aa[13]=pfma(tp,uh2(u3.y),Aa[13]);
        Aa[14]=pfma(t01,uh2(a3.z),Aa[14]); Aa[14]=pfma(t23,uh2(b3.z),Aa[14]); Aa[14]=pfma(tp,uh2(u3.z),Aa[14]);
        Aa[15]=pfma(t01,uh2(a3.w),Aa[15]); Aa[15]=pfma(t23,uh2(b3.w),Aa[15]); Aa[15]=pfma(tp,uh2(u3.w),Aa[15]);
    }

    float A0[16];
#pragma unroll
    for (int o = 0; o < 16; ++o) A0[o] = wred4(h2s(Aa[o]));

    if (p == 0 && val) {
        const float cs = 0.03608439182435161f;   // (1/sqrt32)*(1/sqrt24)
        const float sa = sabuf[e];
        const int pos = posbuf[e];
        float4* vp = (float4*)(vbuf + (size_t)pos * 40);
#pragma unroll
        for (int t = 0; t < 4; ++t) {
            float4 r;
            r.x = sa * A0[4*t+0] * cs; r.y = sa * A0[4*t+1] * cs;
            r.z = sa * A0[4*t+2] * cs; r.w = sa * A0[4*t+3] * cs;
            vp[t] = r;
        }
    }
}

// ===================== edge_v_b: V vector outputs (cols [384,640)) =====================
// LDS: 4 x 257 uint4 = 16448 B (stride 4112 B, %128==16 -> conflict-free).
// Per-group uint4 map (round 9): [0,128): w3 idx j*4 + ip*2 + h, half2=(i0,i0+1),
// o=4h..; [128,256): w45 idx 128 + (jp*2+il)*4 + h2, half2=(j0,j0+1);
// h2<2 -> w4, else w5, o0=(h2&1)*4.
__global__ __launch_bounds__(BS) void edge_v_b(
    const float* __restrict__ node_ft,
    const int*   __restrict__ ei,
    const float* __restrict__ edge_sh,
    const float* __restrict__ edge_scalars,
    const float* __restrict__ fcv_w1,
    const float* __restrict__ fcv_w2,
    const float* __restrict__ sabuf,
    const int*   __restrict__ posbuf,
    float* __restrict__ vbuf,               // [E,40]
    const int* __restrict__ flag,
    int E)
{
    __shared__ uint4 sb4[4 * 257];          // 16448 B

    const int tid = threadIdx.x;
    for (int idx = tid; idx < 4 * 256; idx += BS) {
        const int p = idx >> 8;
        const int local = idx & 255;
        const float* s0;
        const float* s1;
        if (local < 128) {                           // w3: pair over i
            const int j = local >> 2, rr = local & 3, ip = rr >> 1, h = rr & 1;
            const int i0 = 4*p + 2*ip;
            s0 = fcv_w2 + j*640 + 384 + i0*8 + 4*h;
            s1 = s0 + 8;
        } else {                                     // w45: pair over j
            const int l = local - 128;
            const int jp = l >> 3, rr = l & 7, il = rr >> 2, h2c = rr & 3;
            const int i = 2*p + il, j0 = 2*jp;
            const int base = (h2c < 2) ? 512 : 576;
            s0 = fcv_w2 + j0*640 + base + i*8 + (h2c & 1)*4;
            s1 = s0 + 640;
        }
        sb4[p * 257 + local] = make_uint4(
            pk2h(s0[0], s1[0]), pk2h(s0[1], s1[1]),
            pk2h(s0[2], s1[2]), pk2h(s0[3], s1[3]));
    }

    const int lane = tid & 63;
    const int p = lane >> 4;
    const int q = lane & 15;
    const int w = tid >> 6;
    const int e = blockIdx.x * EPB + w * 16 + q;
    const bool val = (e < E);
    const int ec = val ? e : (E - 1);

    const int is64 = *flag;
    const int snd = is64 ? ei[2*ec] : ei[ec];

    const float4 s4 = *(const float4*)(edge_sh + (size_t)ec * 4);
    const float sh_s = s4.x;
    const float sh_v[3] = {s4.y, s4.z, s4.w};

    const float* nf = node_ft + (size_t)snd * 40;

    __syncthreads();

    float hv[32];
    {
        float es[16];
        const float4* a0 = (const float4*)(edge_scalars + (size_t)ec * 16);
#pragma unroll
        for (int t = 0; t < 4; ++t) {
            const float4 v = a0[t];
            es[4*t+0]=v.x; es[4*t+1]=v.y; es[4*t+2]=v.z; es[4*t+3]=v.w;
        }
#pragma unroll 8
        for (int j = 0; j < 32; ++j) {
            float a = 0.f;
#pragma unroll
            for (int t = 0; t < 16; ++t) a += es[t] * fcv_w1[t*32 + j];
            hv[j] = silu_f(a * 0.25f);
        }
    }

    const uint4* g = sb4 + p * 257;

    const h2 xs01 = pkrtz(nf[4*p + 0], nf[4*p + 1]);
    const h2 xs23 = pkrtz(nf[4*p + 2], nf[4*p + 3]);

    // ---- w3 path ----
    h2 T3[8] = {};
#pragma unroll 4
    for (int j = 0; j < 32; ++j) {
        const uint4 E0 = g[j*4+0], E1 = g[j*4+1];   // ip0: o0..3, o4..7
        const uint4 F0 = g[j*4+2], F1 = g[j*4+3];   // ip1
        const h2 hh = pkrtz(hv[j], hv[j]);
        const h2 t01 = hh * xs01, t23 = hh * xs23;
        T3[0]=pfma(t01,uh2(E0.x),T3[0]); T3[0]=pfma(t23,uh2(F0.x),T3[0]);
        T3[1]=pfma(t01,uh2(E0.y),T3[1]); T3[1]=pfma(t23,uh2(F0.y),T3[1]);
        T3[2]=pfma(t01,uh2(E0.z),T3[2]); T3[2]=pfma(t23,uh2(F0.z),T3[2]);
        T3[3]=pfma(t01,uh2(E0.w),T3[3]); T3[3]=pfma(t23,uh2(F0.w),T3[3]);
        T3[4]=pfma(t01,uh2(E1.x),T3[4]); T3[4]=pfma(t23,uh2(F1.x),T3[4]);
        T3[5]=pfma(t01,uh2(E1.y),T3[5]); T3[5]=pfma(t23,uh2(F1.y),T3[5]);
        T3[6]=pfma(t01,uh2(E1.z),T3[6]); T3[6]=pfma(t23,uh2(F1.z),T3[6]);
        T3[7]=pfma(t01,uh2(E1.w),T3[7]); T3[7]=pfma(t23,uh2(F1.w),T3[7]);
    }

    // ---- w4/w5: contract over j-pairs; P[il*8+o] ----
    h2 P4[16] = {}, P5[16] = {};
#pragma unroll 2
    for (int jp = 0; jp < 16; ++jp) {
        const uint4* gw = g + 128 + jp*8;
        const uint4 a4 = gw[0], b4 = gw[1];   // il0 w4 o0-3, o4-7
        const uint4 c4 = gw[2], d4 = gw[3];   // il0 w5
        const uint4 e4 = gw[4], f4 = gw[5];   // il1 w4
        const uint4 m4 = gw[6], n4 = gw[7];   // il1 w5
        const h2 hp = pkrtz(hv[2*jp], hv[2*jp+1]);
        P4[0] =pfma(hp,uh2(a4.x),P4[0]);  P4[1] =pfma(hp,uh2(a4.y),P4[1]);
        P4[2] =pfma(hp,uh2(a4.z),P4[2]);  P4[3] =pfma(hp,uh2(a4.w),P4[3]);
        P4[4] =pfma(hp,uh2(b4.x),P4[4]);  P4[5] =pfma(hp,uh2(b4.y),P4[5]);
        P4[6] =pfma(hp,uh2(b4.z),P4[6]);  P4[7] =pfma(hp,uh2(b4.w),P4[7]);
        P5[0] =pfma(hp,uh2(c4.x),P5[0]);  P5[1] =pfma(hp,uh2(c4.y),P5[1]);
        P5[2] =pfma(hp,uh2(c4.z),P5[2]);  P5[3] =pfma(hp,uh2(c4.w),P5[3]);
        P5[4] =pfma(hp,uh2(d4.x),P5[4]);  P5[5] =pfma(hp,uh2(d4.y),P5[5]);
        P5[6] =pfma(hp,uh2(d4.z),P5[6]);  P5[7] =pfma(hp,uh2(d4.w),P5[7]);
        P4[8] =pfma(hp,uh2(e4.x),P4[8]);  P4[9] =pfma(hp,uh2(e4.y),P4[9]);
        P4[10]=pfma(hp,uh2(e4.z),P4[10]); P4[11]=pfma(hp,uh2(e4.w),P4[11]);
        P4[12]=pfma(hp,uh2(f4.x),P4[12]); P4[13]=pfma(hp,uh2(f4.y),P4[13]);
        P4[14]=pfma(hp,uh2(f4.z),P4[14]); P4[15]=pfma(hp,uh2(f4.w),P4[15]);
        P5[8] =pfma(hp,uh2(m4.x),P5[8]);  P5[9] =pfma(hp,uh2(m4.y),P5[9]);
        P5[10]=pfma(hp,uh2(m4.z),P5[10]); P5[11]=pfma(hp,uh2(m4.w),P5[11]);
        P5[12]=pfma(hp,uh2(n4.x),P5[12]); P5[13]=pfma(hp,uh2(n4.y),P5[13]);
        P5[14]=pfma(hp,uh2(n4.z),P5[14]); P5[15]=pfma(hp,uh2(n4.w),P5[15]);
    }

    // ---- epilogue: per-thread partial R/T3, reduce, p==0 writes ----
    const float c7 = 0.70710678118654752f;
    float R[24], T3f[8];
    {
        float acc[24];
#pragma unroll
        for (int o = 0; o < 24; ++o) acc[o] = 0.f;
        {
            const float x0 = nf[16 + 6*p], x1 = nf[17 + 6*p], x2 = nf[18 + 6*p];
            const float s0 = sh_s*x0, s1 = sh_s*x1, s2 = sh_s*x2;
            const float cx0 = c7*(x1*sh_v[2] - x2*sh_v[1]);
            const float cx1 = c7*(x2*sh_v[0] - x0*sh_v[2]);
            const float cx2 = c7*(x0*sh_v[1] - x1*sh_v[0]);
#pragma unroll
            for (int o = 0; o < 8; ++o) {
                const float w4 = h2s(P4[o]), w5 = h2s(P5[o]);
                acc[o*3+0] += s0*w4 + cx0*w5;
                acc[o*3+1] += s1*w4 + cx1*w5;
                acc[o*3+2] += s2*w4 + cx2*w5;
            }
        }
        {
            const float x0 = nf[19 + 6*p], x1 = nf[20 + 6*p], x2 = nf[21 + 6*p];
            const float s0 = sh_s*x0, s1 = sh_s*x1, s2 = sh_s*x2;
            const float cx0 = c7*(x1*sh_v[2] - x2*sh_v[1]);
            const float cx1 = c7*(x2*sh_v[0] - x0*sh_v[2]);
            const float cx2 = c7*(x0*sh_v[1] - x1*sh_v[0]);
#pragma unroll
            for (int o = 0; o < 8; ++o) {
                const float w4 = h2s(P4[8+o]), w5 = h2s(P5[8+o]);
                acc[o*3+0] += s0*w4 + cx0*w5;
                acc[o*3+1] += s1*w4 + cx1*w5;
                acc[o*3+2] += s2*w4 + cx2*w5;
            }
        }
#pragma unroll
        for (int o = 0; o < 24; ++o) R[o] = wred4(acc[o]);
    }
#pragma unroll
    for (int o = 0; o < 8; ++o) T3f[o] = wred4(h2s(T3[o]));

    if (p == 0 && val) {
        const float sc = 0.03125f;               // (1/sqrt32)*(1/sqrt32)
        const float sa = sabuf[e];
        const int pos = posbuf[e];
        float row[24];
#pragma unroll
        for (int o = 0; o < 8; ++o)
#pragma unroll
            for (int c = 0; c < 3; ++c)
                row[o*3+c] = sa * (T3f[o]*sh_v[c] + R[o*3+c]) * sc;
        float4* vp = (float4*)(vbuf + (size_t)pos * 40 + 16);
#pragma unroll
        for (int t = 0; t < 6; ++t) {
            float4 r; r.x = row[4*t+0]; r.y = row[4*t+1]; r.z = row[4*t+2]; r.w = row[4*t+3];
            vp[t] = r;
        }
    }
}

__global__ __launch_bounds__(256) void node_reduce(
    const int*   __restrict__ start,
    const float* __restrict__ exbuf,
    const float* __restrict__ vbuf,
    float* __restrict__ out, int N)
{
    const int wave = threadIdx.x >> 6;
    const int lane = threadIdx.x & 63;
    const int n = blockIdx.x * 4 + wave;
    if (n >= N) return;
    const int r0 = start[n], r1 = start[n + 1];
    float z = 0.f, comp = 0.f;
    for (int r = r0; r < r1; ++r) {
        z += exbuf[r];
        if (lane < 40) comp += vbuf[(size_t)r * 40 + lane];
    }
    if (lane < 40)
        out[(size_t)n * 40 + lane] = (z > 0.f) ? comp * rsqrtf(z) : 0.f;
}

extern "C" void kernel_launch(void* const* d_in, const int* in_sizes, int n_in,
                              void* d_out, int out_size, void* d_ws, size_t ws_size,
                              hipStream_t stream) {
    const float* node_ft      = (const float*)d_in[0];
    const int*   edge_index   = (const int*)  d_in[1];
    const float* edge_sh      = (const float*)d_in[2];
    const float* edge_scalars = (const float*)d_in[3];
    const float* w_q_s        = (const float*)d_in[4];
    const float* w_q_v        = (const float*)d_in[5];
    const float* fck_w1       = (const float*)d_in[6];
    const float* fck_w2       = (const float*)d_in[7];
    const float* fcv_w1       = (const float*)d_in[8];
    const float* fcv_w2       = (const float*)d_in[9];
    const float* wdot_s       = (const float*)d_in[10];
    const float* wdot_v       = (const float*)d_in[11];

    const int N = in_sizes[0] / 40;
    const int E = in_sizes[2] / 4;

    float* ws    = (float*)d_ws;
    float* qd    = ws;                               // N*20
    int*   cnt   = (int*)(ws + (size_t)N * 20);      // N
    int*   start = cnt + N;                          // N+1
    int*   curs  = start + N + 1;                    // N
    int*   flg   = curs + N;                         // 1
    size_t off   = (size_t)N * 20 + N + (N + 1) + N + 1;
    off = (off + 3) & ~(size_t)3;                    // 16B align
    float* exbuf  = ws + off;                        // E
    float* sabuf  = exbuf + E;                       // E
    int*   posbuf = (int*)(sabuf + E);               // E
    float* vbuf   = (float*)(posbuf + E);            // E*40 (E%4==0 -> aligned)

    float* out = (float*)d_out;

    const int EB = (E + EPB - 1) / EPB;

    hipLaunchKernelGGL(node_pre, dim3((N + 255) / 256), dim3(256), 0, stream,
                       node_ft, edge_index, w_q_s, w_q_v, wdot_s, wdot_v,
                       qd, cnt, flg, N, E);
    hipLaunchKernelGGL(count_edges, dim3((E + 255) / 256), dim3(256), 0, stream,
                       edge_index, cnt, flg, E);
    hipLaunchKernelGGL(scan_kernel, dim3(1), dim3(1024), 0, stream,
                       cnt, start, curs, N);
    hipLaunchKernelGGL(edge_k, dim3(EB), dim3(BS), 0, stream,
                       node_ft, edge_index, edge_sh, edge_scalars,
                       fck_w1, fck_w2, qd, curs, exbuf, sabuf, posbuf, flg, N, E);
    hipLaunchKernelGGL(edge_v_a, dim3(EB), dim3(BS), 0, stream,
                       node_ft, edge_index, edge_sh, edge_scalars,
                       fcv_w1, fcv_w2, sabuf, posbuf, vbuf, flg, E);
    hipLaunchKernelGGL(edge_v_b, dim3(EB), dim3(BS), 0, stream,
                       node_ft, edge_index, edge_sh, edge_scalars,
                       fcv_w1, fcv_w2, sabuf, posbuf, vbuf, flg, E);
    hipLaunchKernelGGL(node_reduce, dim3((N + 3) / 4), dim3(256), 0, stream,
                       start, exbuf, vbuf, out, N);
}

// Round 10
// 269.093 us; speedup vs baseline: 1.9545x; 1.0002x over previous
//
#include <hip/hip_runtime.h>

// GraphAttention (e3nn-style) on MI355X — Round 14: fused edge pipeline
// (identical to round 13; that bench died to an infra failure, not the kernel).
// Round-12 post-mortem: 269us best; edge kernels sum ~173us, but ~95us is
// OUTSIDE them: 7 launches (~10us gaps), hv computed twice, node/sh/es loaded
// 3x, sabuf/posbuf global round-trip. Fix: one edge_all kernel with 3 phases
// (K | Va | Vb), re-staging weights into ONE 24640B LDS buffer per phase
// (keeps 6 blocks/CU; a 61KB union would drop to 2 -> round-11 latency trap).
// sa/pos live in registers across phases; hv computed once. node_pre+count
// fused (cnt zeroed via hipMemsetAsync; is64 derived per-wave). 7 -> 5 stream
// ops. All inner loops are byte-identical copies of round-12's verified ones.
//
// Dims: M0=16 M1=8 Q0=8 Q1=4 O0=16 O1=8 EDGE_BASIS=16 HIDDEN=32
// TPK [32][320]: w1[0,128) w2[128,192) w3[192,256) w4[256,288) w5[288,320)
// TPV [32][640]: w1[0,256) w2[256,384) w3[384,512) w4[512,576) w5[576,640)
//
// ws (4B units): qd[N*20] | cnt[N] | start[N+1] | cursor[N] | flag | pad |
//                exbuf[E] | vbuf[E*40]

#define BS 256           // threads per block (edge kernel): 4 waves
#define EPB 64           // edges per block: 4 waves x 16 q-lanes x 1 edge

typedef _Float16 h2 __attribute__((ext_vector_type(2)));

__device__ __forceinline__ float silu_f(float x) {
    return x * (1.0f / (1.0f + __expf(-x)));
}
__device__ __forceinline__ unsigned short f2h(float f) {   // f32 -> f16 RNE
    return __builtin_bit_cast(unsigned short, (_Float16)f);
}
__device__ __forceinline__ unsigned pk2h(float a, float b) { // pack 2 f16 (RNE)
    return (unsigned)f2h(a) | ((unsigned)f2h(b) << 16);
}
__device__ __forceinline__ h2 uh2(unsigned u) {
    return __builtin_bit_cast(h2, u);
}
__device__ __forceinline__ h2 pkrtz(float a, float b) {    // v_cvt_pkrtz_f16_f32
    return __builtin_bit_cast(h2, __builtin_amdgcn_cvt_pkrtz(a, b));
}
__device__ __forceinline__ h2 pfma(h2 a, h2 b, h2 c) {     // v_pk_fma_f16
    return __builtin_elementwise_fma(a, b, c);
}
__device__ __forceinline__ float h2s(h2 a) {               // lo+hi in f32
    return (float)a[0] + (float)a[1];
}
__device__ __forceinline__ float wred4(float v) {          // sum over 4 p-groups
    v += __shfl_xor(v, 16);
    v += __shfl_xor(v, 32);
    return v;
}

// ===================== pre_count: node precompute + edge degree count ==========
// cnt must be zeroed (hipMemsetAsync) before this kernel. is64 derived per-wave.
__global__ __launch_bounds__(256) void pre_count(
    const float* __restrict__ node_ft,
    const int*   __restrict__ ei,
    const float* __restrict__ w_q_s, const float* __restrict__ w_q_v,
    const float* __restrict__ wdot_s, const float* __restrict__ wdot_v,
    float* __restrict__ qd, int* __restrict__ cnt, int* __restrict__ flag,
    int N, int E)
{
    const int gid = blockIdx.x * blockDim.x + threadIdx.x;

    int acc = 0;
    if ((threadIdx.x & 63) == 0) {
        const int kmax = (E < 64) ? E : 64;
        for (int k = 0; k < kmax; ++k) acc |= ei[2*k + 1];
    }
    acc = __shfl(acc, 0, 64);
    const int is64 = (acc == 0) ? 1 : 0;   // int64 layout => odd words all zero
    if (gid == 0) *flag = is64;

    if (gid < E) {
        const int rcv = is64 ? ei[2*(E + gid)] : ei[E + gid];
        atomicAdd(cnt + rcv, 1);
    }

    const int n = gid;
    if (n >= N) return;

    const float* nf = node_ft + (size_t)n * 40;
    float xs[16];
#pragma unroll
    for (int i = 0; i < 16; ++i) xs[i] = nf[i];
    float qv0[8];
#pragma unroll
    for (int o = 0; o < 8; ++o) {
        float a = 0.f;
#pragma unroll
        for (int i = 0; i < 16; ++i) a += xs[i] * w_q_s[i*8 + o];
        qv0[o] = a * 0.25f;
    }
    float* qdn = qd + (size_t)n * 20;
#pragma unroll
    for (int j = 0; j < 8; ++j) {
        float a = 0.f;
#pragma unroll
        for (int i = 0; i < 8; ++i) a += qv0[i] * wdot_s[i*8 + j];
        qdn[j] = a;
    }
    float xv[8][3];
#pragma unroll
    for (int i = 0; i < 8; ++i)
#pragma unroll
        for (int c = 0; c < 3; ++c) xv[i][c] = nf[16 + i*3 + c];
    float qv[4][3];
#pragma unroll
    for (int o = 0; o < 4; ++o)
#pragma unroll
        for (int c = 0; c < 3; ++c) {
            float a = 0.f;
#pragma unroll
            for (int i = 0; i < 8; ++i) a += xv[i][c] * w_q_v[i*4 + o];
            qv[o][c] = a * 0.35355339059327379f;
        }
#pragma unroll
    for (int j = 0; j < 4; ++j)
#pragma unroll
        for (int c = 0; c < 3; ++c) {
            float a = 0.f;
#pragma unroll
            for (int i = 0; i < 4; ++i) a += qv[i][c] * wdot_v[i*4 + j];
            qdn[8 + j*3 + c] = a;
        }
}

// 1 block, 1024 threads; shuffle-based scan (few barriers).
__global__ __launch_bounds__(1024) void scan_kernel(
    const int* __restrict__ cnt, int* __restrict__ start,
    int* __restrict__ cursor, int N)
{
    __shared__ int wsum[16];
    __shared__ int s_carry;
    const int tid = threadIdx.x, wave = tid >> 6, lane = tid & 63;
    if (tid == 0) s_carry = 0;
    __syncthreads();
    for (int base = 0; base < N; base += 1024) {
        const int i = base + tid;
        const int v = (i < N) ? cnt[i] : 0;
        int x = v;                                  // inclusive intra-wave scan
#pragma unroll
        for (int d = 1; d < 64; d <<= 1) {
            const int y = __shfl_up(x, d, 64);
            if (lane >= d) x += y;
        }
        if (lane == 63) wsum[wave] = x;
        __syncthreads();
        if (wave == 0 && lane < 16) {
            int w = wsum[lane];
#pragma unroll
            for (int d = 1; d < 16; d <<= 1) {
                const int y = __shfl_up(w, d, 64);
                if (lane >= d) w += y;              // lanes 16..63 inactive
            }
            wsum[lane] = w;                         // inclusive wave-prefix
        }
        __syncthreads();
        const int woff = (wave == 0) ? 0 : wsum[wave - 1];
        const int carry = s_carry;
        if (i < N) {
            const int s = carry + woff + x - v;     // exclusive
            start[i] = s;
            cursor[i] = s;
        }
        __syncthreads();
        if (tid == 0) s_carry = carry + wsum[15];
        __syncthreads();
    }
    if (tid == 0) start[N] = s_carry;
}

// ===================== edge_all: K + Va + Vb fused =====================
// One 24640B LDS buffer, re-staged per phase (layouts identical to round 12):
//  K  (stride 321): [0,128) w1 | [128,192) w3 | [192,256) w2 | [256,320) w45
//  Va (stride 385): [0,256) w1 | [256,384) w2
//  Vb (stride 257): [0,128) w3 | [128,256) w45
// All group strides %128==16 -> 4 concurrent group reads on disjoint bank quads.
// No early returns (5 barriers); tail edges clamped + val-guarded.
__global__ __launch_bounds__(BS) void edge_all(
    const float* __restrict__ node_ft,
    const int*   __restrict__ ei,
    const float* __restrict__ edge_sh,
    const float* __restrict__ edge_scalars,
    const float* __restrict__ fck_w1,
    const float* __restrict__ fck_w2,
    const float* __restrict__ fcv_w1,
    const float* __restrict__ fcv_w2,
    const float* __restrict__ qd,
    int*   __restrict__ cursor,
    float* __restrict__ exbuf,              // [E] CSR order
    float* __restrict__ vbuf,               // [E,40] CSR order
    const int* __restrict__ flag,
    int N, int E)
{
    __shared__ uint4 swz[4 * 385];          // 24640 B (max of 3 phase layouts)

    const int tid = threadIdx.x;
    const int lane = tid & 63;
    const int p = lane >> 4;
    const int q = lane & 15;
    const int w = tid >> 6;
    const int e = blockIdx.x * EPB + w * 16 + q;
    const bool val = (e < E);
    const int ec = val ? e : (E - 1);

    const int is64 = *flag;
    const int snd = is64 ? ei[2*ec]       : ei[ec];
    const int rcv = is64 ? ei[2*(E + ec)] : ei[E + ec];

    int pos = 0;
    if (p == 0 && val) pos = atomicAdd(cursor + rcv, 1);  // one claimant/edge

    const float4 s4 = *(const float4*)(edge_sh + (size_t)ec * 4);
    const float sh_s = s4.x;
    const float sh_v[3] = {s4.y, s4.z, s4.w};
    const float* nf = node_ft + (size_t)snd * 40;
    const float c3 = 0.57735026918962576f;
    const float c7 = 0.70710678118654752f;

    float es[16];
    {
        const float4* a0 = (const float4*)(edge_scalars + (size_t)ec * 16);
#pragma unroll
        for (int t = 0; t < 4; ++t) {
            const float4 v = a0[t];
            es[4*t+0]=v.x; es[4*t+1]=v.y; es[4*t+2]=v.z; es[4*t+3]=v.w;
        }
    }

    // ================= stage K weights =================
    for (int idx = tid; idx < 4 * 320; idx += BS) {
        const int pg = idx / 320;
        const int local = idx - pg * 320;
        unsigned r0, r1, r2, r3;
        if (local < 128) {                       // w1: pair over i, 4 outs
            const int j = local >> 2, rr = local & 3, ip = rr >> 1, h = rr & 1;
            const int i0 = 4*pg + 2*ip;
            const float* s0 = fck_w2 + j*320 + i0*8 + 4*h;
            const float* s1 = s0 + 8;
            r0 = pk2h(s0[0], s1[0]); r1 = pk2h(s0[1], s1[1]);
            r2 = pk2h(s0[2], s1[2]); r3 = pk2h(s0[3], s1[3]);
        } else if (local < 192) {                // w3: pair over i, 4 outs
            const int l = local - 128; const int j = l >> 1, ip = l & 1;
            const int i0 = 4*pg + 2*ip;
            const float* s0 = fck_w2 + j*320 + 192 + i0*4;
            const float* s1 = s0 + 4;
            r0 = pk2h(s0[0], s1[0]); r1 = pk2h(s0[1], s1[1]);
            r2 = pk2h(s0[2], s1[2]); r3 = pk2h(s0[3], s1[3]);
        } else if (local < 256) {                // w2: pair over i=(2pg,2pg+1)
            const int l = local - 192; const int j = l >> 1, h = l & 1;
            const int i0 = 2*pg;
            const float* s0 = fck_w2 + j*320 + 128 + i0*8 + 4*h;
            const float* s1 = s0 + 8;
            r0 = pk2h(s0[0], s1[0]); r1 = pk2h(s0[1], s1[1]);
            r2 = pk2h(s0[2], s1[2]); r3 = pk2h(s0[3], s1[3]);
        } else {                                 // w45: pair over j=(2jp,2jp+1)
            const int l = local - 256; const int jp = l >> 2, rr = l & 3;
            const int il = rr >> 1, h = rr & 1;
            const int i = 2*pg + il, j0 = 2*jp;
            const int col = (h == 0 ? 256 : 288) + i*4;
            const float* s0 = fck_w2 + j0*320 + col;
            const float* s1 = s0 + 320;
            r0 = pk2h(s0[0], s1[0]); r1 = pk2h(s0[1], s1[1]);
            r2 = pk2h(s0[2], s1[2]); r3 = pk2h(s0[3], s1[3]);
        }
        swz[pg * 321 + local] = make_uint4(r0, r1, r2, r3);
    }
    __syncthreads();

    // ---- hk net + K phase ----
    float sa = 0.f;
    {
        float hk[32];
#pragma unroll 8
        for (int j = 0; j < 32; ++j) {
            float a = 0.f;
#pragma unroll
            for (int t = 0; t < 16; ++t) a += es[t] * fck_w1[t*32 + j];
            hk[j] = silu_f(a * 0.25f);
        }

        const uint4* g = swz + p * 321;

        const h2 xs01 = pkrtz(nf[4*p + 0], nf[4*p + 1]);
        const h2 xs23 = pkrtz(nf[4*p + 2], nf[4*p + 3]);
        const float x00 = nf[16 + 6*p], x01 = nf[17 + 6*p], x02 = nf[18 + 6*p];
        const float x10 = nf[19 + 6*p], x11 = nf[20 + 6*p], x12 = nf[21 + 6*p];
        const h2 pvp = pkrtz((x00*sh_v[0] + x01*sh_v[1] + x02*sh_v[2]) * c3,
                             (x10*sh_v[0] + x11*sh_v[1] + x12*sh_v[2]) * c3);

        h2 K1[8] = {}, K3[4] = {}, K2[8] = {};
#pragma unroll 4
        for (int j = 0; j < 32; ++j) {
            const uint4 A = g[j*4+0], B = g[j*4+1], C = g[j*4+2], D = g[j*4+3];
            const uint4 Ea = g[128 + j*2], Fb = g[128 + j*2 + 1];
            const uint4 U = g[192 + j*2], V = g[192 + j*2 + 1];
            const h2 hh = pkrtz(hk[j], hk[j]);
            const h2 t01 = hh * xs01, t23 = hh * xs23, tp = hh * pvp;
            K1[0]=pfma(t01,uh2(A.x),K1[0]); K1[0]=pfma(t23,uh2(C.x),K1[0]);
            K1[1]=pfma(t01,uh2(A.y),K1[1]); K1[1]=pfma(t23,uh2(C.y),K1[1]);
            K1[2]=pfma(t01,uh2(A.z),K1[2]); K1[2]=pfma(t23,uh2(C.z),K1[2]);
            K1[3]=pfma(t01,uh2(A.w),K1[3]); K1[3]=pfma(t23,uh2(C.w),K1[3]);
            K1[4]=pfma(t01,uh2(B.x),K1[4]); K1[4]=pfma(t23,uh2(D.x),K1[4]);
            K1[5]=pfma(t01,uh2(B.y),K1[5]); K1[5]=pfma(t23,uh2(D.y),K1[5]);
            K1[6]=pfma(t01,uh2(B.z),K1[6]); K1[6]=pfma(t23,uh2(D.z),K1[6]);
            K1[7]=pfma(t01,uh2(B.w),K1[7]); K1[7]=pfma(t23,uh2(D.w),K1[7]);
            K3[0]=pfma(t01,uh2(Ea.x),K3[0]); K3[0]=pfma(t23,uh2(Fb.x),K3[0]);
            K3[1]=pfma(t01,uh2(Ea.y),K3[1]); K3[1]=pfma(t23,uh2(Fb.y),K3[1]);
            K3[2]=pfma(t01,uh2(Ea.z),K3[2]); K3[2]=pfma(t23,uh2(Fb.z),K3[2]);
            K3[3]=pfma(t01,uh2(Ea.w),K3[3]); K3[3]=pfma(t23,uh2(Fb.w),K3[3]);
            K2[0]=pfma(tp,uh2(U.x),K2[0]); K2[1]=pfma(tp,uh2(U.y),K2[1]);
            K2[2]=pfma(tp,uh2(U.z),K2[2]); K2[3]=pfma(tp,uh2(U.w),K2[3]);
            K2[4]=pfma(tp,uh2(V.x),K2[4]); K2[5]=pfma(tp,uh2(V.y),K2[5]);
            K2[6]=pfma(tp,uh2(V.z),K2[6]); K2[7]=pfma(tp,uh2(V.w),K2[7]);
        }

        h2 P4[8] = {}, P5[8] = {};
#pragma unroll 4
        for (int jp = 0; jp < 16; ++jp) {
            const uint4 a4 = g[256 + jp*4 + 0];   // il0 w4
            const uint4 b4 = g[256 + jp*4 + 1];   // il0 w5
            const uint4 c4 = g[256 + jp*4 + 2];   // il1 w4
            const uint4 d4 = g[256 + jp*4 + 3];   // il1 w5
            const h2 hp = pkrtz(hk[2*jp], hk[2*jp+1]);
            P4[0]=pfma(hp,uh2(a4.x),P4[0]); P4[1]=pfma(hp,uh2(a4.y),P4[1]);
            P4[2]=pfma(hp,uh2(a4.z),P4[2]); P4[3]=pfma(hp,uh2(a4.w),P4[3]);
            P5[0]=pfma(hp,uh2(b4.x),P5[0]); P5[1]=pfma(hp,uh2(b4.y),P5[1]);
            P5[2]=pfma(hp,uh2(b4.z),P5[2]); P5[3]=pfma(hp,uh2(b4.w),P5[3]);
            P4[4]=pfma(hp,uh2(c4.x),P4[4]); P4[5]=pfma(hp,uh2(c4.y),P4[5]);
            P4[6]=pfma(hp,uh2(c4.z),P4[6]); P4[7]=pfma(hp,uh2(c4.w),P4[7]);
            P5[4]=pfma(hp,uh2(d4.x),P5[4]); P5[5]=pfma(hp,uh2(d4.y),P5[5]);
            P5[6]=pfma(hp,uh2(d4.z),P5[6]); P5[7]=pfma(hp,uh2(d4.w),P5[7]);
        }

        float ds = 0.f, dv = 0.f;
        {
            float qdr[20];
            const float4* rp = (const float4*)(qd + (size_t)rcv * 20);
#pragma unroll
            for (int t = 0; t < 5; ++t) {
                const float4 a = rp[t];
                qdr[4*t+0]=a.x; qdr[4*t+1]=a.y; qdr[4*t+2]=a.z; qdr[4*t+3]=a.w;
            }
#pragma unroll
            for (int o = 0; o < 8; ++o)
                ds += qdr[o] * (sh_s*h2s(K1[o]) + h2s(K2[o]));
            float KV[12] = {};
            {
                const float s0=sh_s*x00, s1=sh_s*x01, s2=sh_s*x02;
                const float cx0=c7*(x01*sh_v[2]-x02*sh_v[1]);
                const float cx1=c7*(x02*sh_v[0]-x00*sh_v[2]);
                const float cx2=c7*(x00*sh_v[1]-x01*sh_v[0]);
#pragma unroll
                for (int o = 0; o < 4; ++o) {
                    const float w4 = h2s(P4[o]), w5 = h2s(P5[o]);
                    KV[o*3+0] += s0*w4 + cx0*w5;
                    KV[o*3+1] += s1*w4 + cx1*w5;
                    KV[o*3+2] += s2*w4 + cx2*w5;
                }
            }
            {
                const float s0=sh_s*x10, s1=sh_s*x11, s2=sh_s*x12;
                const float cx0=c7*(x11*sh_v[2]-x12*sh_v[1]);
                const float cx1=c7*(x12*sh_v[0]-x10*sh_v[2]);
                const float cx2=c7*(x10*sh_v[1]-x11*sh_v[0]);
#pragma unroll
                for (int o = 0; o < 4; ++o) {
                    const float w4 = h2s(P4[4+o]), w5 = h2s(P5[4+o]);
                    KV[o*3+0] += s0*w4 + cx0*w5;
                    KV[o*3+1] += s1*w4 + cx1*w5;
                    KV[o*3+2] += s2*w4 + cx2*w5;
                }
            }
#pragma unroll
            for (int o = 0; o < 4; ++o) {
                const float k3 = h2s(K3[o]);
#pragma unroll
                for (int c = 0; c < 3; ++c)
                    dv += qdr[8 + o*3 + c] * (k3*sh_v[c] + KV[o*3+c]);
            }
        }
        ds = wred4(ds); dv = wred4(dv);

        if (p == 0 && val) {
            const float dot = ds * 4.0343567508008e-3f + dv * 2.0171788261497e-3f;
            sa = __expf(0.5f * dot);
            exbuf[pos] = sa * sa;
        }
    }

    // ================= stage Va weights =================
    __syncthreads();                         // all K reads complete
    for (int idx = tid; idx < 4 * 384; idx += BS) {
        const int pg = idx / 384;
        const int local = idx - pg * 384;
        const float* s0;
        const float* s1;
        if (local < 256) {                           // w1
            const int j = local >> 3, rr = local & 7, ip = rr >> 2, h = rr & 3;
            const int i0 = 4*pg + 2*ip;
            s0 = fcv_w2 + j*640 + i0*16 + h*4;
            s1 = s0 + 16;
        } else {                                     // w2
            const int l = local - 256; const int j = l >> 2, h = l & 3;
            const int i0 = 2*pg;
            s0 = fcv_w2 + j*640 + 256 + i0*16 + h*4;
            s1 = s0 + 16;
        }
        swz[pg * 385 + local] = make_uint4(
            pk2h(s0[0], s1[0]), pk2h(s0[1], s1[1]),
            pk2h(s0[2], s1[2]), pk2h(s0[3], s1[3]));
    }
    __syncthreads();

    // ---- hv net (es still live; hv spans Va and Vb) ----
    float hv[32];
#pragma unroll 8
    for (int j = 0; j < 32; ++j) {
        float a = 0.f;
#pragma unroll
        for (int t = 0; t < 16; ++t) a += es[t] * fcv_w1[t*32 + j];
        hv[j] = silu_f(a * 0.25f);
    }

    // ================= Va phase =================
    {
        const uint4* g = swz + p * 385;

        const h2 xs01 = pkrtz(nf[4*p + 0]*sh_s, nf[4*p + 1]*sh_s);
        const h2 xs23 = pkrtz(nf[4*p + 2]*sh_s, nf[4*p + 3]*sh_s);
        const h2 pvp = pkrtz(
            (nf[16+6*p]*sh_v[0] + nf[17+6*p]*sh_v[1] + nf[18+6*p]*sh_v[2]) * c3,
            (nf[19+6*p]*sh_v[0] + nf[20+6*p]*sh_v[1] + nf[21+6*p]*sh_v[2]) * c3);

        h2 Aa[16] = {};
#pragma unroll 4
        for (int j = 0; j < 32; ++j) {
            const uint4* gw = g + j*8;
            const uint4 a0 = gw[0], a1 = gw[1], a2 = gw[2], a3 = gw[3];   // ip0
            const uint4 b0 = gw[4], b1 = gw[5], b2 = gw[6], b3 = gw[7];   // ip1
            const uint4* g2 = g + 256 + j*4;
            const uint4 u0 = g2[0], u1 = g2[1], u2 = g2[2], u3 = g2[3];
            const h2 hh = pkrtz(hv[j], hv[j]);
            const h2 t01 = hh * xs01, t23 = hh * xs23, tp = hh * pvp;
            Aa[0] =pfma(t01,uh2(a0.x),Aa[0]);  Aa[0] =pfma(t23,uh2(b0.x),Aa[0]);  Aa[0] =pfma(tp,uh2(u0.x),Aa[0]);
            Aa[1] =pfma(t01,uh2(a0.y),Aa[1]);  Aa[1] =pfma(t23,uh2(b0.y),Aa[1]);  Aa[1] =pfma(tp,uh2(u0.y),Aa[1]);
            Aa[2] =pfma(t01,uh2(a0.z),Aa[2]);  Aa[2] =pfma(t23,uh2(b0.z),Aa[2]);  Aa[2] =pfma(tp,uh2(u0.z),Aa[2]);
            Aa[3] =pfma(t01,uh2(a0.w),Aa[3]);  Aa[3] =pfma(t23,uh2(b0.w),Aa[3]);  Aa[3] =pfma(tp,uh2(u0.w),Aa[3]);
            Aa[4] =pfma(t01,uh2(a1.x),Aa[4]);  Aa[4] =pfma(t23,uh2(b1.x),Aa[4]);  Aa[4] =pfma(tp,uh2(u1.x),Aa[4]);
            Aa[5] =pfma(t01,uh2(a1.y),Aa[5]);  Aa[5] =pfma(t23,uh2(b1.y),Aa[5]);  Aa[5] =pfma(tp,uh2(u1.y),Aa[5]);
            Aa[6] =pfma(t01,uh2(a1.z),Aa[6]);  Aa[6] =pfma(t23,uh2(b1.z),Aa[6]);  Aa[6] =pfma(tp,uh2(u1.z),Aa[6]);
            Aa[7] =pfma(t01,uh2(a1.w),Aa[7]);  Aa[7] =pfma(t23,uh2(b1.w),Aa[7]);  Aa[7] =pfma(tp,uh2(u1.w),Aa[7]);
            Aa[8] =pfma(t01,uh2(a2.x),Aa[8]);  Aa[8] =pfma(t23,uh2(b2.x),Aa[8]);  Aa[8] =pfma(tp,uh2(u2.x),Aa[8]);
            Aa[9] =pfma(t01,uh2(a2.y),Aa[9]);  Aa[9] =pfma(t23,uh2(b2.y),Aa[9]);  Aa[9] =pfma(tp,uh2(u2.y),Aa[9]);
            Aa[10]=pfma(t01,uh2(a2.z),Aa[10]); Aa[10]=pfma(t23,uh2(b2.z),Aa[10]); Aa[10]=pfma(tp,uh2(u2.z),Aa[10]);
            Aa[11]=pfma(t01,uh2(a2.w),Aa[11]); Aa[11]=pfma(t23,uh2(b2.w),Aa[11]); Aa[11]=pfma(tp,uh2(u2.w),Aa[11]);
            Aa[12]=pfma(t01,uh2(a3.x),Aa[12]); Aa[12]=pfma(t23,uh2(b3.x),Aa[12]); Aa[12]=pfma(tp,uh2(u3.x),Aa[12]);
            Aa[13]=pfma(t01,uh2(a3.y),Aa[13]); Aa[13]=pfma(t23,uh2(b3.y),Aa[13]); Aa[13]=pfma(tp,uh2(u3.y),Aa[13]);
            Aa[14]=pfma(t01,uh2(a3.z),Aa[14]); Aa[14]=pfma(t23,uh2(b3.z),Aa[14]); Aa[14]=pfma(tp,uh2(u3.z),Aa[14]);
            Aa[15]=pfma(t01,uh2(a3.w),Aa[15]); Aa[15]=pfma(t23,uh2(b3.w),Aa[15]); Aa[15]=pfma(tp,uh2(u3.w),Aa[15]);
        }

        float A0[16];
#pragma unroll
        for (int o = 0; o < 16; ++o) A0[o] = wred4(h2s(Aa[o]));

        if (p == 0 && val) {
            const float cs = 0.03608439182435161f;   // (1/sqrt32)*(1/sqrt24)
            float4* vp = (float4*)(vbuf + (size_t)pos * 40);
#pragma unroll
            for (int t = 0; t < 4; ++t) {
                float4 r;
                r.x = sa * A0[4*t+0] * cs; r.y = sa * A0[4*t+1] * cs;
                r.z = sa * A0[4*t+2] * cs; r.w = sa * A0[4*t+3] * cs;
                vp[t] = r;
            }
        }
    }

    // ================= stage Vb weights =================
    __syncthreads();                         // all Va reads complete
    for (int idx = tid; idx < 4 * 256; idx += BS) {
        const int pg = idx >> 8;
        const int local = idx & 255;
        const float* s0;
        const float* s1;
        if (local < 128) {                           // w3: pair over i
            const int j = local >> 2, rr = local & 3, ip = rr >> 1, h = rr & 1;
            const int i0 = 4*pg + 2*ip;
            s0 = fcv_w2 + j*640 + 384 + i0*8 + 4*h;
            s1 = s0 + 8;
        } else {                                     // w45: pair over j
            const int l = local - 128;
            const int jp = l >> 3, rr = l & 7, il = rr >> 2, h2c = rr & 3;
            const int i = 2*pg + il, j0 = 2*jp;
            const int base = (h2c < 2) ? 512 : 576;
            s0 = fcv_w2 + j0*640 + base + i*8 + (h2c & 1)*4;
            s1 = s0 + 640;
        }
        swz[pg * 257 + local] = make_uint4(
            pk2h(s0[0], s1[0]), pk2h(s0[1], s1[1]),
            pk2h(s0[2], s1[2]), pk2h(s0[3], s1[3]));
    }
    __syncthreads();

    // ================= Vb phase =================
    {
        const uint4* g = swz + p * 257;

        const h2 xs01 = pkrtz(nf[4*p + 0], nf[4*p + 1]);
        const h2 xs23 = pkrtz(nf[4*p + 2], nf[4*p + 3]);

        h2 T3[8] = {};
#pragma unroll 4
        for (int j = 0; j < 32; ++j) {
            const uint4 E0 = g[j*4+0], E1 = g[j*4+1];   // ip0: o0..3, o4..7
            const uint4 F0 = g[j*4+2], F1 = g[j*4+3];   // ip1
            const h2 hh = pkrtz(hv[j], hv[j]);
            const h2 t01 = hh * xs01, t23 = hh * xs23;
            T3[0]=pfma(t01,uh2(E0.x),T3[0]); T3[0]=pfma(t23,uh2(F0.x),T3[0]);
            T3[1]=pfma(t01,uh2(E0.y),T3[1]); T3[1]=pfma(t23,uh2(F0.y),T3[1]);
            T3[2]=pfma(t01,uh2(E0.z),T3[2]); T3[2]=pfma(t23,uh2(F0.z),T3[2]);
            T3[3]=pfma(t01,uh2(E0.w),T3[3]); T3[3]=pfma(t23,uh2(F0.w),T3[3]);
            T3[4]=pfma(t01,uh2(E1.x),T3[4]); T3[4]=pfma(t23,uh2(F1.x),T3[4]);
            T3[5]=pfma(t01,uh2(E1.y),T3[5]); T3[5]=pfma(t23,uh2(F1.y),T3[5]);
            T3[6]=pfma(t01,uh2(E1.z),T3[6]); T3[6]=pfma(t23,uh2(F1.z),T3[6]);
            T3[7]=pfma(t01,uh2(E1.w),T3[7]); T3[7]=pfma(t23,uh2(F1.w),T3[7]);
        }

        h2 P4[16] = {}, P5[16] = {};
#pragma unroll 2
        for (int jp = 0; jp < 16; ++jp) {
            const uint4* gw = g + 128 + jp*8;
            const uint4 a4 = gw[0], b4 = gw[1];   // il0 w4 o0-3, o4-7
            const uint4 c4 = gw[2], d4 = gw[3];   // il0 w5
            const uint4 e4 = gw[4], f4 = gw[5];   // il1 w4
            const uint4 m4 = gw[6], n4 = gw[7];   // il1 w5
            const h2 hp = pkrtz(hv[2*jp], hv[2*jp+1]);
            P4[0] =pfma(hp,uh2(a4.x),P4[0]);  P4[1] =pfma(hp,uh2(a4.y),P4[1]);
            P4[2] =pfma(hp,uh2(a4.z),P4[2]);  P4[3] =pfma(hp,uh2(a4.w),P4[3]);
            P4[4] =pfma(hp,uh2(b4.x),P4[4]);  P4[5] =pfma(hp,uh2(b4.y),P4[5]);
            P4[6] =pfma(hp,uh2(b4.z),P4[6]);  P4[7] =pfma(hp,uh2(b4.w),P4[7]);
            P5[0] =pfma(hp,uh2(c4.x),P5[0]);  P5[1] =pfma(hp,uh2(c4.y),P5[1]);
            P5[2] =pfma(hp,uh2(c4.z),P5[2]);  P5[3] =pfma(hp,uh2(c4.w),P5[3]);
            P5[4] =pfma(hp,uh2(d4.x),P5[4]);  P5[5] =pfma(hp,uh2(d4.y),P5[5]);
            P5[6] =pfma(hp,uh2(d4.z),P5[6]);  P5[7] =pfma(hp,uh2(d4.w),P5[7]);
            P4[8] =pfma(hp,uh2(e4.x),P4[8]);  P4[9] =pfma(hp,uh2(e4.y),P4[9]);
            P4[10]=pfma(hp,uh2(e4.z),P4[10]); P4[11]=pfma(hp,uh2(e4.w),P4[11]);
            P4[12]=pfma(hp,uh2(f4.x),P4[12]); P4[13]=pfma(hp,uh2(f4.y),P4[13]);
            P4[14]=pfma(hp,uh2(f4.z),P4[14]); P4[15]=pfma(hp,uh2(f4.w),P4[15]);
            P5[8] =pfma(hp,uh2(m4.x),P5[8]);  P5[9] =pfma(hp,uh2(m4.y),P5[9]);
            P5[10]=pfma(hp,uh2(m4.z),P5[10]); P5[11]=pfma(hp,uh2(m4.w),P5[11]);
            P5[12]=pfma(hp,uh2(n4.x),P5[12]); P5[13]=pfma(hp,uh2(n4.y),P5[13]);
            P5[14]=pfma(hp,uh2(n4.z),P5[14]); P5[15]=pfma(hp,uh2(n4.w),P5[15]);
        }

        float R[24], T3f[8];
        {
            float acc[24];
#pragma unroll
            for (int o = 0; o < 24; ++o) acc[o] = 0.f;
            {
                const float x0 = nf[16 + 6*p], x1 = nf[17 + 6*p], x2 = nf[18 + 6*p];
                const float s0 = sh_s*x0, s1 = sh_s*x1, s2 = sh_s*x2;
                const float cx0 = c7*(x1*sh_v[2] - x2*sh_v[1]);
                const float cx1 = c7*(x2*sh_v[0] - x0*sh_v[2]);
                const float cx2 = c7*(x0*sh_v[1] - x1*sh_v[0]);
#pragma unroll
                for (int o = 0; o < 8; ++o) {
                    const float w4 = h2s(P4[o]), w5 = h2s(P5[o]);
                    acc[o*3+0] += s0*w4 + cx0*w5;
                    acc[o*3+1] += s1*w4 + cx1*w5;
                    acc[o*3+2] += s2*w4 + cx2*w5;
                }
            }
            {
                const float x0 = nf[19 + 6*p], x1 = nf[20 + 6*p], x2 = nf[21 + 6*p];
                const float s0 = sh_s*x0, s1 = sh_s*x1, s2 = sh_s*x2;
                const float cx0 = c7*(x1*sh_v[2] - x2*sh_v[1]);
                const float cx1 = c7*(x2*sh_v[0] - x0*sh_v[2]);
                const float cx2 = c7*(x0*sh_v[1] - x1*sh_v[0]);
#pragma unroll
                for (int o = 0; o < 8; ++o) {
                    const float w4 = h2s(P4[8+o]), w5 = h2s(P5[8+o]);
                    acc[o*3+0] += s0*w4 + cx0*w5;
                    acc[o*3+1] += s1*w4 + cx1*w5;
                    acc[o*3+2] += s2*w4 + cx2*w5;
                }
            }
#pragma unroll
            for (int o = 0; o < 24; ++o) R[o] = wred4(acc[o]);
        }
#pragma unroll
        for (int o = 0; o < 8; ++o) T3f[o] = wred4(h2s(T3[o]));

        if (p == 0 && val) {
            const float sc = 0.03125f;               // (1/sqrt32)*(1/sqrt32)
            float row[24];
#pragma unroll
            for (int o = 0; o < 8; ++o)
#pragma unroll
                for (int c = 0; c < 3; ++c)
                    row[o*3+c] = sa * (T3f[o]*sh_v[c] + R[o*3+c]) * sc;
            float4* vp = (float4*)(vbuf + (size_t)pos * 40 + 16);
#pragma unroll
            for (int t = 0; t < 6; ++t) {
                float4 r; r.x = row[4*t+0]; r.y = row[4*t+1]; r.z = row[4*t+2]; r.w = row[4*t+3];
                vp[t] = r;
            }
        }
    }
}

__global__ __launch_bounds__(256) void node_reduce(
    const int*   __restrict__ start,
    const float* __restrict__ exbuf,
    const float* __restrict__ vbuf,
    float* __restrict__ out, int N)
{
    const int wave = threadIdx.x >> 6;
    const int lane = threadIdx.x & 63;
    const int n = blockIdx.x * 4 + wave;
    if (n >= N) return;
    const int r0 = start[n], r1 = start[n + 1];
    float z = 0.f, comp = 0.f;
    for (int r = r0; r < r1; ++r) {
        z += exbuf[r];
        if (lane < 40) comp += vbuf[(size_t)r * 40 + lane];
    }
    if (lane < 40)
        out[(size_t)n * 40 + lane] = (z > 0.f) ? comp * rsqrtf(z) : 0.f;
}

extern "C" void kernel_launch(void* const* d_in, const int* in_sizes, int n_in,
                              void* d_out, int out_size, void* d_ws, size_t ws_size,
                              hipStream_t stream) {
    const float* node_ft      = (const float*)d_in[0];
    const int*   edge_index   = (const int*)  d_in[1];
    const float* edge_sh      = (const float*)d_in[2];
    const float* edge_scalars = (const float*)d_in[3];
    const float* w_q_s        = (const float*)d_in[4];
    const float* w_q_v        = (const float*)d_in[5];
    const float* fck_w1       = (const float*)d_in[6];
    const float* fck_w2       = (const float*)d_in[7];
    const float* fcv_w1       = (const float*)d_in[8];
    const float* fcv_w2       = (const float*)d_in[9];
    const float* wdot_s       = (const float*)d_in[10];
    const float* wdot_v       = (const float*)d_in[11];

    const int N = in_sizes[0] / 40;
    const int E = in_sizes[2] / 4;

    float* ws    = (float*)d_ws;
    float* qd    = ws;                               // N*20
    int*   cnt   = (int*)(ws + (size_t)N * 20);      // N
    int*   start = cnt + N;                          // N+1
    int*   curs  = start + N + 1;                    // N
    int*   flg   = curs + N;                         // 1
    size_t off   = (size_t)N * 20 + N + (N + 1) + N + 1;
    off = (off + 3) & ~(size_t)3;                    // 16B align
    float* exbuf  = ws + off;                        // E
    float* vbuf   = exbuf + E;                       // E*40 (E%4==0 -> aligned)

    float* out = (float*)d_out;

    const int NE = (E > N) ? E : N;
    const int EB = (E + EPB - 1) / EPB;

    hipMemsetAsync(cnt, 0, (size_t)N * sizeof(int), stream);
    hipLaunchKernelGGL(pre_count, dim3((NE + 255) / 256), dim3(256), 0, stream,
                       node_ft, edge_index, w_q_s, w_q_v, wdot_s, wdot_v,
                       qd, cnt, flg, N, E);
    hipLaunchKernelGGL(scan_kernel, dim3(1), dim3(1024), 0, stream,
                       cnt, start, curs, N);
    hipLaunchKernelGGL(edge_all, dim3(EB), dim3(BS), 0, stream,
                       node_ft, edge_index, edge_sh, edge_scalars,
                       fck_w1, fck_w2, fcv_w1, fcv_w2,
                       qd, curs, exbuf, vbuf, flg, N, E);
    hipLaunchKernelGGL(node_reduce, dim3((N + 3) / 4), dim3(256), 0, stream,
                       start, exbuf, vbuf, out, N);
}

// Round 11
// 241.721 us; speedup vs baseline: 2.1758x; 1.1132x over previous
//
#include <hip/hip_runtime.h>

// GraphAttention (e3nn-style) on MI355X — Round 15: fused edge pipeline,
// full-unroll fix for the scratch spill.
// Round-14 post-mortem: fused kernel ran at 169us == sum of old parts; FETCH
// 81MB / WRITE 129MB (legit ~30/17) at VGPR 76 -> hk[32]/hv[32] demoted to
// SCRATCH: the "#pragma unroll 4/8" j-loops index hk[j]/hv[j] with a runtime
// j; in the small round-12 kernels LLVM fully unrolled anyway (no scratch),
// in the 3x-larger fused kernel it honored the partial unroll (rule #20).
// Fix: full "#pragma unroll" on every loop that indexes a per-thread array
// by its induction var -> all indices compile-time -> arrays stay in VGPRs.
//
// Dims: M0=16 M1=8 Q0=8 Q1=4 O0=16 O1=8 EDGE_BASIS=16 HIDDEN=32
// TPK [32][320]: w1[0,128) w2[128,192) w3[192,256) w4[256,288) w5[288,320)
// TPV [32][640]: w1[0,256) w2[256,384) w3[384,512) w4[512,576) w5[576,640)
//
// ws (4B units): qd[N*20] | cnt[N] | start[N+1] | cursor[N] | flag | pad |
//                exbuf[E] | vbuf[E*40]

#define BS 256           // threads per block (edge kernel): 4 waves
#define EPB 64           // edges per block: 4 waves x 16 q-lanes x 1 edge

typedef _Float16 h2 __attribute__((ext_vector_type(2)));

__device__ __forceinline__ float silu_f(float x) {
    return x * (1.0f / (1.0f + __expf(-x)));
}
__device__ __forceinline__ unsigned short f2h(float f) {   // f32 -> f16 RNE
    return __builtin_bit_cast(unsigned short, (_Float16)f);
}
__device__ __forceinline__ unsigned pk2h(float a, float b) { // pack 2 f16 (RNE)
    return (unsigned)f2h(a) | ((unsigned)f2h(b) << 16);
}
__device__ __forceinline__ h2 uh2(unsigned u) {
    return __builtin_bit_cast(h2, u);
}
__device__ __forceinline__ h2 pkrtz(float a, float b) {    // v_cvt_pkrtz_f16_f32
    return __builtin_bit_cast(h2, __builtin_amdgcn_cvt_pkrtz(a, b));
}
__device__ __forceinline__ h2 pfma(h2 a, h2 b, h2 c) {     // v_pk_fma_f16
    return __builtin_elementwise_fma(a, b, c);
}
__device__ __forceinline__ float h2s(h2 a) {               // lo+hi in f32
    return (float)a[0] + (float)a[1];
}
__device__ __forceinline__ float wred4(float v) {          // sum over 4 p-groups
    v += __shfl_xor(v, 16);
    v += __shfl_xor(v, 32);
    return v;
}

// ===================== pre_count: node precompute + edge degree count ==========
// cnt must be zeroed (hipMemsetAsync) before this kernel. is64 derived per-wave.
__global__ __launch_bounds__(256) void pre_count(
    const float* __restrict__ node_ft,
    const int*   __restrict__ ei,
    const float* __restrict__ w_q_s, const float* __restrict__ w_q_v,
    const float* __restrict__ wdot_s, const float* __restrict__ wdot_v,
    float* __restrict__ qd, int* __restrict__ cnt, int* __restrict__ flag,
    int N, int E)
{
    const int gid = blockIdx.x * blockDim.x + threadIdx.x;

    int acc = 0;
    if ((threadIdx.x & 63) == 0) {
        const int kmax = (E < 64) ? E : 64;
        for (int k = 0; k < kmax; ++k) acc |= ei[2*k + 1];
    }
    acc = __shfl(acc, 0, 64);
    const int is64 = (acc == 0) ? 1 : 0;   // int64 layout => odd words all zero
    if (gid == 0) *flag = is64;

    if (gid < E) {
        const int rcv = is64 ? ei[2*(E + gid)] : ei[E + gid];
        atomicAdd(cnt + rcv, 1);
    }

    const int n = gid;
    if (n >= N) return;

    const float* nf = node_ft + (size_t)n * 40;
    float xs[16];
#pragma unroll
    for (int i = 0; i < 16; ++i) xs[i] = nf[i];
    float qv0[8];
#pragma unroll
    for (int o = 0; o < 8; ++o) {
        float a = 0.f;
#pragma unroll
        for (int i = 0; i < 16; ++i) a += xs[i] * w_q_s[i*8 + o];
        qv0[o] = a * 0.25f;
    }
    float* qdn = qd + (size_t)n * 20;
#pragma unroll
    for (int j = 0; j < 8; ++j) {
        float a = 0.f;
#pragma unroll
        for (int i = 0; i < 8; ++i) a += qv0[i] * wdot_s[i*8 + j];
        qdn[j] = a;
    }
    float xv[8][3];
#pragma unroll
    for (int i = 0; i < 8; ++i)
#pragma unroll
        for (int c = 0; c < 3; ++c) xv[i][c] = nf[16 + i*3 + c];
    float qv[4][3];
#pragma unroll
    for (int o = 0; o < 4; ++o)
#pragma unroll
        for (int c = 0; c < 3; ++c) {
            float a = 0.f;
#pragma unroll
            for (int i = 0; i < 8; ++i) a += xv[i][c] * w_q_v[i*4 + o];
            qv[o][c] = a * 0.35355339059327379f;
        }
#pragma unroll
    for (int j = 0; j < 4; ++j)
#pragma unroll
        for (int c = 0; c < 3; ++c) {
            float a = 0.f;
#pragma unroll
            for (int i = 0; i < 4; ++i) a += qv[i][c] * wdot_v[i*4 + j];
            qdn[8 + j*3 + c] = a;
        }
}

// 1 block, 1024 threads; shuffle-based scan (few barriers).
__global__ __launch_bounds__(1024) void scan_kernel(
    const int* __restrict__ cnt, int* __restrict__ start,
    int* __restrict__ cursor, int N)
{
    __shared__ int wsum[16];
    __shared__ int s_carry;
    const int tid = threadIdx.x, wave = tid >> 6, lane = tid & 63;
    if (tid == 0) s_carry = 0;
    __syncthreads();
    for (int base = 0; base < N; base += 1024) {
        const int i = base + tid;
        const int v = (i < N) ? cnt[i] : 0;
        int x = v;                                  // inclusive intra-wave scan
#pragma unroll
        for (int d = 1; d < 64; d <<= 1) {
            const int y = __shfl_up(x, d, 64);
            if (lane >= d) x += y;
        }
        if (lane == 63) wsum[wave] = x;
        __syncthreads();
        if (wave == 0 && lane < 16) {
            int w = wsum[lane];
#pragma unroll
            for (int d = 1; d < 16; d <<= 1) {
                const int y = __shfl_up(w, d, 64);
                if (lane >= d) w += y;              // lanes 16..63 inactive
            }
            wsum[lane] = w;                         // inclusive wave-prefix
        }
        __syncthreads();
        const int woff = (wave == 0) ? 0 : wsum[wave - 1];
        const int carry = s_carry;
        if (i < N) {
            const int s = carry + woff + x - v;     // exclusive
            start[i] = s;
            cursor[i] = s;
        }
        __syncthreads();
        if (tid == 0) s_carry = carry + wsum[15];
        __syncthreads();
    }
    if (tid == 0) start[N] = s_carry;
}

// ===================== edge_all: K + Va + Vb fused =====================
// One 24640B LDS buffer, re-staged per phase (layouts identical to round 12):
//  K  (stride 321): [0,128) w1 | [128,192) w3 | [192,256) w2 | [256,320) w45
//  Va (stride 385): [0,256) w1 | [256,384) w2
//  Vb (stride 257): [0,128) w3 | [128,256) w45
// All group strides %128==16 -> 4 concurrent group reads on disjoint bank quads.
// No early returns (5 barriers); tail edges clamped + val-guarded.
// ALL per-thread-array loops fully unrolled (scratch-spill fix, rule #20).
__global__ __launch_bounds__(BS) void edge_all(
    const float* __restrict__ node_ft,
    const int*   __restrict__ ei,
    const float* __restrict__ edge_sh,
    const float* __restrict__ edge_scalars,
    const float* __restrict__ fck_w1,
    const float* __restrict__ fck_w2,
    const float* __restrict__ fcv_w1,
    const float* __restrict__ fcv_w2,
    const float* __restrict__ qd,
    int*   __restrict__ cursor,
    float* __restrict__ exbuf,              // [E] CSR order
    float* __restrict__ vbuf,               // [E,40] CSR order
    const int* __restrict__ flag,
    int N, int E)
{
    __shared__ uint4 swz[4 * 385];          // 24640 B (max of 3 phase layouts)

    const int tid = threadIdx.x;
    const int lane = tid & 63;
    const int p = lane >> 4;
    const int q = lane & 15;
    const int w = tid >> 6;
    const int e = blockIdx.x * EPB + w * 16 + q;
    const bool val = (e < E);
    const int ec = val ? e : (E - 1);

    const int is64 = *flag;
    const int snd = is64 ? ei[2*ec]       : ei[ec];
    const int rcv = is64 ? ei[2*(E + ec)] : ei[E + ec];

    int pos = 0;
    if (p == 0 && val) pos = atomicAdd(cursor + rcv, 1);  // one claimant/edge

    const float4 s4 = *(const float4*)(edge_sh + (size_t)ec * 4);
    const float sh_s = s4.x;
    const float sh_v[3] = {s4.y, s4.z, s4.w};
    const float* nf = node_ft + (size_t)snd * 40;
    const float c3 = 0.57735026918962576f;
    const float c7 = 0.70710678118654752f;

    float es[16];
    {
        const float4* a0 = (const float4*)(edge_scalars + (size_t)ec * 16);
#pragma unroll
        for (int t = 0; t < 4; ++t) {
            const float4 v = a0[t];
            es[4*t+0]=v.x; es[4*t+1]=v.y; es[4*t+2]=v.z; es[4*t+3]=v.w;
        }
    }

    // ================= stage K weights =================
    for (int idx = tid; idx < 4 * 320; idx += BS) {
        const int pg = idx / 320;
        const int local = idx - pg * 320;
        unsigned r0, r1, r2, r3;
        if (local < 128) {                       // w1: pair over i, 4 outs
            const int j = local >> 2, rr = local & 3, ip = rr >> 1, h = rr & 1;
            const int i0 = 4*pg + 2*ip;
            const float* s0 = fck_w2 + j*320 + i0*8 + 4*h;
            const float* s1 = s0 + 8;
            r0 = pk2h(s0[0], s1[0]); r1 = pk2h(s0[1], s1[1]);
            r2 = pk2h(s0[2], s1[2]); r3 = pk2h(s0[3], s1[3]);
        } else if (local < 192) {                // w3: pair over i, 4 outs
            const int l = local - 128; const int j = l >> 1, ip = l & 1;
            const int i0 = 4*pg + 2*ip;
            const float* s0 = fck_w2 + j*320 + 192 + i0*4;
            const float* s1 = s0 + 4;
            r0 = pk2h(s0[0], s1[0]); r1 = pk2h(s0[1], s1[1]);
            r2 = pk2h(s0[2], s1[2]); r3 = pk2h(s0[3], s1[3]);
        } else if (local < 256) {                // w2: pair over i=(2pg,2pg+1)
            const int l = local - 192; const int j = l >> 1, h = l & 1;
            const int i0 = 2*pg;
            const float* s0 = fck_w2 + j*320 + 128 + i0*8 + 4*h;
            const float* s1 = s0 + 8;
            r0 = pk2h(s0[0], s1[0]); r1 = pk2h(s0[1], s1[1]);
            r2 = pk2h(s0[2], s1[2]); r3 = pk2h(s0[3], s1[3]);
        } else {                                 // w45: pair over j=(2jp,2jp+1)
            const int l = local - 256; const int jp = l >> 2, rr = l & 3;
            const int il = rr >> 1, h = rr & 1;
            const int i = 2*pg + il, j0 = 2*jp;
            const int col = (h == 0 ? 256 : 288) + i*4;
            const float* s0 = fck_w2 + j0*320 + col;
            const float* s1 = s0 + 320;
            r0 = pk2h(s0[0], s1[0]); r1 = pk2h(s0[1], s1[1]);
            r2 = pk2h(s0[2], s1[2]); r3 = pk2h(s0[3], s1[3]);
        }
        swz[pg * 321 + local] = make_uint4(r0, r1, r2, r3);
    }
    __syncthreads();

    // ---- hk net + K phase ----
    float sa = 0.f;
    {
        float hk[32];
#pragma unroll
        for (int j = 0; j < 32; ++j) {
            float a = 0.f;
#pragma unroll
            for (int t = 0; t < 16; ++t) a += es[t] * fck_w1[t*32 + j];
            hk[j] = silu_f(a * 0.25f);
        }

        const uint4* g = swz + p * 321;

        const h2 xs01 = pkrtz(nf[4*p + 0], nf[4*p + 1]);
        const h2 xs23 = pkrtz(nf[4*p + 2], nf[4*p + 3]);
        const float x00 = nf[16 + 6*p], x01 = nf[17 + 6*p], x02 = nf[18 + 6*p];
        const float x10 = nf[19 + 6*p], x11 = nf[20 + 6*p], x12 = nf[21 + 6*p];
        const h2 pvp = pkrtz((x00*sh_v[0] + x01*sh_v[1] + x02*sh_v[2]) * c3,
                             (x10*sh_v[0] + x11*sh_v[1] + x12*sh_v[2]) * c3);

        h2 K1[8] = {}, K3[4] = {}, K2[8] = {};
#pragma unroll
        for (int j = 0; j < 32; ++j) {
            const uint4 A = g[j*4+0], B = g[j*4+1], C = g[j*4+2], D = g[j*4+3];
            const uint4 Ea = g[128 + j*2], Fb = g[128 + j*2 + 1];
            const uint4 U = g[192 + j*2], V = g[192 + j*2 + 1];
            const h2 hh = pkrtz(hk[j], hk[j]);
            const h2 t01 = hh * xs01, t23 = hh * xs23, tp = hh * pvp;
            K1[0]=pfma(t01,uh2(A.x),K1[0]); K1[0]=pfma(t23,uh2(C.x),K1[0]);
            K1[1]=pfma(t01,uh2(A.y),K1[1]); K1[1]=pfma(t23,uh2(C.y),K1[1]);
            K1[2]=pfma(t01,uh2(A.z),K1[2]); K1[2]=pfma(t23,uh2(C.z),K1[2]);
            K1[3]=pfma(t01,uh2(A.w),K1[3]); K1[3]=pfma(t23,uh2(C.w),K1[3]);
            K1[4]=pfma(t01,uh2(B.x),K1[4]); K1[4]=pfma(t23,uh2(D.x),K1[4]);
            K1[5]=pfma(t01,uh2(B.y),K1[5]); K1[5]=pfma(t23,uh2(D.y),K1[5]);
            K1[6]=pfma(t01,uh2(B.z),K1[6]); K1[6]=pfma(t23,uh2(D.z),K1[6]);
            K1[7]=pfma(t01,uh2(B.w),K1[7]); K1[7]=pfma(t23,uh2(D.w),K1[7]);
            K3[0]=pfma(t01,uh2(Ea.x),K3[0]); K3[0]=pfma(t23,uh2(Fb.x),K3[0]);
            K3[1]=pfma(t01,uh2(Ea.y),K3[1]); K3[1]=pfma(t23,uh2(Fb.y),K3[1]);
            K3[2]=pfma(t01,uh2(Ea.z),K3[2]); K3[2]=pfma(t23,uh2(Fb.z),K3[2]);
            K3[3]=pfma(t01,uh2(Ea.w),K3[3]); K3[3]=pfma(t23,uh2(Fb.w),K3[3]);
            K2[0]=pfma(tp,uh2(U.x),K2[0]); K2[1]=pfma(tp,uh2(U.y),K2[1]);
            K2[2]=pfma(tp,uh2(U.z),K2[2]); K2[3]=pfma(tp,uh2(U.w),K2[3]);
            K2[4]=pfma(tp,uh2(V.x),K2[4]); K2[5]=pfma(tp,uh2(V.y),K2[5]);
            K2[6]=pfma(tp,uh2(V.z),K2[6]); K2[7]=pfma(tp,uh2(V.w),K2[7]);
        }

        h2 P4[8] = {}, P5[8] = {};
#pragma unroll
        for (int jp = 0; jp < 16; ++jp) {
            const uint4 a4 = g[256 + jp*4 + 0];   // il0 w4
            const uint4 b4 = g[256 + jp*4 + 1];   // il0 w5
            const uint4 c4 = g[256 + jp*4 + 2];   // il1 w4
            const uint4 d4 = g[256 + jp*4 + 3];   // il1 w5
            const h2 hp = pkrtz(hk[2*jp], hk[2*jp+1]);
            P4[0]=pfma(hp,uh2(a4.x),P4[0]); P4[1]=pfma(hp,uh2(a4.y),P4[1]);
            P4[2]=pfma(hp,uh2(a4.z),P4[2]); P4[3]=pfma(hp,uh2(a4.w),P4[3]);
            P5[0]=pfma(hp,uh2(b4.x),P5[0]); P5[1]=pfma(hp,uh2(b4.y),P5[1]);
            P5[2]=pfma(hp,uh2(b4.z),P5[2]); P5[3]=pfma(hp,uh2(b4.w),P5[3]);
            P4[4]=pfma(hp,uh2(c4.x),P4[4]); P4[5]=pfma(hp,uh2(c4.y),P4[5]);
            P4[6]=pfma(hp,uh2(c4.z),P4[6]); P4[7]=pfma(hp,uh2(c4.w),P4[7]);
            P5[4]=pfma(hp,uh2(d4.x),P5[4]); P5[5]=pfma(hp,uh2(d4.y),P5[5]);
            P5[6]=pfma(hp,uh2(d4.z),P5[6]); P5[7]=pfma(hp,uh2(d4.w),P5[7]);
        }

        float ds = 0.f, dv = 0.f;
        {
            float qdr[20];
            const float4* rp = (const float4*)(qd + (size_t)rcv * 20);
#pragma unroll
            for (int t = 0; t < 5; ++t) {
                const float4 a = rp[t];
                qdr[4*t+0]=a.x; qdr[4*t+1]=a.y; qdr[4*t+2]=a.z; qdr[4*t+3]=a.w;
            }
#pragma unroll
            for (int o = 0; o < 8; ++o)
                ds += qdr[o] * (sh_s*h2s(K1[o]) + h2s(K2[o]));
            float KV[12] = {};
            {
                const float s0=sh_s*x00, s1=sh_s*x01, s2=sh_s*x02;
                const float cx0=c7*(x01*sh_v[2]-x02*sh_v[1]);
                const float cx1=c7*(x02*sh_v[0]-x00*sh_v[2]);
                const float cx2=c7*(x00*sh_v[1]-x01*sh_v[0]);
#pragma unroll
                for (int o = 0; o < 4; ++o) {
                    const float w4 = h2s(P4[o]), w5 = h2s(P5[o]);
                    KV[o*3+0] += s0*w4 + cx0*w5;
                    KV[o*3+1] += s1*w4 + cx1*w5;
                    KV[o*3+2] += s2*w4 + cx2*w5;
                }
            }
            {
                const float s0=sh_s*x10, s1=sh_s*x11, s2=sh_s*x12;
                const float cx0=c7*(x11*sh_v[2]-x12*sh_v[1]);
                const float cx1=c7*(x12*sh_v[0]-x10*sh_v[2]);
                const float cx2=c7*(x10*sh_v[1]-x11*sh_v[0]);
#pragma unroll
                for (int o = 0; o < 4; ++o) {
                    const float w4 = h2s(P4[4+o]), w5 = h2s(P5[4+o]);
                    KV[o*3+0] += s0*w4 + cx0*w5;
                    KV[o*3+1] += s1*w4 + cx1*w5;
                    KV[o*3+2] += s2*w4 + cx2*w5;
                }
            }
#pragma unroll
            for (int o = 0; o < 4; ++o) {
                const float k3 = h2s(K3[o]);
#pragma unroll
                for (int c = 0; c < 3; ++c)
                    dv += qdr[8 + o*3 + c] * (k3*sh_v[c] + KV[o*3+c]);
            }
        }
        ds = wred4(ds); dv = wred4(dv);

        if (p == 0 && val) {
            const float dot = ds * 4.0343567508008e-3f + dv * 2.0171788261497e-3f;
            sa = __expf(0.5f * dot);
            exbuf[pos] = sa * sa;
        }
    }

    // ================= stage Va weights =================
    __syncthreads();                         // all K reads complete
    for (int idx = tid; idx < 4 * 384; idx += BS) {
        const int pg = idx / 384;
        const int local = idx - pg * 384;
        const float* s0;
        const float* s1;
        if (local < 256) {                           // w1
            const int j = local >> 3, rr = local & 7, ip = rr >> 2, h = rr & 3;
            const int i0 = 4*pg + 2*ip;
            s0 = fcv_w2 + j*640 + i0*16 + h*4;
            s1 = s0 + 16;
        } else {                                     // w2
            const int l = local - 256; const int j = l >> 2, h = l & 3;
            const int i0 = 2*pg;
            s0 = fcv_w2 + j*640 + 256 + i0*16 + h*4;
            s1 = s0 + 16;
        }
        swz[pg * 385 + local] = make_uint4(
            pk2h(s0[0], s1[0]), pk2h(s0[1], s1[1]),
            pk2h(s0[2], s1[2]), pk2h(s0[3], s1[3]));
    }
    __syncthreads();

    // ---- hv net (es still live; hv spans Va and Vb) ----
    float hv[32];
#pragma unroll
    for (int j = 0; j < 32; ++j) {
        float a = 0.f;
#pragma unroll
        for (int t = 0; t < 16; ++t) a += es[t] * fcv_w1[t*32 + j];
        hv[j] = silu_f(a * 0.25f);
    }

    // ================= Va phase =================
    {
        const uint4* g = swz + p * 385;

        const h2 xs01 = pkrtz(nf[4*p + 0]*sh_s, nf[4*p + 1]*sh_s);
        const h2 xs23 = pkrtz(nf[4*p + 2]*sh_s, nf[4*p + 3]*sh_s);
        const h2 pvp = pkrtz(
            (nf[16+6*p]*sh_v[0] + nf[17+6*p]*sh_v[1] + nf[18+6*p]*sh_v[2]) * c3,
            (nf[19+6*p]*sh_v[0] + nf[20+6*p]*sh_v[1] + nf[21+6*p]*sh_v[2]) * c3);

        h2 Aa[16] = {};
#pragma unroll
        for (int j = 0; j < 32; ++j) {
            const uint4* gw = g + j*8;
            const uint4 a0 = gw[0], a1 = gw[1], a2 = gw[2], a3 = gw[3];   // ip0
            const uint4 b0 = gw[4], b1 = gw[5], b2 = gw[6], b3 = gw[7];   // ip1
            const uint4* g2 = g + 256 + j*4;
            const uint4 u0 = g2[0], u1 = g2[1], u2 = g2[2], u3 = g2[3];
            const h2 hh = pkrtz(hv[j], hv[j]);
            const h2 t01 = hh * xs01, t23 = hh * xs23, tp = hh * pvp;
            Aa[0] =pfma(t01,uh2(a0.x),Aa[0]);  Aa[0] =pfma(t23,uh2(b0.x),Aa[0]);  Aa[0] =pfma(tp,uh2(u0.x),Aa[0]);
            Aa[1] =pfma(t01,uh2(a0.y),Aa[1]);  Aa[1] =pfma(t23,uh2(b0.y),Aa[1]);  Aa[1] =pfma(tp,uh2(u0.y),Aa[1]);
            Aa[2] =pfma(t01,uh2(a0.z),Aa[2]);  Aa[2] =pfma(t23,uh2(b0.z),Aa[2]);  Aa[2] =pfma(tp,uh2(u0.z),Aa[2]);
            Aa[3] =pfma(t01,uh2(a0.w),Aa[3]);  Aa[3] =pfma(t23,uh2(b0.w),Aa[3]);  Aa[3] =pfma(tp,uh2(u0.w),Aa[3]);
            Aa[4] =pfma(t01,uh2(a1.x),Aa[4]);  Aa[4] =pfma(t23,uh2(b1.x),Aa[4]);  Aa[4] =pfma(tp,uh2(u1.x),Aa[4]);
            Aa[5] =pfma(t01,uh2(a1.y),Aa[5]);  Aa[5] =pfma(t23,uh2(b1.y),Aa[5]);  Aa[5] =pfma(tp,uh2(u1.y),Aa[5]);
            Aa[6] =pfma(t01,uh2(a1.z),Aa[6]);  Aa[6] =pfma(t23,uh2(b1.z),Aa[6]);  Aa[6] =pfma(tp,uh2(u1.z),Aa[6]);
            Aa[7] =pfma(t01,uh2(a1.w),Aa[7]);  Aa[7] =pfma(t23,uh2(b1.w),Aa[7]);  Aa[7] =pfma(tp,uh2(u1.w),Aa[7]);
            Aa[8] =pfma(t01,uh2(a2.x),Aa[8]);  Aa[8] =pfma(t23,uh2(b2.x),Aa[8]);  Aa[8] =pfma(tp,uh2(u2.x),Aa[8]);
            Aa[9] =pfma(t01,uh2(a2.y),Aa[9]);  Aa[9] =pfma(t23,uh2(b2.y),Aa[9]);  Aa[9] =pfma(tp,uh2(u2.y),Aa[9]);
            Aa[10]=pfma(t01,uh2(a2.z),Aa[10]); Aa[10]=pfma(t23,uh2(b2.z),Aa[10]); Aa[10]=pfma(tp,uh2(u2.z),Aa[10]);
            Aa[11]=pfma(t01,uh2(a2.w),Aa[11]); Aa[11]=pfma(t23,uh2(b2.w),Aa[11]); Aa[11]=pfma(tp,uh2(u2.w),Aa[11]);
            Aa[12]=pfma(t01,uh2(a3.x),Aa[12]); Aa[12]=pfma(t23,uh2(b3.x),Aa[12]); Aa[12]=pfma(tp,uh2(u3.x),Aa[12]);
            Aa[13]=pfma(t01,uh2(a3.y),Aa[13]); Aa[13]=pfma(t23,uh2(b3.y),Aa[13]); Aa[13]=pfma(tp,uh2(u3.y),Aa[13]);
            Aa[14]=pfma(t01,uh2(a3.z),Aa[14]); Aa[14]=pfma(t23,uh2(b3.z),Aa[14]); Aa[14]=pfma(tp,uh2(u3.z),Aa[14]);
            Aa[15]=pfma(t01,uh2(a3.w),Aa[15]); Aa[15]=pfma(t23,uh2(b3.w),Aa[15]); Aa[15]=pfma(tp,uh2(u3.w),Aa[15]);
        }

        float A0[16];
#pragma unroll
        for (int o = 0; o < 16; ++o) A0[o] = wred4(h2s(Aa[o]));

        if (p == 0 && val) {
            const float cs = 0.03608439182435161f;   // (1/sqrt32)*(1/sqrt24)
            float4* vp = (float4*)(vbuf + (size_t)pos * 40);
#pragma unroll
            for (int t = 0; t < 4; ++t) {
                float4 r;
                r.x = sa * A0[4*t+0] * cs; r.y = sa * A0[4*t+1] * cs;
                r.z = sa * A0[4*t+2] * cs; r.w = sa * A0[4*t+3] * cs;
                vp[t] = r;
            }
        }
    }

    // ================= stage Vb weights =================
    __syncthreads();                         // all Va reads complete
    for (int idx = tid; idx < 4 * 256; idx += BS) {
        const int pg = idx >> 8;
        const int local = idx & 255;
        const float* s0;
        const float* s1;
        if (local < 128) {                           // w3: pair over i
            const int j = local >> 2, rr = local & 3, ip = rr >> 1, h = rr & 1;
            const int i0 = 4*pg + 2*ip;
            s0 = fcv_w2 + j*640 + 384 + i0*8 + 4*h;
            s1 = s0 + 8;
        } else {                                     // w45: pair over j
            const int l = local - 128;
            const int jp = l >> 3, rr = l & 7, il = rr >> 2, h2c = rr & 3;
            const int i = 2*pg + il, j0 = 2*jp;
            const int base = (h2c < 2) ? 512 : 576;
            s0 = fcv_w2 + j0*640 + base + i*8 + (h2c & 1)*4;
            s1 = s0 + 640;
        }
        swz[pg * 257 + local] = make_uint4(
            pk2h(s0[0], s1[0]), pk2h(s0[1], s1[1]),
            pk2h(s0[2], s1[2]), pk2h(s0[3], s1[3]));
    }
    __syncthreads();

    // ================= Vb phase =================
    {
        const uint4* g = swz + p * 257;

        const h2 xs01 = pkrtz(nf[4*p + 0], nf[4*p + 1]);
        const h2 xs23 = pkrtz(nf[4*p + 2], nf[4*p + 3]);

        h2 T3[8] = {};
#pragma unroll
        for (int j = 0; j < 32; ++j) {
            const uint4 E0 = g[j*4+0], E1 = g[j*4+1];   // ip0: o0..3, o4..7
            const uint4 F0 = g[j*4+2], F1 = g[j*4+3];   // ip1
            const h2 hh = pkrtz(hv[j], hv[j]);
            const h2 t01 = hh * xs01, t23 = hh * xs23;
            T3[0]=pfma(t01,uh2(E0.x),T3[0]); T3[0]=pfma(t23,uh2(F0.x),T3[0]);
            T3[1]=pfma(t01,uh2(E0.y),T3[1]); T3[1]=pfma(t23,uh2(F0.y),T3[1]);
            T3[2]=pfma(t01,uh2(E0.z),T3[2]); T3[2]=pfma(t23,uh2(F0.z),T3[2]);
            T3[3]=pfma(t01,uh2(E0.w),T3[3]); T3[3]=pfma(t23,uh2(F0.w),T3[3]);
            T3[4]=pfma(t01,uh2(E1.x),T3[4]); T3[4]=pfma(t23,uh2(F1.x),T3[4]);
            T3[5]=pfma(t01,uh2(E1.y),T3[5]); T3[5]=pfma(t23,uh2(F1.y),T3[5]);
            T3[6]=pfma(t01,uh2(E1.z),T3[6]); T3[6]=pfma(t23,uh2(F1.z),T3[6]);
            T3[7]=pfma(t01,uh2(E1.w),T3[7]); T3[7]=pfma(t23,uh2(F1.w),T3[7]);
        }

        h2 P4[16] = {}, P5[16] = {};
#pragma unroll
        for (int jp = 0; jp < 16; ++jp) {
            const uint4* gw = g + 128 + jp*8;
            const uint4 a4 = gw[0], b4 = gw[1];   // il0 w4 o0-3, o4-7
            const uint4 c4 = gw[2], d4 = gw[3];   // il0 w5
            const uint4 e4 = gw[4], f4 = gw[5];   // il1 w4
            const uint4 m4 = gw[6], n4 = gw[7];   // il1 w5
            const h2 hp = pkrtz(hv[2*jp], hv[2*jp+1]);
            P4[0] =pfma(hp,uh2(a4.x),P4[0]);  P4[1] =pfma(hp,uh2(a4.y),P4[1]);
            P4[2] =pfma(hp,uh2(a4.z),P4[2]);  P4[3] =pfma(hp,uh2(a4.w),P4[3]);
            P4[4] =pfma(hp,uh2(b4.x),P4[4]);  P4[5] =pfma(hp,uh2(b4.y),P4[5]);
            P4[6] =pfma(hp,uh2(b4.z),P4[6]);  P4[7] =pfma(hp,uh2(b4.w),P4[7]);
            P5[0] =pfma(hp,uh2(c4.x),P5[0]);  P5[1] =pfma(hp,uh2(c4.y),P5[1]);
            P5[2] =pfma(hp,uh2(c4.z),P5[2]);  P5[3] =pfma(hp,uh2(c4.w),P5[3]);
            P5[4] =pfma(hp,uh2(d4.x),P5[4]);  P5[5] =pfma(hp,uh2(d4.y),P5[5]);
            P5[6] =pfma(hp,uh2(d4.z),P5[6]);  P5[7] =pfma(hp,uh2(d4.w),P5[7]);
            P4[8] =pfma(hp,uh2(e4.x),P4[8]);  P4[9] =pfma(hp,uh2(e4.y),P4[9]);
            P4[10]=pfma(hp,uh2(e4.z),P4[10]); P4[11]=pfma(hp,uh2(e4.w),P4[11]);
            P4[12]=pfma(hp,uh2(f4.x),P4[12]); P4[13]=pfma(hp,uh2(f4.y),P4[13]);
            P4[14]=pfma(hp,uh2(f4.z),P4[14]); P4[15]=pfma(hp,uh2(f4.w),P4[15]);
            P5[8] =pfma(hp,uh2(m4.x),P5[8]);  P5[9] =pfma(hp,uh2(m4.y),P5[9]);
            P5[10]=pfma(hp,uh2(m4.z),P5[10]); P5[11]=pfma(hp,uh2(m4.w),P5[11]);
            P5[12]=pfma(hp,uh2(n4.x),P5[12]); P5[13]=pfma(hp,uh2(n4.y),P5[13]);
            P5[14]=pfma(hp,uh2(n4.z),P5[14]); P5[15]=pfma(hp,uh2(n4.w),P5[15]);
        }

        float R[24], T3f[8];
        {
            float acc[24];
#pragma unroll
            for (int o = 0; o < 24; ++o) acc[o] = 0.f;
            {
                const float x0 = nf[16 + 6*p], x1 = nf[17 + 6*p], x2 = nf[18 + 6*p];
                const float s0 = sh_s*x0, s1 = sh_s*x1, s2 = sh_s*x2;
                const float cx0 = c7*(x1*sh_v[2] - x2*sh_v[1]);
                const float cx1 = c7*(x2*sh_v[0] - x0*sh_v[2]);
                const float cx2 = c7*(x0*sh_v[1] - x1*sh_v[0]);
#pragma unroll
                for (int o = 0; o < 8; ++o) {
                    const float w4 = h2s(P4[o]), w5 = h2s(P5[o]);
                    acc[o*3+0] += s0*w4 + cx0*w5;
                    acc[o*3+1] += s1*w4 + cx1*w5;
                    acc[o*3+2] += s2*w4 + cx2*w5;
                }
            }
            {
                const float x0 = nf[19 + 6*p], x1 = nf[20 + 6*p], x2 = nf[21 + 6*p];
                const float s0 = sh_s*x0, s1 = sh_s*x1, s2 = sh_s*x2;
                const float cx0 = c7*(x1*sh_v[2] - x2*sh_v[1]);
                const float cx1 = c7*(x2*sh_v[0] - x0*sh_v[2]);
                const float cx2 = c7*(x0*sh_v[1] - x1*sh_v[0]);
#pragma unroll
                for (int o = 0; o < 8; ++o) {
                    const float w4 = h2s(P4[8+o]), w5 = h2s(P5[8+o]);
                    acc[o*3+0] += s0*w4 + cx0*w5;
                    acc[o*3+1] += s1*w4 + cx1*w5;
                    acc[o*3+2] += s2*w4 + cx2*w5;
                }
            }
#pragma unroll
            for (int o = 0; o < 24; ++o) R[o] = wred4(acc[o]);
        }
#pragma unroll
        for (int o = 0; o < 8; ++o) T3f[o] = wred4(h2s(T3[o]));

        if (p == 0 && val) {
            const float sc = 0.03125f;               // (1/sqrt32)*(1/sqrt32)
            float row[24];
#pragma unroll
            for (int o = 0; o < 8; ++o)
#pragma unroll
                for (int c = 0; c < 3; ++c)
                    row[o*3+c] = sa * (T3f[o]*sh_v[c] + R[o*3+c]) * sc;
            float4* vp = (float4*)(vbuf + (size_t)pos * 40 + 16);
#pragma unroll
            for (int t = 0; t < 6; ++t) {
                float4 r; r.x = row[4*t+0]; r.y = row[4*t+1]; r.z = row[4*t+2]; r.w = row[4*t+3];
                vp[t] = r;
            }
        }
    }
}

__global__ __launch_bounds__(256) void node_reduce(
    const int*   __restrict__ start,
    const float* __restrict__ exbuf,
    const float* __restrict__ vbuf,
    float* __restrict__ out, int N)
{
    const int wave = threadIdx.x >> 6;
    const int lane = threadIdx.x & 63;
    const int n = blockIdx.x * 4 + wave;
    if (n >= N) return;
    const int r0 = start[n], r1 = start[n + 1];
    float z = 0.f, comp = 0.f;
    for (int r = r0; r < r1; ++r) {
        z += exbuf[r];
        if (lane < 40) comp += vbuf[(size_t)r * 40 + lane];
    }
    if (lane < 40)
        out[(size_t)n * 40 + lane] = (z > 0.f) ? comp * rsqrtf(z) : 0.f;
}

extern "C" void kernel_launch(void* const* d_in, const int* in_sizes, int n_in,
                              void* d_out, int out_size, void* d_ws, size_t ws_size,
                              hipStream_t stream) {
    const float* node_ft      = (const float*)d_in[0];
    const int*   edge_index   = (const int*)  d_in[1];
    const float* edge_sh      = (const float*)d_in[2];
    const float* edge_scalars = (const float*)d_in[3];
    const float* w_q_s        = (const float*)d_in[4];
    const float* w_q_v        = (const float*)d_in[5];
    const float* fck_w1       = (const float*)d_in[6];
    const float* fck_w2       = (const float*)d_in[7];
    const float* fcv_w1       = (const float*)d_in[8];
    const float* fcv_w2       = (const float*)d_in[9];
    const float* wdot_s       = (const float*)d_in[10];
    const float* wdot_v       = (const float*)d_in[11];

    const int N = in_sizes[0] / 40;
    const int E = in_sizes[2] / 4;

    float* ws    = (float*)d_ws;
    float* qd    = ws;                               // N*20
    int*   cnt   = (int*)(ws + (size_t)N * 20);      // N
    int*   start = cnt + N;                          // N+1
    int*   curs  = start + N + 1;                    // N
    int*   flg   = curs + N;                         // 1
    size_t off   = (size_t)N * 20 + N + (N + 1) + N + 1;
    off = (off + 3) & ~(size_t)3;                    // 16B align
    float* exbuf  = ws + off;                        // E
    float* vbuf   = exbuf + E;                       // E*40 (E%4==0 -> aligned)

    float* out = (float*)d_out;

    const int NE = (E > N) ? E : N;
    const int EB = (E + EPB - 1) / EPB;

    hipMemsetAsync(cnt, 0, (size_t)N * sizeof(int), stream);
    hipLaunchKernelGGL(pre_count, dim3((NE + 255) / 256), dim3(256), 0, stream,
                       node_ft, edge_index, w_q_s, w_q_v, wdot_s, wdot_v,
                       qd, cnt, flg, N, E);
    hipLaunchKernelGGL(scan_kernel, dim3(1), dim3(1024), 0, stream,
                       cnt, start, curs, N);
    hipLaunchKernelGGL(edge_all, dim3(EB), dim3(BS), 0, stream,
                       node_ft, edge_index, edge_sh, edge_scalars,
                       fck_w1, fck_w2, fcv_w1, fcv_w2,
                       qd, curs, exbuf, vbuf, flg, N, E);
    hipLaunchKernelGGL(node_reduce, dim3((N + 3) / 4), dim3(256), 0, stream,
                       start, exbuf, vbuf, out, N);
}

// Round 12
// 240.397 us; speedup vs baseline: 2.1878x; 1.0055x over previous
//
#include <hip/hip_runtime.h>

// GraphAttention (e3nn-style) on MI355X — Round 16: pre-packed weights +
// dense staging copy, exbuf folded into vbuf, nets hoisted over staging.
// Round-15 post-mortem: 241.7us best; edge_all 142us VALU-bound (62%), spill
// gone. Remaining fat: (a) per-block weight staging does 8 scattered f32
// gathers + pack per uint4 (~300-400 VALU/thread); (b) exbuf scattered 4B
// stores dirty 64B lines (~6MB excess WRITE); (c) hk/hv nets serialize after
// staging barriers. Fix: (a) pre_count packs all weights once into a 61KB ws
// region (same verified index math); edge_all stages via dense coalesced
// uint4 copy; (b) vbuf stride 40->44, ex lives in row slot 40; (c) nets
// computed between staging-copy issue and the barrier (overlap).
//
// Dims: M0=16 M1=8 Q0=8 Q1=4 O0=16 O1=8 EDGE_BASIS=16 HIDDEN=32
// TPK [32][320]: w1[0,128) w2[128,192) w3[192,256) w4[256,288) w5[288,320)
// TPV [32][640]: w1[0,256) w2[256,384) w3[384,512) w4[512,576) w5[576,640)
//
// ws (4B units): qd[N*20] | cnt[N] | start[N+1] | cursor[N] | flag | pad |
//                pk[15360] (= uint4[3840]: K 1280 | Va 1536 | Vb 1024) |
//                vbuf[E*44]

#define BS 256           // threads per block (edge kernel): 4 waves
#define EPB 64           // edges per block: 4 waves x 16 q-lanes x 1 edge

typedef _Float16 h2 __attribute__((ext_vector_type(2)));

__device__ __forceinline__ float silu_f(float x) {
    return x * (1.0f / (1.0f + __expf(-x)));
}
__device__ __forceinline__ unsigned short f2h(float f) {   // f32 -> f16 RNE
    return __builtin_bit_cast(unsigned short, (_Float16)f);
}
__device__ __forceinline__ unsigned pk2h(float a, float b) { // pack 2 f16 (RNE)
    return (unsigned)f2h(a) | ((unsigned)f2h(b) << 16);
}
__device__ __forceinline__ h2 uh2(unsigned u) {
    return __builtin_bit_cast(h2, u);
}
__device__ __forceinline__ h2 pkrtz(float a, float b) {    // v_cvt_pkrtz_f16_f32
    return __builtin_bit_cast(h2, __builtin_amdgcn_cvt_pkrtz(a, b));
}
__device__ __forceinline__ h2 pfma(h2 a, h2 b, h2 c) {     // v_pk_fma_f16
    return __builtin_elementwise_fma(a, b, c);
}
__device__ __forceinline__ float h2s(h2 a) {               // lo+hi in f32
    return (float)a[0] + (float)a[1];
}
__device__ __forceinline__ float wred4(float v) {          // sum over 4 p-groups
    v += __shfl_xor(v, 16);
    v += __shfl_xor(v, 32);
    return v;
}

// ===================== pre_count: node precompute + degree count + weight pack
// cnt must be zeroed (hipMemsetAsync) before this kernel.
__global__ __launch_bounds__(256) void pre_count(
    const float* __restrict__ node_ft,
    const int*   __restrict__ ei,
    const float* __restrict__ w_q_s, const float* __restrict__ w_q_v,
    const float* __restrict__ wdot_s, const float* __restrict__ wdot_v,
    const float* __restrict__ fck_w2, const float* __restrict__ fcv_w2,
    float* __restrict__ qd, int* __restrict__ cnt, int* __restrict__ flag,
    uint4* __restrict__ pk,
    int N, int E)
{
    const int gid = blockIdx.x * blockDim.x + threadIdx.x;

    int acc = 0;
    if ((threadIdx.x & 63) == 0) {
        const int kmax = (E < 64) ? E : 64;
        for (int k = 0; k < kmax; ++k) acc |= ei[2*k + 1];
    }
    acc = __shfl(acc, 0, 64);
    const int is64 = (acc == 0) ? 1 : 0;   // int64 layout => odd words all zero
    if (gid == 0) *flag = is64;

    if (gid < E) {
        const int rcv = is64 ? ei[2*(E + gid)] : ei[E + gid];
        atomicAdd(cnt + rcv, 1);
    }

    // ---- weight packing: one uint4 per thread, gid < 3840 ----
    if (gid < 3840) {
        uint4 r;
        if (gid < 1280) {                            // K layout (round-12 verified)
            const int pg = gid / 320;
            const int local = gid - pg * 320;
            if (local < 128) {                       // w1: pair over i, 4 outs
                const int j = local >> 2, rr = local & 3, ip = rr >> 1, h = rr & 1;
                const int i0 = 4*pg + 2*ip;
                const float* s0 = fck_w2 + j*320 + i0*8 + 4*h;
                const float* s1 = s0 + 8;
                r = make_uint4(pk2h(s0[0], s1[0]), pk2h(s0[1], s1[1]),
                               pk2h(s0[2], s1[2]), pk2h(s0[3], s1[3]));
            } else if (local < 192) {                // w3: pair over i, 4 outs
                const int l = local - 128; const int j = l >> 1, ip = l & 1;
                const int i0 = 4*pg + 2*ip;
                const float* s0 = fck_w2 + j*320 + 192 + i0*4;
                const float* s1 = s0 + 4;
                r = make_uint4(pk2h(s0[0], s1[0]), pk2h(s0[1], s1[1]),
                               pk2h(s0[2], s1[2]), pk2h(s0[3], s1[3]));
            } else if (local < 256) {                // w2: pair over i=(2pg,2pg+1)
                const int l = local - 192; const int j = l >> 1, h = l & 1;
                const int i0 = 2*pg;
                const float* s0 = fck_w2 + j*320 + 128 + i0*8 + 4*h;
                const float* s1 = s0 + 8;
                r = make_uint4(pk2h(s0[0], s1[0]), pk2h(s0[1], s1[1]),
                               pk2h(s0[2], s1[2]), pk2h(s0[3], s1[3]));
            } else {                                 // w45: pair over j
                const int l = local - 256; const int jp = l >> 2, rr = l & 3;
                const int il = rr >> 1, h = rr & 1;
                const int i = 2*pg + il, j0 = 2*jp;
                const int col = (h == 0 ? 256 : 288) + i*4;
                const float* s0 = fck_w2 + j0*320 + col;
                const float* s1 = s0 + 320;
                r = make_uint4(pk2h(s0[0], s1[0]), pk2h(s0[1], s1[1]),
                               pk2h(s0[2], s1[2]), pk2h(s0[3], s1[3]));
            }
        } else if (gid < 2816) {                     // Va layout
            const int l2 = gid - 1280;
            const int pg = l2 / 384;
            const int local = l2 - pg * 384;
            const float* s0;
            const float* s1;
            if (local < 256) {                       // w1
                const int j = local >> 3, rr = local & 7, ip = rr >> 2, h = rr & 3;
                const int i0 = 4*pg + 2*ip;
                s0 = fcv_w2 + j*640 + i0*16 + h*4;
                s1 = s0 + 16;
            } else {                                 // w2
                const int l = local - 256; const int j = l >> 2, h = l & 3;
                const int i0 = 2*pg;
                s0 = fcv_w2 + j*640 + 256 + i0*16 + h*4;
                s1 = s0 + 16;
            }
            r = make_uint4(pk2h(s0[0], s1[0]), pk2h(s0[1], s1[1]),
                           pk2h(s0[2], s1[2]), pk2h(s0[3], s1[3]));
        } else {                                     // Vb layout
            const int l2 = gid - 2816;
            const int pg = l2 >> 8;
            const int local = l2 & 255;
            const float* s0;
            const float* s1;
            if (local < 128) {                       // w3: pair over i
                const int j = local >> 2, rr = local & 3, ip = rr >> 1, h = rr & 1;
                const int i0 = 4*pg + 2*ip;
                s0 = fcv_w2 + j*640 + 384 + i0*8 + 4*h;
                s1 = s0 + 8;
            } else {                                 // w45: pair over j
                const int l = local - 128;
                const int jp = l >> 3, rr = l & 7, il = rr >> 2, h2c = rr & 3;
                const int i = 2*pg + il, j0 = 2*jp;
                const int base = (h2c < 2) ? 512 : 576;
                s0 = fcv_w2 + j0*640 + base + i*8 + (h2c & 1)*4;
                s1 = s0 + 640;
            }
            r = make_uint4(pk2h(s0[0], s1[0]), pk2h(s0[1], s1[1]),
                           pk2h(s0[2], s1[2]), pk2h(s0[3], s1[3]));
        }
        pk[gid] = r;
    }

    const int n = gid;
    if (n >= N) return;

    const float* nf = node_ft + (size_t)n * 40;
    float xs[16];
#pragma unroll
    for (int i = 0; i < 16; ++i) xs[i] = nf[i];
    float qv0[8];
#pragma unroll
    for (int o = 0; o < 8; ++o) {
        float a = 0.f;
#pragma unroll
        for (int i = 0; i < 16; ++i) a += xs[i] * w_q_s[i*8 + o];
        qv0[o] = a * 0.25f;
    }
    float* qdn = qd + (size_t)n * 20;
#pragma unroll
    for (int j = 0; j < 8; ++j) {
        float a = 0.f;
#pragma unroll
        for (int i = 0; i < 8; ++i) a += qv0[i] * wdot_s[i*8 + j];
        qdn[j] = a;
    }
    float xv[8][3];
#pragma unroll
    for (int i = 0; i < 8; ++i)
#pragma unroll
        for (int c = 0; c < 3; ++c) xv[i][c] = nf[16 + i*3 + c];
    float qv[4][3];
#pragma unroll
    for (int o = 0; o < 4; ++o)
#pragma unroll
        for (int c = 0; c < 3; ++c) {
            float a = 0.f;
#pragma unroll
            for (int i = 0; i < 8; ++i) a += xv[i][c] * w_q_v[i*4 + o];
            qv[o][c] = a * 0.35355339059327379f;
        }
#pragma unroll
    for (int j = 0; j < 4; ++j)
#pragma unroll
        for (int c = 0; c < 3; ++c) {
            float a = 0.f;
#pragma unroll
            for (int i = 0; i < 4; ++i) a += qv[i][c] * wdot_v[i*4 + j];
            qdn[8 + j*3 + c] = a;
        }
}

// 1 block, 1024 threads; shuffle-based scan (few barriers).
__global__ __launch_bounds__(1024) void scan_kernel(
    const int* __restrict__ cnt, int* __restrict__ start,
    int* __restrict__ cursor, int N)
{
    __shared__ int wsum[16];
    __shared__ int s_carry;
    const int tid = threadIdx.x, wave = tid >> 6, lane = tid & 63;
    if (tid == 0) s_carry = 0;
    __syncthreads();
    for (int base = 0; base < N; base += 1024) {
        const int i = base + tid;
        const int v = (i < N) ? cnt[i] : 0;
        int x = v;                                  // inclusive intra-wave scan
#pragma unroll
        for (int d = 1; d < 64; d <<= 1) {
            const int y = __shfl_up(x, d, 64);
            if (lane >= d) x += y;
        }
        if (lane == 63) wsum[wave] = x;
        __syncthreads();
        if (wave == 0 && lane < 16) {
            int w = wsum[lane];
#pragma unroll
            for (int d = 1; d < 16; d <<= 1) {
                const int y = __shfl_up(w, d, 64);
                if (lane >= d) w += y;              // lanes 16..63 inactive
            }
            wsum[lane] = w;                         // inclusive wave-prefix
        }
        __syncthreads();
        const int woff = (wave == 0) ? 0 : wsum[wave - 1];
        const int carry = s_carry;
        if (i < N) {
            const int s = carry + woff + x - v;     // exclusive
            start[i] = s;
            cursor[i] = s;
        }
        __syncthreads();
        if (tid == 0) s_carry = carry + wsum[15];
        __syncthreads();
    }
    if (tid == 0) start[N] = s_carry;
}

// ===================== edge_all: K + Va + Vb fused =====================
// One 24640B LDS buffer, staged per phase by DENSE COPY from pre-packed pk:
//  K  (stride 321): pk[0,1280)   | Va (stride 385): pk[1280,2816)
//  Vb (stride 257): pk[2816,3840)
// All group strides %128==16 -> 4 concurrent group reads on disjoint bank quads.
// No early returns (5 barriers); tail edges clamped + val-guarded.
// vbuf stride 44: slots [0,40) = V row, slot 40 = exp(dot).
__global__ __launch_bounds__(BS) void edge_all(
    const float* __restrict__ node_ft,
    const int*   __restrict__ ei,
    const float* __restrict__ edge_sh,
    const float* __restrict__ edge_scalars,
    const float* __restrict__ fck_w1,
    const float* __restrict__ fcv_w1,
    const uint4* __restrict__ pk,
    const float* __restrict__ qd,
    int*   __restrict__ cursor,
    float* __restrict__ vbuf,               // [E,44] CSR order
    const int* __restrict__ flag,
    int N, int E)
{
    __shared__ uint4 swz[4 * 385];          // 24640 B (max of 3 phase layouts)

    const int tid = threadIdx.x;
    const int lane = tid & 63;
    const int p = lane >> 4;
    const int q = lane & 15;
    const int w = tid >> 6;
    const int e = blockIdx.x * EPB + w * 16 + q;
    const bool val = (e < E);
    const int ec = val ? e : (E - 1);

    const int is64 = *flag;
    const int snd = is64 ? ei[2*ec]       : ei[ec];
    const int rcv = is64 ? ei[2*(E + ec)] : ei[E + ec];

    int pos = 0;
    if (p == 0 && val) pos = atomicAdd(cursor + rcv, 1);  // one claimant/edge

    const float4 s4 = *(const float4*)(edge_sh + (size_t)ec * 4);
    const float sh_s = s4.x;
    const float sh_v[3] = {s4.y, s4.z, s4.w};
    const float* nf = node_ft + (size_t)snd * 40;
    const float c3 = 0.57735026918962576f;
    const float c7 = 0.70710678118654752f;

    float es[16];
    {
        const float4* a0 = (const float4*)(edge_scalars + (size_t)ec * 16);
#pragma unroll
        for (int t = 0; t < 4; ++t) {
            const float4 v = a0[t];
            es[4*t+0]=v.x; es[4*t+1]=v.y; es[4*t+2]=v.z; es[4*t+3]=v.w;
        }
    }

    // ================= stage K weights (dense copy) =================
#pragma unroll
    for (int it = 0; it < 5; ++it) {
        const int idx = it * BS + tid;              // 1280 = 5*256
        const int pg = idx / 320;
        swz[pg * 321 + (idx - pg * 320)] = pk[idx];
    }

    // ---- hk net (overlaps staging loads; barrier below drains both) ----
    float sa = 0.f;
    float hk[32];
#pragma unroll
    for (int j = 0; j < 32; ++j) {
        float a = 0.f;
#pragma unroll
        for (int t = 0; t < 16; ++t) a += es[t] * fck_w1[t*32 + j];
        hk[j] = silu_f(a * 0.25f);
    }
    __syncthreads();

    // ================= K phase =================
    {
        const uint4* g = swz + p * 321;

        const h2 xs01 = pkrtz(nf[4*p + 0], nf[4*p + 1]);
        const h2 xs23 = pkrtz(nf[4*p + 2], nf[4*p + 3]);
        const float x00 = nf[16 + 6*p], x01 = nf[17 + 6*p], x02 = nf[18 + 6*p];
        const float x10 = nf[19 + 6*p], x11 = nf[20 + 6*p], x12 = nf[21 + 6*p];
        const h2 pvp = pkrtz((x00*sh_v[0] + x01*sh_v[1] + x02*sh_v[2]) * c3,
                             (x10*sh_v[0] + x11*sh_v[1] + x12*sh_v[2]) * c3);

        h2 K1[8] = {}, K3[4] = {}, K2[8] = {};
#pragma unroll
        for (int j = 0; j < 32; ++j) {
            const uint4 A = g[j*4+0], B = g[j*4+1], C = g[j*4+2], D = g[j*4+3];
            const uint4 Ea = g[128 + j*2], Fb = g[128 + j*2 + 1];
            const uint4 U = g[192 + j*2], V = g[192 + j*2 + 1];
            const h2 hh = pkrtz(hk[j], hk[j]);
            const h2 t01 = hh * xs01, t23 = hh * xs23, tp = hh * pvp;
            K1[0]=pfma(t01,uh2(A.x),K1[0]); K1[0]=pfma(t23,uh2(C.x),K1[0]);
            K1[1]=pfma(t01,uh2(A.y),K1[1]); K1[1]=pfma(t23,uh2(C.y),K1[1]);
            K1[2]=pfma(t01,uh2(A.z),K1[2]); K1[2]=pfma(t23,uh2(C.z),K1[2]);
            K1[3]=pfma(t01,uh2(A.w),K1[3]); K1[3]=pfma(t23,uh2(C.w),K1[3]);
            K1[4]=pfma(t01,uh2(B.x),K1[4]); K1[4]=pfma(t23,uh2(D.x),K1[4]);
            K1[5]=pfma(t01,uh2(B.y),K1[5]); K1[5]=pfma(t23,uh2(D.y),K1[5]);
            K1[6]=pfma(t01,uh2(B.z),K1[6]); K1[6]=pfma(t23,uh2(D.z),K1[6]);
            K1[7]=pfma(t01,uh2(B.w),K1[7]); K1[7]=pfma(t23,uh2(D.w),K1[7]);
            K3[0]=pfma(t01,uh2(Ea.x),K3[0]); K3[0]=pfma(t23,uh2(Fb.x),K3[0]);
            K3[1]=pfma(t01,uh2(Ea.y),K3[1]); K3[1]=pfma(t23,uh2(Fb.y),K3[1]);
            K3[2]=pfma(t01,uh2(Ea.z),K3[2]); K3[2]=pfma(t23,uh2(Fb.z),K3[2]);
            K3[3]=pfma(t01,uh2(Ea.w),K3[3]); K3[3]=pfma(t23,uh2(Fb.w),K3[3]);
            K2[0]=pfma(tp,uh2(U.x),K2[0]); K2[1]=pfma(tp,uh2(U.y),K2[1]);
            K2[2]=pfma(tp,uh2(U.z),K2[2]); K2[3]=pfma(tp,uh2(U.w),K2[3]);
            K2[4]=pfma(tp,uh2(V.x),K2[4]); K2[5]=pfma(tp,uh2(V.y),K2[5]);
            K2[6]=pfma(tp,uh2(V.z),K2[6]); K2[7]=pfma(tp,uh2(V.w),K2[7]);
        }

        h2 P4[8] = {}, P5[8] = {};
#pragma unroll
        for (int jp = 0; jp < 16; ++jp) {
            const uint4 a4 = g[256 + jp*4 + 0];   // il0 w4
            const uint4 b4 = g[256 + jp*4 + 1];   // il0 w5
            const uint4 c4 = g[256 + jp*4 + 2];   // il1 w4
            const uint4 d4 = g[256 + jp*4 + 3];   // il1 w5
            const h2 hp = pkrtz(hk[2*jp], hk[2*jp+1]);
            P4[0]=pfma(hp,uh2(a4.x),P4[0]); P4[1]=pfma(hp,uh2(a4.y),P4[1]);
            P4[2]=pfma(hp,uh2(a4.z),P4[2]); P4[3]=pfma(hp,uh2(a4.w),P4[3]);
            P5[0]=pfma(hp,uh2(b4.x),P5[0]); P5[1]=pfma(hp,uh2(b4.y),P5[1]);
            P5[2]=pfma(hp,uh2(b4.z),P5[2]); P5[3]=pfma(hp,uh2(b4.w),P5[3]);
            P4[4]=pfma(hp,uh2(c4.x),P4[4]); P4[5]=pfma(hp,uh2(c4.y),P4[5]);
            P4[6]=pfma(hp,uh2(c4.z),P4[6]); P4[7]=pfma(hp,uh2(c4.w),P4[7]);
            P5[4]=pfma(hp,uh2(d4.x),P5[4]); P5[5]=pfma(hp,uh2(d4.y),P5[5]);
            P5[6]=pfma(hp,uh2(d4.z),P5[6]); P5[7]=pfma(hp,uh2(d4.w),P5[7]);
        }

        float ds = 0.f, dv = 0.f;
        {
            float qdr[20];
            const float4* rp = (const float4*)(qd + (size_t)rcv * 20);
#pragma unroll
            for (int t = 0; t < 5; ++t) {
                const float4 a = rp[t];
                qdr[4*t+0]=a.x; qdr[4*t+1]=a.y; qdr[4*t+2]=a.z; qdr[4*t+3]=a.w;
            }
#pragma unroll
            for (int o = 0; o < 8; ++o)
                ds += qdr[o] * (sh_s*h2s(K1[o]) + h2s(K2[o]));
            float KV[12] = {};
            {
                const float s0=sh_s*x00, s1=sh_s*x01, s2=sh_s*x02;
                const float cx0=c7*(x01*sh_v[2]-x02*sh_v[1]);
                const float cx1=c7*(x02*sh_v[0]-x00*sh_v[2]);
                const float cx2=c7*(x00*sh_v[1]-x01*sh_v[0]);
#pragma unroll
                for (int o = 0; o < 4; ++o) {
                    const float w4 = h2s(P4[o]), w5 = h2s(P5[o]);
                    KV[o*3+0] += s0*w4 + cx0*w5;
                    KV[o*3+1] += s1*w4 + cx1*w5;
                    KV[o*3+2] += s2*w4 + cx2*w5;
                }
            }
            {
                const float s0=sh_s*x10, s1=sh_s*x11, s2=sh_s*x12;
                const float cx0=c7*(x11*sh_v[2]-x12*sh_v[1]);
                const float cx1=c7*(x12*sh_v[0]-x10*sh_v[2]);
                const float cx2=c7*(x10*sh_v[1]-x11*sh_v[0]);
#pragma unroll
                for (int o = 0; o < 4; ++o) {
                    const float w4 = h2s(P4[4+o]), w5 = h2s(P5[4+o]);
                    KV[o*3+0] += s0*w4 + cx0*w5;
                    KV[o*3+1] += s1*w4 + cx1*w5;
                    KV[o*3+2] += s2*w4 + cx2*w5;
                }
            }
#pragma unroll
            for (int o = 0; o < 4; ++o) {
                const float k3 = h2s(K3[o]);
#pragma unroll
                for (int c = 0; c < 3; ++c)
                    dv += qdr[8 + o*3 + c] * (k3*sh_v[c] + KV[o*3+c]);
            }
        }
        ds = wred4(ds); dv = wred4(dv);

        if (p == 0 && val) {
            const float dot = ds * 4.0343567508008e-3f + dv * 2.0171788261497e-3f;
            sa = __expf(0.5f * dot);
            vbuf[(size_t)pos * 44 + 40] = sa * sa;
        }
    }

    // ================= stage Va weights (dense copy) =================
    __syncthreads();                         // all K reads complete
#pragma unroll
    for (int it = 0; it < 6; ++it) {
        const int idx = it * BS + tid;              // 1536 = 6*256
        const int pg = idx / 384;
        swz[pg * 385 + (idx - pg * 384)] = pk[1280 + idx];
    }

    // ---- hv net (overlaps Va staging; spans Va and Vb) ----
    float hv[32];
#pragma unroll
    for (int j = 0; j < 32; ++j) {
        float a = 0.f;
#pragma unroll
        for (int t = 0; t < 16; ++t) a += es[t] * fcv_w1[t*32 + j];
        hv[j] = silu_f(a * 0.25f);
    }
    __syncthreads();

    // ================= Va phase =================
    {
        const uint4* g = swz + p * 385;

        const h2 xs01 = pkrtz(nf[4*p + 0]*sh_s, nf[4*p + 1]*sh_s);
        const h2 xs23 = pkrtz(nf[4*p + 2]*sh_s, nf[4*p + 3]*sh_s);
        const h2 pvp = pkrtz(
            (nf[16+6*p]*sh_v[0] + nf[17+6*p]*sh_v[1] + nf[18+6*p]*sh_v[2]) * c3,
            (nf[19+6*p]*sh_v[0] + nf[20+6*p]*sh_v[1] + nf[21+6*p]*sh_v[2]) * c3);

        h2 Aa[16] = {};
#pragma unroll
        for (int j = 0; j < 32; ++j) {
            const uint4* gw = g + j*8;
            const uint4 a0 = gw[0], a1 = gw[1], a2 = gw[2], a3 = gw[3];   // ip0
            const uint4 b0 = gw[4], b1 = gw[5], b2 = gw[6], b3 = gw[7];   // ip1
            const uint4* g2 = g + 256 + j*4;
            const uint4 u0 = g2[0], u1 = g2[1], u2 = g2[2], u3 = g2[3];
            const h2 hh = pkrtz(hv[j], hv[j]);
            const h2 t01 = hh * xs01, t23 = hh * xs23, tp = hh * pvp;
            Aa[0] =pfma(t01,uh2(a0.x),Aa[0]);  Aa[0] =pfma(t23,uh2(b0.x),Aa[0]);  Aa[0] =pfma(tp,uh2(u0.x),Aa[0]);
            Aa[1] =pfma(t01,uh2(a0.y),Aa[1]);  Aa[1] =pfma(t23,uh2(b0.y),Aa[1]);  Aa[1] =pfma(tp,uh2(u0.y),Aa[1]);
            Aa[2] =pfma(t01,uh2(a0.z),Aa[2]);  Aa[2] =pfma(t23,uh2(b0.z),Aa[2]);  Aa[2] =pfma(tp,uh2(u0.z),Aa[2]);
            Aa[3] =pfma(t01,uh2(a0.w),Aa[3]);  Aa[3] =pfma(t23,uh2(b0.w),Aa[3]);  Aa[3] =pfma(tp,uh2(u0.w),Aa[3]);
            Aa[4] =pfma(t01,uh2(a1.x),Aa[4]);  Aa[4] =pfma(t23,uh2(b1.x),Aa[4]);  Aa[4] =pfma(tp,uh2(u1.x),Aa[4]);
            Aa[5] =pfma(t01,uh2(a1.y),Aa[5]);  Aa[5] =pfma(t23,uh2(b1.y),Aa[5]);  Aa[5] =pfma(tp,uh2(u1.y),Aa[5]);
            Aa[6] =pfma(t01,uh2(a1.z),Aa[6]);  Aa[6] =pfma(t23,uh2(b1.z),Aa[6]);  Aa[6] =pfma(tp,uh2(u1.z),Aa[6]);
            Aa[7] =pfma(t01,uh2(a1.w),Aa[7]);  Aa[7] =pfma(t23,uh2(b1.w),Aa[7]);  Aa[7] =pfma(tp,uh2(u1.w),Aa[7]);
            Aa[8] =pfma(t01,uh2(a2.x),Aa[8]);  Aa[8] =pfma(t23,uh2(b2.x),Aa[8]);  Aa[8] =pfma(tp,uh2(u2.x),Aa[8]);
            Aa[9] =pfma(t01,uh2(a2.y),Aa[9]);  Aa[9] =pfma(t23,uh2(b2.y),Aa[9]);  Aa[9] =pfma(tp,uh2(u2.y),Aa[9]);
            Aa[10]=pfma(t01,uh2(a2.z),Aa[10]); Aa[10]=pfma(t23,uh2(b2.z),Aa[10]); Aa[10]=pfma(tp,uh2(u2.z),Aa[10]);
            Aa[11]=pfma(t01,uh2(a2.w),Aa[11]); Aa[11]=pfma(t23,uh2(b2.w),Aa[11]); Aa[11]=pfma(tp,uh2(u2.w),Aa[11]);
            Aa[12]=pfma(t01,uh2(a3.x),Aa[12]); Aa[12]=pfma(t23,uh2(b3.x),Aa[12]); Aa[12]=pfma(tp,uh2(u3.x),Aa[12]);
            Aa[13]=pfma(t01,uh2(a3.y),Aa[13]); Aa[13]=pfma(t23,uh2(b3.y),Aa[13]); Aa[13]=pfma(tp,uh2(u3.y),Aa[13]);
            Aa[14]=pfma(t01,uh2(a3.z),Aa[14]); Aa[14]=pfma(t23,uh2(b3.z),Aa[14]); Aa[14]=pfma(tp,uh2(u3.z),Aa[14]);
            Aa[15]=pfma(t01,uh2(a3.w),Aa[15]); Aa[15]=pfma(t23,uh2(b3.w),Aa[15]); Aa[15]=pfma(tp,uh2(u3.w),Aa[15]);
        }

        float A0[16];
#pragma unroll
        for (int o = 0; o < 16; ++o) A0[o] = wred4(h2s(Aa[o]));

        if (p == 0 && val) {
            const float cs = 0.03608439182435161f;   // (1/sqrt32)*(1/sqrt24)
            float4* vp = (float4*)(vbuf + (size_t)pos * 44);
#pragma unroll
            for (int t = 0; t < 4; ++t) {
                float4 r;
                r.x = sa * A0[4*t+0] * cs; r.y = sa * A0[4*t+1] * cs;
                r.z = sa * A0[4*t+2] * cs; r.w = sa * A0[4*t+3] * cs;
                vp[t] = r;
            }
        }
    }

    // ================= stage Vb weights (dense copy) =================
    __syncthreads();                         // all Va reads complete
#pragma unroll
    for (int it = 0; it < 4; ++it) {
        const int idx = it * BS + tid;              // 1024 = 4*256
        const int pg = idx >> 8;
        swz[pg * 257 + (idx & 255)] = pk[2816 + idx];
    }
    __syncthreads();

    // ================= Vb phase =================
    {
        const uint4* g = swz + p * 257;

        const h2 xs01 = pkrtz(nf[4*p + 0], nf[4*p + 1]);
        const h2 xs23 = pkrtz(nf[4*p + 2], nf[4*p + 3]);

        h2 T3[8] = {};
#pragma unroll
        for (int j = 0; j < 32; ++j) {
            const uint4 E0 = g[j*4+0], E1 = g[j*4+1];   // ip0: o0..3, o4..7
            const uint4 F0 = g[j*4+2], F1 = g[j*4+3];   // ip1
            const h2 hh = pkrtz(hv[j], hv[j]);
            const h2 t01 = hh * xs01, t23 = hh * xs23;
            T3[0]=pfma(t01,uh2(E0.x),T3[0]); T3[0]=pfma(t23,uh2(F0.x),T3[0]);
            T3[1]=pfma(t01,uh2(E0.y),T3[1]); T3[1]=pfma(t23,uh2(F0.y),T3[1]);
            T3[2]=pfma(t01,uh2(E0.z),T3[2]); T3[2]=pfma(t23,uh2(F0.z),T3[2]);
            T3[3]=pfma(t01,uh2(E0.w),T3[3]); T3[3]=pfma(t23,uh2(F0.w),T3[3]);
            T3[4]=pfma(t01,uh2(E1.x),T3[4]); T3[4]=pfma(t23,uh2(F1.x),T3[4]);
            T3[5]=pfma(t01,uh2(E1.y),T3[5]); T3[5]=pfma(t23,uh2(F1.y),T3[5]);
            T3[6]=pfma(t01,uh2(E1.z),T3[6]); T3[6]=pfma(t23,uh2(F1.z),T3[6]);
            T3[7]=pfma(t01,uh2(E1.w),T3[7]); T3[7]=pfma(t23,uh2(F1.w),T3[7]);
        }

        h2 P4[16] = {}, P5[16] = {};
#pragma unroll
        for (int jp = 0; jp < 16; ++jp) {
            const uint4* gw = g + 128 + jp*8;
            const uint4 a4 = gw[0], b4 = gw[1];   // il0 w4 o0-3, o4-7
            const uint4 c4 = gw[2], d4 = gw[3];   // il0 w5
            const uint4 e4 = gw[4], f4 = gw[5];   // il1 w4
            const uint4 m4 = gw[6], n4 = gw[7];   // il1 w5
            const h2 hp = pkrtz(hv[2*jp], hv[2*jp+1]);
            P4[0] =pfma(hp,uh2(a4.x),P4[0]);  P4[1] =pfma(hp,uh2(a4.y),P4[1]);
            P4[2] =pfma(hp,uh2(a4.z),P4[2]);  P4[3] =pfma(hp,uh2(a4.w),P4[3]);
            P4[4] =pfma(hp,uh2(b4.x),P4[4]);  P4[5] =pfma(hp,uh2(b4.y),P4[5]);
            P4[6] =pfma(hp,uh2(b4.z),P4[6]);  P4[7] =pfma(hp,uh2(b4.w),P4[7]);
            P5[0] =pfma(hp,uh2(c4.x),P5[0]);  P5[1] =pfma(hp,uh2(c4.y),P5[1]);
            P5[2] =pfma(hp,uh2(c4.z),P5[2]);  P5[3] =pfma(hp,uh2(c4.w),P5[3]);
            P5[4] =pfma(hp,uh2(d4.x),P5[4]);  P5[5] =pfma(hp,uh2(d4.y),P5[5]);
            P5[6] =pfma(hp,uh2(d4.z),P5[6]);  P5[7] =pfma(hp,uh2(d4.w),P5[7]);
            P4[8] =pfma(hp,uh2(e4.x),P4[8]);  P4[9] =pfma(hp,uh2(e4.y),P4[9]);
            P4[10]=pfma(hp,uh2(e4.z),P4[10]); P4[11]=pfma(hp,uh2(e4.w),P4[11]);
            P4[12]=pfma(hp,uh2(f4.x),P4[12]); P4[13]=pfma(hp,uh2(f4.y),P4[13]);
            P4[14]=pfma(hp,uh2(f4.z),P4[14]); P4[15]=pfma(hp,uh2(f4.w),P4[15]);
            P5[8] =pfma(hp,uh2(m4.x),P5[8]);  P5[9] =pfma(hp,uh2(m4.y),P5[9]);
            P5[10]=pfma(hp,uh2(m4.z),P5[10]); P5[11]=pfma(hp,uh2(m4.w),P5[11]);
            P5[12]=pfma(hp,uh2(n4.x),P5[12]); P5[13]=pfma(hp,uh2(n4.y),P5[13]);
            P5[14]=pfma(hp,uh2(n4.z),P5[14]); P5[15]=pfma(hp,uh2(n4.w),P5[15]);
        }

        float R[24], T3f[8];
        {
            float acc[24];
#pragma unroll
            for (int o = 0; o < 24; ++o) acc[o] = 0.f;
            {
                const float x0 = nf[16 + 6*p], x1 = nf[17 + 6*p], x2 = nf[18 + 6*p];
                const float s0 = sh_s*x0, s1 = sh_s*x1, s2 = sh_s*x2;
                const float cx0 = c7*(x1*sh_v[2] - x2*sh_v[1]);
                const float cx1 = c7*(x2*sh_v[0] - x0*sh_v[2]);
                const float cx2 = c7*(x0*sh_v[1] - x1*sh_v[0]);
#pragma unroll
                for (int o = 0; o < 8; ++o) {
                    const float w4 = h2s(P4[o]), w5 = h2s(P5[o]);
                    acc[o*3+0] += s0*w4 + cx0*w5;
                    acc[o*3+1] += s1*w4 + cx1*w5;
                    acc[o*3+2] += s2*w4 + cx2*w5;
                }
            }
            {
                const float x0 = nf[19 + 6*p], x1 = nf[20 + 6*p], x2 = nf[21 + 6*p];
                const float s0 = sh_s*x0, s1 = sh_s*x1, s2 = sh_s*x2;
                const float cx0 = c7*(x1*sh_v[2] - x2*sh_v[1]);
                const float cx1 = c7*(x2*sh_v[0] - x0*sh_v[2]);
                const float cx2 = c7*(x0*sh_v[1] - x1*sh_v[0]);
#pragma unroll
                for (int o = 0; o < 8; ++o) {
                    const float w4 = h2s(P4[8+o]), w5 = h2s(P5[8+o]);
                    acc[o*3+0] += s0*w4 + cx0*w5;
                    acc[o*3+1] += s1*w4 + cx1*w5;
                    acc[o*3+2] += s2*w4 + cx2*w5;
                }
            }
#pragma unroll
            for (int o = 0; o < 24; ++o) R[o] = wred4(acc[o]);
        }
#pragma unroll
        for (int o = 0; o < 8; ++o) T3f[o] = wred4(h2s(T3[o]));

        if (p == 0 && val) {
            const float sc = 0.03125f;               // (1/sqrt32)*(1/sqrt32)
            float row[24];
#pragma unroll
            for (int o = 0; o < 8; ++o)
#pragma unroll
                for (int c = 0; c < 3; ++c)
                    row[o*3+c] = sa * (T3f[o]*sh_v[c] + R[o*3+c]) * sc;
            float4* vp = (float4*)(vbuf + (size_t)pos * 44 + 16);
#pragma unroll
            for (int t = 0; t < 6; ++t) {
                float4 r; r.x = row[4*t+0]; r.y = row[4*t+1]; r.z = row[4*t+2]; r.w = row[4*t+3];
                vp[t] = r;
            }
        }
    }
}

__global__ __launch_bounds__(256) void node_reduce(
    const int*   __restrict__ start,
    const float* __restrict__ vbuf,         // [E,44]: V row + ex at slot 40
    float* __restrict__ out, int N)
{
    const int wave = threadIdx.x >> 6;
    const int lane = threadIdx.x & 63;
    const int n = blockIdx.x * 4 + wave;
    if (n >= N) return;
    const int r0 = start[n], r1 = start[n + 1];
    float z = 0.f, comp = 0.f;
    for (int r = r0; r < r1; ++r) {
        const float* row = vbuf + (size_t)r * 44;
        z += row[40];
        if (lane < 40) comp += row[lane];
    }
    if (lane < 40)
        out[(size_t)n * 40 + lane] = (z > 0.f) ? comp * rsqrtf(z) : 0.f;
}

extern "C" void kernel_launch(void* const* d_in, const int* in_sizes, int n_in,
                              void* d_out, int out_size, void* d_ws, size_t ws_size,
                              hipStream_t stream) {
    const float* node_ft      = (const float*)d_in[0];
    const int*   edge_index   = (const int*)  d_in[1];
    const float* edge_sh      = (const float*)d_in[2];
    const float* edge_scalars = (const float*)d_in[3];
    const float* w_q_s        = (const float*)d_in[4];
    const float* w_q_v        = (const float*)d_in[5];
    const float* fck_w1       = (const float*)d_in[6];
    const float* fck_w2       = (const float*)d_in[7];
    const float* fcv_w1       = (const float*)d_in[8];
    const float* fcv_w2       = (const float*)d_in[9];
    const float* wdot_s       = (const float*)d_in[10];
    const float* wdot_v       = (const float*)d_in[11];

    const int N = in_sizes[0] / 40;
    const int E = in_sizes[2] / 4;

    float* ws    = (float*)d_ws;
    float* qd    = ws;                               // N*20
    int*   cnt   = (int*)(ws + (size_t)N * 20);      // N
    int*   start = cnt + N;                          // N+1
    int*   curs  = start + N + 1;                    // N
    int*   flg   = curs + N;                         // 1
    size_t off   = (size_t)N * 20 + N + (N + 1) + N + 1;
    off = (off + 3) & ~(size_t)3;                    // 16B align
    uint4* pk    = (uint4*)(ws + off);               // 3840 uint4 = 15360 floats
    float* vbuf  = ws + off + 15360;                 // E*44 (16B-aligned rows)

    float* out = (float*)d_out;

    const int NE = (E > N) ? E : N;
    const int EB = (E + EPB - 1) / EPB;

    hipMemsetAsync(cnt, 0, (size_t)N * sizeof(int), stream);
    hipLaunchKernelGGL(pre_count, dim3((NE + 255) / 256), dim3(256), 0, stream,
                       node_ft, edge_index, w_q_s, w_q_v, wdot_s, wdot_v,
                       fck_w2, fcv_w2, qd, cnt, flg, pk, N, E);
    hipLaunchKernelGGL(scan_kernel, dim3(1), dim3(1024), 0, stream,
                       cnt, start, curs, N);
    hipLaunchKernelGGL(edge_all, dim3(EB), dim3(BS), 0, stream,
                       node_ft, edge_index, edge_sh, edge_scalars,
                       fck_w1, fcv_w1, pk, qd, curs, vbuf, flg, N, E);
    hipLaunchKernelGGL(node_reduce, dim3((N + 3) / 4), dim3(256), 0, stream,
                       start, vbuf, out, N);
}